// Round 4
// baseline (1305.216 us; speedup 1.0000x reference)
//
#include <hip/hip_runtime.h>
#include <math.h>

#define B_ 32
#define L_ 256
#define C_ 55
#define D_ 512
#define H_ 8
#define NL_ 3
#define DF_ 512
#define Z_ 16
#define DK_ 64

typedef unsigned short u16;
typedef __attribute__((ext_vector_type(8))) short bf16x8;
typedef __attribute__((ext_vector_type(4))) float f32x4;

__device__ __forceinline__ float bf2f(u16 u) {
  unsigned v = ((unsigned)u) << 16;
  return __builtin_bit_cast(float, v);
}
__device__ __forceinline__ u16 f2bf(float f) {
  unsigned u = __builtin_bit_cast(unsigned, f);
  u += 0x7fffu + ((u >> 16) & 1u);
  return (u16)(u >> 16);
}
__device__ __forceinline__ void gload16(const void* g, void* l) {
  __builtin_amdgcn_global_load_lds(
      (const __attribute__((address_space(1))) unsigned*)g,
      (__attribute__((address_space(3))) unsigned*)l, 16, 0, 0);
}

// ---------------- block reduce (256 threads = 4 waves) ----------------
__device__ __forceinline__ float blockReduceSum(float v, float* sm) {
#pragma unroll
  for (int off = 32; off > 0; off >>= 1) v += __shfl_xor(v, off, 64);
  int wid = threadIdx.x >> 6;
  if ((threadIdx.x & 63) == 0) sm[wid] = v;
  __syncthreads();
  float r = sm[0] + sm[1] + sm[2] + sm[3];
  __syncthreads();
  return r;
}

// ================= MFMA GEMM: C = act(alpha * A @ B^T + bias) ==============
// SPLIT: 3-term bf16x3 (Ah*Bh + Al*Bh + Ah*Bl). OUT: 0 fp32, 1 bf16, 2 split.
template <int WM, int WN, bool SPLIT, int ACT, int OUT>
__global__ __launch_bounds__(WM * WN * 64) void mgemm(
    const u16* __restrict__ Ah, const u16* __restrict__ Al,
    const u16* __restrict__ Bh, const u16* __restrict__ Bl,
    const float* __restrict__ bias, float* __restrict__ Cf,
    u16* __restrict__ Ch, u16* __restrict__ Cl, int K, int lda, int ldb,
    int ldc, float alpha) {
  constexpr int BM = WM * 64, BN = WN * 64, T = WM * WN * 64;
  __shared__ __align__(16) short As[BM * 32];
  __shared__ __align__(16) short Bs[BN * 32];
  __shared__ __align__(16) short Als[SPLIT ? BM * 32 : 8];
  __shared__ __align__(16) short Bls[SPLIT ? BN * 32 : 8];
  const int t = threadIdx.x, lane = t & 63, w = t >> 6;
  const int wm = w / WN, wn = w % WN;
  const long m0 = (long)blockIdx.y * BM, n0 = (long)blockIdx.x * BN;
  const char* Ab = (const char*)(Ah + m0 * lda);
  const char* Bb = (const char*)(Bh + n0 * ldb);
  const char* Alb = SPLIT ? (const char*)(Al + m0 * lda) : nullptr;
  const char* Blb = SPLIT ? (const char*)(Bl + n0 * ldb) : nullptr;
  const int fr = lane & 15, gq = lane >> 4;
  const int aoff = ((wm * 64 + fr) * 64 + gq * 16) >> 1;
  const int boff = ((wn * 64 + fr) * 64 + gq * 16) >> 1;
  const long lda2 = (long)lda * 2, ldb2 = (long)ldb * 2;
  f32x4 acc[4][4] = {};
  for (int k0 = 0; k0 < K; k0 += 32) {
    const long kb = (long)k0 * 2;
#pragma unroll
    for (int e = 0; e < BM * 4; e += T) {
      int d = (e + t) * 16;
      long src = (long)(d >> 6) * lda2 + kb + (d & 63);
      gload16(Ab + src, (char*)As + d);
      if (SPLIT) gload16(Alb + src, (char*)Als + d);
    }
#pragma unroll
    for (int e = 0; e < BN * 4; e += T) {
      int d = (e + t) * 16;
      long src = (long)(d >> 6) * ldb2 + kb + (d & 63);
      gload16(Bb + src, (char*)Bs + d);
      if (SPLIT) gload16(Blb + src, (char*)Bls + d);
    }
    __syncthreads();
    bf16x8 a[4], b[4], a2[4], b2[4];
#pragma unroll
    for (int m = 0; m < 4; ++m) {
      a[m] = *(const bf16x8*)(As + aoff + m * 512);
      if (SPLIT) a2[m] = *(const bf16x8*)(Als + aoff + m * 512);
    }
#pragma unroll
    for (int n = 0; n < 4; ++n) {
      b[n] = *(const bf16x8*)(Bs + boff + n * 512);
      if (SPLIT) b2[n] = *(const bf16x8*)(Bls + boff + n * 512);
    }
#pragma unroll
    for (int m = 0; m < 4; ++m)
#pragma unroll
      for (int n = 0; n < 4; ++n) {
        if (SPLIT) {
          acc[m][n] = __builtin_amdgcn_mfma_f32_16x16x32_bf16(a2[m], b[n],
                                                              acc[m][n], 0, 0, 0);
          acc[m][n] = __builtin_amdgcn_mfma_f32_16x16x32_bf16(a[m], b2[n],
                                                              acc[m][n], 0, 0, 0);
        }
        acc[m][n] =
            __builtin_amdgcn_mfma_f32_16x16x32_bf16(a[m], b[n], acc[m][n], 0, 0, 0);
      }
    __syncthreads();
  }
#pragma unroll
  for (int m = 0; m < 4; ++m) {
    long mg = m0 + wm * 64 + m * 16 + gq * 4;
#pragma unroll
    for (int n = 0; n < 4; ++n) {
      long ng = n0 + wn * 64 + n * 16 + fr;
      float bv = bias ? bias[ng] : 0.f;
#pragma unroll
      for (int r = 0; r < 4; ++r) {
        float v = acc[m][n][r] * alpha + bv;
        if (ACT == 1) v = 0.5f * v * (1.f + erff(v * 0.70710678118654752f));
        long idx = (mg + r) * ldc + ng;
        if (OUT == 0) Cf[idx] = v;
        if (OUT >= 1) {
          u16 hv = f2bf(v);
          Ch[idx] = hv;
          if (OUT == 2) Cl[idx] = f2bf(v - bf2f(hv));
        }
      }
    }
  }
}

// =============== fused attention: scores+softmax+series+PV =================
// grid (L/64, B*H), 256 threads. Q,K from merged qk buffers (ld=1024):
// q cols [0,512), k cols [512,1024). vt hi/lo are (512, M). pv hi/lo (M,512).
__global__ __launch_bounds__(256, 2) void fused_attn(
    const u16* __restrict__ qkh, const u16* __restrict__ qkl,
    const u16* __restrict__ vth, const u16* __restrict__ vtl,
    const float* __restrict__ vbias, float* __restrict__ ser,
    u16* __restrict__ pvh, u16* __restrict__ pvl) {
  __shared__ __align__(16) char smem[67584];
  char* Kreg = smem;                       // 32KB: K staging / P matrix
  char* Qreg = smem + 32768;               // Q hi+lo (18.4KB) / V hi+lo (32KB)
  float* rowred = (float*)(smem + 65536);  // [4][64][2]
  const int t = threadIdx.x, lane = t & 63, w = t >> 6;
  const int fr = lane & 15, gq = lane >> 4;
  const int r0 = blockIdx.x * 64;
  const int bh = blockIdx.y, b = bh >> 3, h = bh & 7;
  const long qrow0 = (long)b * 256 + r0;
  const long krow0 = (long)b * 256;
  // ---- stage Q (rows r0..+63, 64 cols), layout [64][72] shorts, hi+lo
  {
    const char* qs = (const char*)qkh + qrow0 * 2048 + h * 128;
    const char* ql = (const char*)qkl + qrow0 * 2048 + h * 128;
#pragma unroll
    for (int j = 0; j < 2; ++j) {
      int id = t + j * 256;
      int row = id >> 3, c = id & 7;
      bf16x8 vh = *(const bf16x8*)(qs + (long)row * 2048 + c * 16);
      bf16x8 vl = *(const bf16x8*)(ql + (long)row * 2048 + c * 16);
      *(bf16x8*)(Qreg + row * 144 + c * 16) = vh;
      *(bf16x8*)(Qreg + 9216 + row * 144 + c * 16) = vl;
    }
  }
  // ---- stage Kh full (256x64) with chunk-xor swizzle
  const char* kbh = (const char*)qkh + krow0 * 2048 + 1024 + h * 128;
  const char* kbl = (const char*)qkl + krow0 * 2048 + 1024 + h * 128;
#pragma unroll
  for (int j = 0; j < 8; ++j) {
    int id = t + j * 256;
    int row = id >> 3, c = (id & 7) ^ (row & 7);
    gload16(kbh + (long)row * 2048 + c * 16, Kreg + id * 16);
  }
  __syncthreads();
  f32x4 acc[4][4] = {};
  // ---- phase A: ql*kh + qh*kh
#pragma unroll
  for (int ks = 0; ks < 2; ++ks) {
    bf16x8 ah[4], al[4], bk[4];
#pragma unroll
    for (int m = 0; m < 4; ++m) {
      int qb = (m * 16 + fr) * 144 + gq * 16 + ks * 64;
      ah[m] = *(const bf16x8*)(Qreg + qb);
      al[m] = *(const bf16x8*)(Qreg + 9216 + qb);
    }
#pragma unroll
    for (int n = 0; n < 4; ++n) {
      int row = w * 64 + n * 16 + fr;
      bk[n] = *(const bf16x8*)(Kreg + row * 128 +
                               ((gq * 16 + ks * 64) ^ ((row & 7) << 4)));
    }
#pragma unroll
    for (int m = 0; m < 4; ++m)
#pragma unroll
      for (int n = 0; n < 4; ++n) {
        acc[m][n] =
            __builtin_amdgcn_mfma_f32_16x16x32_bf16(al[m], bk[n], acc[m][n], 0, 0, 0);
        acc[m][n] =
            __builtin_amdgcn_mfma_f32_16x16x32_bf16(ah[m], bk[n], acc[m][n], 0, 0, 0);
      }
  }
  __syncthreads();
  // ---- restage Kl
#pragma unroll
  for (int j = 0; j < 8; ++j) {
    int id = t + j * 256;
    int row = id >> 3, c = (id & 7) ^ (row & 7);
    gload16(kbl + (long)row * 2048 + c * 16, Kreg + id * 16);
  }
  __syncthreads();
  // ---- phase B: qh*kl
#pragma unroll
  for (int ks = 0; ks < 2; ++ks) {
    bf16x8 ah[4], bk[4];
#pragma unroll
    for (int m = 0; m < 4; ++m)
      ah[m] = *(const bf16x8*)(Qreg + (m * 16 + fr) * 144 + gq * 16 + ks * 64);
#pragma unroll
    for (int n = 0; n < 4; ++n) {
      int row = w * 64 + n * 16 + fr;
      bk[n] = *(const bf16x8*)(Kreg + row * 128 +
                               ((gq * 16 + ks * 64) ^ ((row & 7) << 4)));
    }
#pragma unroll
    for (int m = 0; m < 4; ++m)
#pragma unroll
      for (int n = 0; n < 4; ++n)
        acc[m][n] =
            __builtin_amdgcn_mfma_f32_16x16x32_bf16(ah[m], bk[n], acc[m][n], 0, 0, 0);
  }
  // ---- softmax: scale, wave-local max/sum, one cross-wave LDS round
#pragma unroll
  for (int m = 0; m < 4; ++m)
#pragma unroll
    for (int n = 0; n < 4; ++n) acc[m][n] *= 0.125f;
  float lmax[4][4], lsum[4][4];
#pragma unroll
  for (int m = 0; m < 4; ++m)
#pragma unroll
    for (int r = 0; r < 4; ++r) {
      float v = fmaxf(fmaxf(acc[m][0][r], acc[m][1][r]),
                      fmaxf(acc[m][2][r], acc[m][3][r]));
#pragma unroll
      for (int off = 8; off > 0; off >>= 1) v = fmaxf(v, __shfl_xor(v, off, 64));
      lmax[m][r] = v;
    }
#pragma unroll
  for (int m = 0; m < 4; ++m)
#pragma unroll
    for (int n = 0; n < 4; ++n)
#pragma unroll
      for (int r = 0; r < 4; ++r)
        acc[m][n][r] = __expf(acc[m][n][r] - lmax[m][r]);
#pragma unroll
  for (int m = 0; m < 4; ++m)
#pragma unroll
    for (int r = 0; r < 4; ++r) {
      float s = acc[m][0][r] + acc[m][1][r] + acc[m][2][r] + acc[m][3][r];
#pragma unroll
      for (int off = 8; off > 0; off >>= 1) s += __shfl_xor(s, off, 64);
      lsum[m][r] = s;
    }
  if (fr == 0) {
#pragma unroll
    for (int m = 0; m < 4; ++m)
#pragma unroll
      for (int r = 0; r < 4; ++r) {
        int row = m * 16 + gq * 4 + r;
        rowred[(w * 64 + row) * 2] = lmax[m][r];
        rowred[(w * 64 + row) * 2 + 1] = lsum[m][r];
      }
  }
  __syncthreads();
  float scale[4][4];
#pragma unroll
  for (int m = 0; m < 4; ++m)
#pragma unroll
    for (int r = 0; r < 4; ++r) {
      int row = m * 16 + gq * 4 + r;
      float g = -1e30f, tot = 0.f;
      float2 pr[4];
#pragma unroll
      for (int ww = 0; ww < 4; ++ww) {
        pr[ww] = *(const float2*)&rowred[(ww * 64 + row) * 2];
        g = fmaxf(g, pr[ww].x);
      }
#pragma unroll
      for (int ww = 0; ww < 4; ++ww) tot += pr[ww].y * __expf(pr[ww].x - g);
      scale[m][r] = __expf(lmax[m][r] - g) / tot;
    }
  // ---- issue Vt half0 loads (d rows 0..31, hi+lo) into Qreg (Q is dead)
  const char* vtbh = (const char*)vth + ((long)h * 64 * 8192 + krow0) * 2;
  const char* vtbl = (const char*)vtl + ((long)h * 64 * 8192 + krow0) * 2;
#pragma unroll
  for (int j = 0; j < 4; ++j) {
    int id = t + j * 256;
    int row = id >> 5, c = (id & 31) ^ (row & 7);
    gload16(vtbh + (long)row * 16384 + c * 16, Qreg + id * 16);
    gload16(vtbl + (long)row * 16384 + c * 16, Qreg + 16384 + id * 16);
  }
  // ---- write series (fp32, global) + P (bf16, swizzled LDS @ Kreg)
  float* serb = ser + ((long)bh * 256 + r0) * 256 + w * 64;
#pragma unroll
  for (int m = 0; m < 4; ++m)
#pragma unroll
    for (int n = 0; n < 4; ++n)
#pragma unroll
      for (int r = 0; r < 4; ++r) {
        int row = m * 16 + gq * 4 + r, col = n * 16 + fr;
        float p = acc[m][n][r] * scale[m][r];
        serb[(long)row * 256 + col] = p;
        int pb = row * 512 + (((w * 64 + col) * 2) ^ ((row & 7) << 4));
        *(u16*)(Kreg + pb) = f2bf(p);
      }
  __syncthreads();  // drains Vt half0 + P visible
  // ---- PV in two d-halves, V = Vh + Vl
#pragma unroll
  for (int half = 0; half < 2; ++half) {
    if (half) {
      __syncthreads();  // all half0 reads done
#pragma unroll
      for (int j = 0; j < 4; ++j) {
        int id = t + j * 256;
        int row = id >> 5, c = (id & 31) ^ (row & 7);
        gload16(vtbh + (long)(32 + row) * 16384 + c * 16, Qreg + id * 16);
        gload16(vtbl + (long)(32 + row) * 16384 + c * 16,
                Qreg + 16384 + id * 16);
      }
      __syncthreads();  // drain
    }
    f32x4 acc2[2] = {};
#pragma unroll
    for (int ks = 0; ks < 8; ++ks) {
      int arow = w * 16 + fr;
      bf16x8 pa = *(const bf16x8*)(
          Kreg + arow * 512 + ((gq * 16 + ks * 64) ^ ((arow & 7) << 4)));
#pragma unroll
      for (int n = 0; n < 2; ++n) {
        int vrow = n * 16 + fr;
        int vo = vrow * 512 + ((gq * 16 + ks * 64) ^ ((vrow & 7) << 4));
        bf16x8 vbh = *(const bf16x8*)(Qreg + vo);
        bf16x8 vbl = *(const bf16x8*)(Qreg + 16384 + vo);
        acc2[n] = __builtin_amdgcn_mfma_f32_16x16x32_bf16(pa, vbh, acc2[n], 0, 0, 0);
        acc2[n] = __builtin_amdgcn_mfma_f32_16x16x32_bf16(pa, vbl, acc2[n], 0, 0, 0);
      }
    }
#pragma unroll
    for (int n = 0; n < 2; ++n) {
#pragma unroll
      for (int r = 0; r < 4; ++r) {
        int gcol = h * 64 + half * 32 + n * 16 + fr;
        long gm = qrow0 + w * 16 + gq * 4 + r;
        float val = acc2[n][r] + vbias[gcol];
        u16 hv = f2bf(val);
        pvh[gm * 512 + gcol] = hv;
        pvl[gm * 512 + gcol] = f2bf(val - bf2f(hv));
      }
    }
  }
}

// ---------------- fp32 tiled GEMM (small decoder GEMMs only) ---------------
template <int ACT>
__global__ __launch_bounds__(256) void gemm_kernel(
    const float* __restrict__ A, const float* __restrict__ Bm,
    const float* __restrict__ bias, float* __restrict__ C, int M, int N, int K,
    int lda, int ldb, int ldc, float alpha) {
  __shared__ float Asm[16][65];
  __shared__ float Bsm[16][65];
  int t = threadIdx.x;
  int tx = t & 15, ty = t >> 4;
  int n0 = blockIdx.x * 64, m0 = blockIdx.y * 64;
  float acc[4][4] = {};
  for (int k0 = 0; k0 < K; k0 += 16) {
#pragma unroll
    for (int e = 0; e < 4; ++e) {
      int idx = t + e * 256;
      int mi = idx >> 4, ki = idx & 15;
      int m = m0 + mi, kk = k0 + ki;
      Asm[ki][mi] = (m < M && kk < K) ? A[(long)m * lda + kk] : 0.f;
      int n = n0 + mi;
      Bsm[ki][mi] = (n < N && kk < K) ? Bm[(long)n * ldb + kk] : 0.f;
    }
    __syncthreads();
#pragma unroll
    for (int kk = 0; kk < 16; ++kk) {
      float a[4], b[4];
#pragma unroll
      for (int i = 0; i < 4; ++i) a[i] = Asm[kk][ty + 16 * i];
#pragma unroll
      for (int j = 0; j < 4; ++j) b[j] = Bsm[kk][tx + 16 * j];
#pragma unroll
      for (int i = 0; i < 4; ++i)
#pragma unroll
        for (int j = 0; j < 4; ++j) acc[i][j] = fmaf(a[i], b[j], acc[i][j]);
    }
    __syncthreads();
  }
#pragma unroll
  for (int i = 0; i < 4; ++i) {
    int m = m0 + ty + 16 * i;
    if (m >= M) continue;
#pragma unroll
    for (int j = 0; j < 4; ++j) {
      int n = n0 + tx + 16 * j;
      if (n >= N) continue;
      float v = acc[i][j] * alpha;
      if (bias) v += bias[n];
      if (ACT == 2) v = fmaxf(v, 0.f);
      C[(long)m * ldc + n] = v;
    }
  }
}

// ---------------- convert fp32 -> bf16 (hi [+ lo]) -------------------------
__global__ __launch_bounds__(256) void convsplit(const float* __restrict__ in,
                                                 u16* __restrict__ oh,
                                                 u16* __restrict__ ol, int n) {
  int i = blockIdx.x * 256 + threadIdx.x;
  if (i >= n) return;
  float v = in[i];
  u16 h = f2bf(v);
  oh[i] = h;
  if (ol) ol[i] = f2bf(v - bf2f(h));
}

// ---------------- prior: per-(b,l) block, all 8 heads; h = hi+lo -----------
__global__ __launch_bounds__(256) void prior2_kernel(
    const u16* __restrict__ hh, const u16* __restrict__ hl,
    const float* __restrict__ sw, const float* __restrict__ sb,
    float* __restrict__ out) {
  __shared__ float sm[4];
  int bl = blockIdx.x;
  int l = bl & 255, b = bl >> 8;
  int t = threadIdx.x;
  long base = (long)bl * 512;
  float h0 = bf2f(hh[base + t]) + bf2f(hl[base + t]);
  float h1 = bf2f(hh[base + t + 256]) + bf2f(hl[base + t + 256]);
  float d = (float)(l - t);
  float d2 = d * d;
  for (int hd = 0; hd < 8; ++hd) {
    const float* wrow = sw + hd * 512;
    float part = h0 * wrow[t] + h1 * wrow[t + 256];
    float sig = blockReduceSum(part, sm) + sb[hd];
    sig = 1.f / (1.f + expf(-5.f * sig));
    sig += 1e-5f;
    sig = expf(sig * 1.0986122886681098f) - 1.f;
    float coef = 0.3989422804014327f / sig;
    float c2 = -0.5f / (sig * sig);
    out[((long)(b * 8 + hd) * 256 + l) * 256 + t] = coef * expf(c2 * d2);
  }
}

// --------- residual + layernorm: h (hi/lo) + r(fp32) -> hi/lo [+ fp32] -----
__global__ __launch_bounds__(256) void ln2_kernel(
    const u16* __restrict__ ah, const u16* __restrict__ al,
    const float* __restrict__ r, const float* __restrict__ gg,
    const float* __restrict__ be, u16* __restrict__ oh, u16* __restrict__ ol,
    float* __restrict__ ofp) {
  __shared__ float sm[4];
  long row = blockIdx.x;
  int t = threadIdx.x;
  long base = row * D_;
  float x0 = bf2f(ah[base + t]) + bf2f(al[base + t]);
  float x1 = bf2f(ah[base + t + 256]) + bf2f(al[base + t + 256]);
  if (r) {
    x0 += r[base + t];
    x1 += r[base + t + 256];
  }
  float mean = blockReduceSum(x0 + x1, sm) * (1.f / D_);
  float d0 = x0 - mean, d1 = x1 - mean;
  float var = blockReduceSum(d0 * d0 + d1 * d1, sm) * (1.f / D_);
  float rstd = rsqrtf(var + 1e-5f);
  float v0 = d0 * rstd * gg[t] + be[t];
  float v1 = d1 * rstd * gg[t + 256] + be[t + 256];
  if (oh) {
    u16 h0 = f2bf(v0), h1 = f2bf(v1);
    oh[base + t] = h0;
    oh[base + t + 256] = h1;
    ol[base + t] = f2bf(v0 - bf2f(h0));
    ol[base + t + 256] = f2bf(v1 - bf2f(h1));
  }
  if (ofp) {
    ofp[base + t] = v0;
    ofp[base + t + 256] = v1;
  }
}

// ---------------- embedding: circular conv1d + PE -> bf16 hi/lo ------------
__global__ __launch_bounds__(256) void embed_kernel(
    const float* __restrict__ x, const float* __restrict__ tw,
    u16* __restrict__ oh, u16* __restrict__ ol) {
  __shared__ float xs[18][56];
  int bi = blockIdx.x;
  int lt = (bi & 15) * 16;
  int b = bi >> 4;
  int t = threadIdx.x;
  for (int idx = t; idx < 18 * 55; idx += 256) {
    int rr = idx / 55, cc = idx % 55;
    int gl = (lt + rr - 1 + L_) & (L_ - 1);
    xs[rr][cc] = x[(long)(b * L_ + gl) * C_ + cc];
  }
  __syncthreads();
  for (int dp = 0; dp < 2; ++dp) {
    int d = t + dp * 256;
    float acc[16] = {};
    const float* wr = tw + (long)d * (C_ * 3);
    for (int c = 0; c < C_; ++c) {
#pragma unroll
      for (int w = 0; w < 3; ++w) {
        float wv = wr[c * 3 + w];
#pragma unroll
        for (int l = 0; l < 16; ++l) acc[l] = fmaf(xs[l + w][c], wv, acc[l]);
      }
    }
    float ang_scale = expf(-(float)(d & ~1) * 0.017988946039015984f);
#pragma unroll
    for (int l = 0; l < 16; ++l) {
      float ang = (float)(lt + l) * ang_scale;
      float pe = (d & 1) ? cosf(ang) : sinf(ang);
      float v = acc[l] + pe;
      long idx = (long)(b * L_ + lt + l) * D_ + d;
      u16 h = f2bf(v);
      oh[idx] = h;
      ol[idx] = f2bf(v - bf2f(h));
    }
  }
}

extern "C" void kernel_launch(void* const* d_in, const int* in_sizes, int n_in,
                              void* d_out, int out_size, void* d_ws,
                              size_t ws_size, hipStream_t stream) {
  (void)in_sizes; (void)n_in; (void)out_size; (void)ws_size;
  const float* x = (const float*)d_in[0];
  const float* tok_w = (const float*)d_in[1];
  const float* qkv_w = (const float*)d_in[2];
  const float* qkv_b = (const float*)d_in[3];
  const float* sig_w = (const float*)d_in[4];
  const float* sig_b = (const float*)d_in[5];
  const float* out_w = (const float*)d_in[6];
  const float* out_b = (const float*)d_in[7];
  const float* c1w = (const float*)d_in[8];
  const float* c1b = (const float*)d_in[9];
  const float* c2w = (const float*)d_in[10];
  const float* c2b = (const float*)d_in[11];
  const float* ln1g = (const float*)d_in[12];
  const float* ln1b = (const float*)d_in[13];
  const float* ln2g = (const float*)d_in[14];
  const float* ln2b = (const float*)d_in[15];
  const float* lnfg = (const float*)d_in[16];
  const float* lnfb = (const float*)d_in[17];
  const float* latw = (const float*)d_in[18];
  const float* latb = (const float*)d_in[19];
  const float* d1w = (const float*)d_in[20];
  const float* d1b = (const float*)d_in[21];
  const float* d2w = (const float*)d_in[22];
  const float* d2b = (const float*)d_in[23];
  float* out = (float*)d_out;

  const long BLD = (long)B_ * L_ * D_;         // 4194304
  const long CHUNK = (long)B_ * H_ * L_ * L_;  // 16777216
  const long SER_OFF = (long)B_ * L_ * C_;
  const long PRI_OFF = SER_OFF + NL_ * CHUNK;
  const long Z_OFF = PRI_OFF + NL_ * CHUNK;
  const int M = B_ * L_;  // 8192
  const int DD = D_ * D_;

  char* wp = (char*)d_ws;
  auto alloc = [&](size_t bytes) {
    char* p = wp;
    wp += (bytes + 255) & ~(size_t)255;
    return p;
  };
  u16* hh = (u16*)alloc(BLD * 2);
  u16* hl = (u16*)alloc(BLD * 2);
  float* tb = (float*)alloc(BLD * 4);
  u16* qkh = (u16*)alloc(BLD * 4);  // (M,1024); also FFN-y hi; also dec fp32
  u16* qkl = (u16*)alloc(BLD * 4);  // (M,1024); also FFN-y lo
  u16* vth = (u16*)alloc(BLD * 2);
  u16* vtl = (u16*)alloc(BLD * 2);
  u16* pvh = (u16*)alloc(BLD * 2);
  u16* pvl = (u16*)alloc(BLD * 2);
  u16* wqkvh = (u16*)alloc((size_t)NL_ * 3 * DD * 2);
  u16* wqkvl = (u16*)alloc((size_t)NL_ * 3 * DD * 2);
  u16* woh = (u16*)alloc((size_t)NL_ * DD * 2);
  u16* wol = (u16*)alloc((size_t)NL_ * DD * 2);
  u16* c1h = (u16*)alloc((size_t)NL_ * DD * 2);
  u16* c1l = (u16*)alloc((size_t)NL_ * DD * 2);
  u16* c2h = (u16*)alloc((size_t)NL_ * DD * 2);
  u16* c2l = (u16*)alloc((size_t)NL_ * DD * 2);

  int nqkv = NL_ * 3 * DD;
  convsplit<<<(nqkv + 255) / 256, 256, 0, stream>>>(qkv_w, wqkvh, wqkvl, nqkv);
  convsplit<<<(NL_ * DD + 255) / 256, 256, 0, stream>>>(out_w, woh, wol, NL_ * DD);
  convsplit<<<(NL_ * DD + 255) / 256, 256, 0, stream>>>(c1w, c1h, c1l, NL_ * DD);
  convsplit<<<(NL_ * DD + 255) / 256, 256, 0, stream>>>(c2w, c2h, c2l, NL_ * DD);

  embed_kernel<<<B_ * 16, 256, 0, stream>>>(x, tok_w, hh, hl);

  for (int i = 0; i < NL_; ++i) {
    const long ofQK = (long)(i * 3) * DD, ofV = (long)(i * 3 + 2) * DD;
    // merged q,k projection: (M,1024), split in + split out
    mgemm<2, 2, true, 0, 2><<<dim3(8, 64), 256, 0, stream>>>(
        hh, hl, wqkvh + ofQK, wqkvl + ofQK, qkv_b + (long)i * 3 * D_, nullptr,
        qkh, qkl, D_, D_, D_, 2 * D_, 1.f);
    // v transposed split: vt(d, m) = Wv @ h^T (bias folded into PV epilogue)
    mgemm<2, 1, true, 0, 2><<<dim3(128, 4), 128, 0, stream>>>(
        wqkvh + ofV, wqkvl + ofV, hh, hl, nullptr, nullptr, vth, vtl, D_, D_,
        D_, M, 1.f);
    prior2_kernel<<<M, 256, 0, stream>>>(hh, hl, sig_w + (long)i * H_ * D_,
                                         sig_b + i * H_,
                                         out + PRI_OFF + i * CHUNK);
    fused_attn<<<dim3(4, 256), 256, 0, stream>>>(
        qkh, qkl, vth, vtl, qkv_b + (long)(i * 3 + 2) * D_,
        out + SER_OFF + i * CHUNK, pvh, pvl);
    // out projection, full split (fp32 out)
    mgemm<2, 1, true, 0, 0><<<dim3(8, 64), 128, 0, stream>>>(
        pvh, pvl, woh + (long)i * DD, wol + (long)i * DD, out_b + i * D_, tb,
        nullptr, nullptr, D_, D_, D_, D_, 1.f);
    ln2_kernel<<<M, 256, 0, stream>>>(hh, hl, tb, ln1g + i * D_, ln1b + i * D_,
                                      hh, hl, nullptr);
    // FFN, full split (intermediate y hi/lo reuses qkh/qkl)
    mgemm<2, 1, true, 1, 2><<<dim3(8, 64), 128, 0, stream>>>(
        hh, hl, c1h + (long)i * DD, c1l + (long)i * DD, c1b + i * DF_, nullptr,
        qkh, qkl, D_, D_, D_, DF_, 1.f);
    mgemm<2, 1, true, 0, 0><<<dim3(8, 64), 128, 0, stream>>>(
        qkh, qkl, c2h + (long)i * DD, c2l + (long)i * DD, c2b + i * D_, tb,
        nullptr, nullptr, DF_, DF_, DF_, D_, 1.f);
    ln2_kernel<<<M, 256, 0, stream>>>(hh, hl, tb, ln2g + i * D_, ln2b + i * D_,
                                      hh, hl, nullptr);
  }
  ln2_kernel<<<M, 256, 0, stream>>>(hh, hl, nullptr, lnfg, lnfb, nullptr,
                                    nullptr, tb);
  float* dec = (float*)qkh;  // 16MB fp32 scratch (qk dead)
  gemm_kernel<0><<<dim3(1, M / 64), 256, 0, stream>>>(
      tb, latw, latb, out + Z_OFF, M, Z_, D_, D_, D_, Z_, 1.f);
  gemm_kernel<2><<<dim3(8, M / 64), 256, 0, stream>>>(
      out + Z_OFF, d1w, d1b, dec, M, D_, Z_, Z_, Z_, D_, 1.f);
  gemm_kernel<0><<<dim3(1, M / 64), 256, 0, stream>>>(
      dec, d2w, d2b, out, M, C_, D_, D_, D_, C_, 1.f);
}

// Round 5
// 1102.920 us; speedup vs baseline: 1.1834x; 1.1834x over previous
//
#include <hip/hip_runtime.h>
#include <math.h>

#define B_ 32
#define L_ 256
#define C_ 55
#define D_ 512
#define H_ 8
#define NL_ 3
#define DF_ 512
#define Z_ 16
#define DK_ 64

typedef unsigned short u16;
typedef __attribute__((ext_vector_type(8))) short bf16x8;
typedef __attribute__((ext_vector_type(8))) _Float16 f16x8;
typedef __attribute__((ext_vector_type(4))) float f32x4;

__device__ __forceinline__ float bf2f(u16 u) {
  unsigned v = ((unsigned)u) << 16;
  return __builtin_bit_cast(float, v);
}
__device__ __forceinline__ u16 f2bf(float f) {
  unsigned u = __builtin_bit_cast(unsigned, f);
  u += 0x7fffu + ((u >> 16) & 1u);
  return (u16)(u >> 16);
}
__device__ __forceinline__ u16 f2h(float f) {
  _Float16 h = (_Float16)f;
  return __builtin_bit_cast(u16, h);
}
__device__ __forceinline__ void gload16(const void* g, void* l) {
  __builtin_amdgcn_global_load_lds(
      (const __attribute__((address_space(1))) unsigned*)g,
      (__attribute__((address_space(3))) unsigned*)l, 16, 0, 0);
}

// ================= MFMA GEMM: C = act(alpha * A @ B^T + bias) ==============
// PREC: 1 = bf16x3 split (3 passes), 2 = fp16 single pass.
// OUT: 0 fp32, 1 bf16, 2 bf16 hi/lo split, 3 fp16. ACT: 0 none, 1 exact gelu.
template <int WM, int WN, int PREC, int ACT, int OUT>
__global__ __launch_bounds__(WM * WN * 64) void mgemm(
    const u16* __restrict__ Ah, const u16* __restrict__ Al,
    const u16* __restrict__ Bh, const u16* __restrict__ Bl,
    const float* __restrict__ bias, float* __restrict__ Cf,
    u16* __restrict__ Ch, u16* __restrict__ Cl, int K, int lda, int ldb,
    int ldc, float alpha) {
  constexpr bool SPLIT = (PREC == 1);
  constexpr int BM = WM * 64, BN = WN * 64, T = WM * WN * 64;
  __shared__ __align__(16) short As[BM * 32];
  __shared__ __align__(16) short Bs[BN * 32];
  __shared__ __align__(16) short Als[SPLIT ? BM * 32 : 8];
  __shared__ __align__(16) short Bls[SPLIT ? BN * 32 : 8];
  const int t = threadIdx.x, lane = t & 63, w = t >> 6;
  const int wm = w / WN, wn = w % WN;
  const long m0 = (long)blockIdx.y * BM, n0 = (long)blockIdx.x * BN;
  const char* Ab = (const char*)(Ah + m0 * lda);
  const char* Bb = (const char*)(Bh + n0 * ldb);
  const char* Alb = SPLIT ? (const char*)(Al + m0 * lda) : nullptr;
  const char* Blb = SPLIT ? (const char*)(Bl + n0 * ldb) : nullptr;
  const int fr = lane & 15, gq = lane >> 4;
  const int aoff = ((wm * 64 + fr) * 64 + gq * 16) >> 1;
  const int boff = ((wn * 64 + fr) * 64 + gq * 16) >> 1;
  const long lda2 = (long)lda * 2, ldb2 = (long)ldb * 2;
  f32x4 acc[4][4] = {};
  for (int k0 = 0; k0 < K; k0 += 32) {
    const long kb = (long)k0 * 2;
#pragma unroll
    for (int e = 0; e < BM * 4; e += T) {
      int d = (e + t) * 16;
      long src = (long)(d >> 6) * lda2 + kb + (d & 63);
      gload16(Ab + src, (char*)As + d);
      if (SPLIT) gload16(Alb + src, (char*)Als + d);
    }
#pragma unroll
    for (int e = 0; e < BN * 4; e += T) {
      int d = (e + t) * 16;
      long src = (long)(d >> 6) * ldb2 + kb + (d & 63);
      gload16(Bb + src, (char*)Bs + d);
      if (SPLIT) gload16(Blb + src, (char*)Bls + d);
    }
    __syncthreads();
    bf16x8 a[4], b[4], a2[4], b2[4];
#pragma unroll
    for (int m = 0; m < 4; ++m) {
      a[m] = *(const bf16x8*)(As + aoff + m * 512);
      if (SPLIT) a2[m] = *(const bf16x8*)(Als + aoff + m * 512);
    }
#pragma unroll
    for (int n = 0; n < 4; ++n) {
      b[n] = *(const bf16x8*)(Bs + boff + n * 512);
      if (SPLIT) b2[n] = *(const bf16x8*)(Bls + boff + n * 512);
    }
#pragma unroll
    for (int m = 0; m < 4; ++m)
#pragma unroll
      for (int n = 0; n < 4; ++n) {
        if (PREC == 2) {
          acc[m][n] = __builtin_amdgcn_mfma_f32_16x16x32_f16(
              __builtin_bit_cast(f16x8, a[m]), __builtin_bit_cast(f16x8, b[n]),
              acc[m][n], 0, 0, 0);
        } else {
          if (SPLIT) {
            acc[m][n] = __builtin_amdgcn_mfma_f32_16x16x32_bf16(
                a2[m], b[n], acc[m][n], 0, 0, 0);
            acc[m][n] = __builtin_amdgcn_mfma_f32_16x16x32_bf16(
                a[m], b2[n], acc[m][n], 0, 0, 0);
          }
          acc[m][n] = __builtin_amdgcn_mfma_f32_16x16x32_bf16(a[m], b[n],
                                                              acc[m][n], 0, 0, 0);
        }
      }
    __syncthreads();
  }
#pragma unroll
  for (int m = 0; m < 4; ++m) {
    long mg = m0 + wm * 64 + m * 16 + gq * 4;
#pragma unroll
    for (int n = 0; n < 4; ++n) {
      long ng = n0 + wn * 64 + n * 16 + fr;
      float bv = bias ? bias[ng] : 0.f;
#pragma unroll
      for (int r = 0; r < 4; ++r) {
        float v = acc[m][n][r] * alpha + bv;
        if (ACT == 1) v = 0.5f * v * (1.f + erff(v * 0.70710678118654752f));
        long idx = (mg + r) * ldc + ng;
        if (OUT == 0) Cf[idx] = v;
        if (OUT == 1 || OUT == 2) {
          u16 hv = f2bf(v);
          Ch[idx] = hv;
          if (OUT == 2) Cl[idx] = f2bf(v - bf2f(hv));
        }
        if (OUT == 3) Ch[idx] = f2h(v);
      }
    }
  }
}

// =============== fused attention: scores+softmax+series+PV =================
// grid (L/64, B*H), 256 threads. Q,K from merged qk buffers (ld=1024):
// q cols [0,512), k cols [512,1024). vt16 is (512, M) fp16. pv16 (M,512) fp16.
__global__ __launch_bounds__(256, 2) void fused_attn(
    const u16* __restrict__ qkh, const u16* __restrict__ qkl,
    const u16* __restrict__ vt16, const float* __restrict__ vbias,
    float* __restrict__ ser, u16* __restrict__ pv16) {
  __shared__ __align__(16) char smem[53248];
  char* Kreg = smem;                       // 32KB: K staging / P matrix (fp16)
  char* Qreg = smem + 32768;               // Q hi+lo (18.4KB) / V half (16KB)
  float* rowred = (float*)(smem + 51200);  // [4][64][2]
  const int t = threadIdx.x, lane = t & 63, w = t >> 6;
  const int fr = lane & 15, gq = lane >> 4;
  const int r0 = blockIdx.x * 64;
  const int bh = blockIdx.y, b = bh >> 3, h = bh & 7;
  const long qrow0 = (long)b * 256 + r0;
  const long krow0 = (long)b * 256;
  // ---- stage Q (rows r0..+63, 64 cols), layout [64][72] shorts, hi+lo
  {
    const char* qs = (const char*)qkh + qrow0 * 2048 + h * 128;
    const char* ql = (const char*)qkl + qrow0 * 2048 + h * 128;
#pragma unroll
    for (int j = 0; j < 2; ++j) {
      int id = t + j * 256;
      int row = id >> 3, c = id & 7;
      bf16x8 vh = *(const bf16x8*)(qs + (long)row * 2048 + c * 16);
      bf16x8 vl = *(const bf16x8*)(ql + (long)row * 2048 + c * 16);
      *(bf16x8*)(Qreg + row * 144 + c * 16) = vh;
      *(bf16x8*)(Qreg + 9216 + row * 144 + c * 16) = vl;
    }
  }
  // ---- stage Kh full (256x64) with chunk-xor swizzle
  const char* kbh = (const char*)qkh + krow0 * 2048 + 1024 + h * 128;
  const char* kbl = (const char*)qkl + krow0 * 2048 + 1024 + h * 128;
#pragma unroll
  for (int j = 0; j < 8; ++j) {
    int id = t + j * 256;
    int row = id >> 3, c = (id & 7) ^ (row & 7);
    gload16(kbh + (long)row * 2048 + c * 16, Kreg + id * 16);
  }
  __syncthreads();
  f32x4 acc[4][4] = {};
  // ---- phase A: ql*kh + qh*kh
#pragma unroll
  for (int ks = 0; ks < 2; ++ks) {
    bf16x8 ah[4], al[4], bk[4];
#pragma unroll
    for (int m = 0; m < 4; ++m) {
      int qb = (m * 16 + fr) * 144 + gq * 16 + ks * 64;
      ah[m] = *(const bf16x8*)(Qreg + qb);
      al[m] = *(const bf16x8*)(Qreg + 9216 + qb);
    }
#pragma unroll
    for (int n = 0; n < 4; ++n) {
      int row = w * 64 + n * 16 + fr;
      bk[n] = *(const bf16x8*)(Kreg + row * 128 +
                               ((gq * 16 + ks * 64) ^ ((row & 7) << 4)));
    }
#pragma unroll
    for (int m = 0; m < 4; ++m)
#pragma unroll
      for (int n = 0; n < 4; ++n) {
        acc[m][n] =
            __builtin_amdgcn_mfma_f32_16x16x32_bf16(al[m], bk[n], acc[m][n], 0, 0, 0);
        acc[m][n] =
            __builtin_amdgcn_mfma_f32_16x16x32_bf16(ah[m], bk[n], acc[m][n], 0, 0, 0);
      }
  }
  __syncthreads();
  // ---- restage Kl
#pragma unroll
  for (int j = 0; j < 8; ++j) {
    int id = t + j * 256;
    int row = id >> 3, c = (id & 7) ^ (row & 7);
    gload16(kbl + (long)row * 2048 + c * 16, Kreg + id * 16);
  }
  __syncthreads();
  // ---- phase B: qh*kl
#pragma unroll
  for (int ks = 0; ks < 2; ++ks) {
    bf16x8 ah[4], bk[4];
#pragma unroll
    for (int m = 0; m < 4; ++m)
      ah[m] = *(const bf16x8*)(Qreg + (m * 16 + fr) * 144 + gq * 16 + ks * 64);
#pragma unroll
    for (int n = 0; n < 4; ++n) {
      int row = w * 64 + n * 16 + fr;
      bk[n] = *(const bf16x8*)(Kreg + row * 128 +
                               ((gq * 16 + ks * 64) ^ ((row & 7) << 4)));
    }
#pragma unroll
    for (int m = 0; m < 4; ++m)
#pragma unroll
      for (int n = 0; n < 4; ++n)
        acc[m][n] =
            __builtin_amdgcn_mfma_f32_16x16x32_bf16(ah[m], bk[n], acc[m][n], 0, 0, 0);
  }
  // ---- softmax: scale, wave-local max/sum, one cross-wave LDS round
#pragma unroll
  for (int m = 0; m < 4; ++m)
#pragma unroll
    for (int n = 0; n < 4; ++n) acc[m][n] *= 0.125f;
  float lmax[4][4], lsum[4][4];
#pragma unroll
  for (int m = 0; m < 4; ++m)
#pragma unroll
    for (int r = 0; r < 4; ++r) {
      float v = fmaxf(fmaxf(acc[m][0][r], acc[m][1][r]),
                      fmaxf(acc[m][2][r], acc[m][3][r]));
#pragma unroll
      for (int off = 8; off > 0; off >>= 1) v = fmaxf(v, __shfl_xor(v, off, 64));
      lmax[m][r] = v;
    }
#pragma unroll
  for (int m = 0; m < 4; ++m)
#pragma unroll
    for (int n = 0; n < 4; ++n)
#pragma unroll
      for (int r = 0; r < 4; ++r)
        acc[m][n][r] = __expf(acc[m][n][r] - lmax[m][r]);
#pragma unroll
  for (int m = 0; m < 4; ++m)
#pragma unroll
    for (int r = 0; r < 4; ++r) {
      float s = acc[m][0][r] + acc[m][1][r] + acc[m][2][r] + acc[m][3][r];
#pragma unroll
      for (int off = 8; off > 0; off >>= 1) s += __shfl_xor(s, off, 64);
      lsum[m][r] = s;
    }
  if (fr == 0) {
#pragma unroll
    for (int m = 0; m < 4; ++m)
#pragma unroll
      for (int r = 0; r < 4; ++r) {
        int row = m * 16 + gq * 4 + r;
        rowred[(w * 64 + row) * 2] = lmax[m][r];
        rowred[(w * 64 + row) * 2 + 1] = lsum[m][r];
      }
  }
  __syncthreads();
  float scale[4][4];
#pragma unroll
  for (int m = 0; m < 4; ++m)
#pragma unroll
    for (int r = 0; r < 4; ++r) {
      int row = m * 16 + gq * 4 + r;
      float g = -1e30f, tot = 0.f;
      float2 pr[4];
#pragma unroll
      for (int ww = 0; ww < 4; ++ww) {
        pr[ww] = *(const float2*)&rowred[(ww * 64 + row) * 2];
        g = fmaxf(g, pr[ww].x);
      }
#pragma unroll
      for (int ww = 0; ww < 4; ++ww) tot += pr[ww].y * __expf(pr[ww].x - g);
      scale[m][r] = __expf(lmax[m][r] - g) / tot;
    }
  // ---- issue V half0 loads (d rows 0..31, fp16) into Qreg (Q is dead)
  const char* vtb = (const char*)vt16 + ((long)h * 64 * 8192 + krow0) * 2;
#pragma unroll
  for (int j = 0; j < 4; ++j) {
    int id = t + j * 256;
    int row = id >> 5, c = (id & 31) ^ (row & 7);
    gload16(vtb + (long)row * 16384 + c * 16, Qreg + id * 16);
  }
  // ---- write series (fp32, global) + P (fp16, swizzled LDS @ Kreg)
  float* serb = ser + ((long)bh * 256 + r0) * 256 + w * 64;
#pragma unroll
  for (int m = 0; m < 4; ++m)
#pragma unroll
    for (int n = 0; n < 4; ++n)
#pragma unroll
      for (int r = 0; r < 4; ++r) {
        int row = m * 16 + gq * 4 + r, col = n * 16 + fr;
        float p = acc[m][n][r] * scale[m][r];
        serb[(long)row * 256 + col] = p;
        int pb = row * 512 + (((w * 64 + col) * 2) ^ ((row & 7) << 4));
        *(u16*)(Kreg + pb) = f2h(p);
      }
  __syncthreads();  // drains V half0 + P visible
  // ---- PV in two d-halves, fp16 single pass
#pragma unroll
  for (int half = 0; half < 2; ++half) {
    if (half) {
      __syncthreads();  // all half0 reads done
#pragma unroll
      for (int j = 0; j < 4; ++j) {
        int id = t + j * 256;
        int row = id >> 5, c = (id & 31) ^ (row & 7);
        gload16(vtb + (long)(32 + row) * 16384 + c * 16, Qreg + id * 16);
      }
      __syncthreads();  // drain
    }
    f32x4 acc2[2] = {};
#pragma unroll
    for (int ks = 0; ks < 8; ++ks) {
      int arow = w * 16 + fr;
      f16x8 pa = *(const f16x8*)(
          Kreg + arow * 512 + ((gq * 16 + ks * 64) ^ ((arow & 7) << 4)));
#pragma unroll
      for (int n = 0; n < 2; ++n) {
        int vrow = n * 16 + fr;
        int vo = vrow * 512 + ((gq * 16 + ks * 64) ^ ((vrow & 7) << 4));
        f16x8 vb = *(const f16x8*)(Qreg + vo);
        acc2[n] = __builtin_amdgcn_mfma_f32_16x16x32_f16(pa, vb, acc2[n], 0, 0, 0);
      }
    }
#pragma unroll
    for (int n = 0; n < 2; ++n) {
#pragma unroll
      for (int r = 0; r < 4; ++r) {
        int gcol = h * 64 + half * 32 + n * 16 + fr;
        long gm = qrow0 + w * 16 + gq * 4 + r;
        pv16[gm * 512 + gcol] = f2h(acc2[n][r] + vbias[gcol]);
      }
    }
  }
}

// ---------------- fp32 tiled GEMM (small decoder GEMMs only) ---------------
template <int ACT>
__global__ __launch_bounds__(256) void gemm_kernel(
    const float* __restrict__ A, const float* __restrict__ Bm,
    const float* __restrict__ bias, float* __restrict__ C, int M, int N, int K,
    int lda, int ldb, int ldc, float alpha) {
  __shared__ float Asm[16][65];
  __shared__ float Bsm[16][65];
  int t = threadIdx.x;
  int tx = t & 15, ty = t >> 4;
  int n0 = blockIdx.x * 64, m0 = blockIdx.y * 64;
  float acc[4][4] = {};
  for (int k0 = 0; k0 < K; k0 += 16) {
#pragma unroll
    for (int e = 0; e < 4; ++e) {
      int idx = t + e * 256;
      int mi = idx >> 4, ki = idx & 15;
      int m = m0 + mi, kk = k0 + ki;
      Asm[ki][mi] = (m < M && kk < K) ? A[(long)m * lda + kk] : 0.f;
      int n = n0 + mi;
      Bsm[ki][mi] = (n < N && kk < K) ? Bm[(long)n * ldb + kk] : 0.f;
    }
    __syncthreads();
#pragma unroll
    for (int kk = 0; kk < 16; ++kk) {
      float a[4], b[4];
#pragma unroll
      for (int i = 0; i < 4; ++i) a[i] = Asm[kk][ty + 16 * i];
#pragma unroll
      for (int j = 0; j < 4; ++j) b[j] = Bsm[kk][tx + 16 * j];
#pragma unroll
      for (int i = 0; i < 4; ++i)
#pragma unroll
        for (int j = 0; j < 4; ++j) acc[i][j] = fmaf(a[i], b[j], acc[i][j]);
    }
    __syncthreads();
  }
#pragma unroll
  for (int i = 0; i < 4; ++i) {
    int m = m0 + ty + 16 * i;
    if (m >= M) continue;
#pragma unroll
    for (int j = 0; j < 4; ++j) {
      int n = n0 + tx + 16 * j;
      if (n >= N) continue;
      float v = acc[i][j] * alpha;
      if (bias) v += bias[n];
      if (ACT == 2) v = fmaxf(v, 0.f);
      C[(long)m * ldc + n] = v;
    }
  }
}

// ---------------- weight conversions ---------------------------------------
__global__ __launch_bounds__(256) void convsplit(const float* __restrict__ in,
                                                 u16* __restrict__ oh,
                                                 u16* __restrict__ ol, int n) {
  int i = blockIdx.x * 256 + threadIdx.x;
  if (i >= n) return;
  float v = in[i];
  u16 h = f2bf(v);
  oh[i] = h;
  if (ol) ol[i] = f2bf(v - bf2f(h));
}
__global__ __launch_bounds__(256) void conv16(const float* __restrict__ in,
                                              u16* __restrict__ o, int n) {
  int i = blockIdx.x * 256 + threadIdx.x;
  if (i >= n) return;
  o[i] = f2h(in[i]);
}

// ---------------- prior: per-(b,l) block, all 8 heads batched --------------
__global__ __launch_bounds__(256) void prior2_kernel(
    const u16* __restrict__ hh, const u16* __restrict__ hl,
    const float* __restrict__ sw, const float* __restrict__ sb,
    float* __restrict__ out) {
  __shared__ float sm[4][8];
  int bl = blockIdx.x;
  int l = bl & 255, b = bl >> 8;
  int t = threadIdx.x;
  long base = (long)bl * 512;
  float h0 = bf2f(hh[base + t]) + bf2f(hl[base + t]);
  float h1 = bf2f(hh[base + t + 256]) + bf2f(hl[base + t + 256]);
  float part[8];
#pragma unroll
  for (int hd = 0; hd < 8; ++hd) {
    const float* wrow = sw + hd * 512;
    part[hd] = h0 * wrow[t] + h1 * wrow[t + 256];
  }
#pragma unroll
  for (int off = 32; off > 0; off >>= 1)
#pragma unroll
    for (int hd = 0; hd < 8; ++hd) part[hd] += __shfl_xor(part[hd], off, 64);
  int wid = t >> 6;
  if ((t & 63) == 0) {
#pragma unroll
    for (int hd = 0; hd < 8; ++hd) sm[wid][hd] = part[hd];
  }
  __syncthreads();
  float d = (float)(l - t);
  float d2 = d * d;
  long obase = ((long)b * 8 * 256 + l) * 256 + t;
#pragma unroll
  for (int hd = 0; hd < 8; ++hd) {
    float sig = sm[0][hd] + sm[1][hd] + sm[2][hd] + sm[3][hd] + sb[hd];
    sig = 1.f / (1.f + expf(-5.f * sig));
    sig += 1e-5f;
    sig = expf(sig * 1.0986122886681098f) - 1.f;
    float coef = 0.3989422804014327f / sig;
    float c2 = -0.5f / (sig * sig);
    out[obase + (long)hd * 65536] = coef * expf(c2 * d2);
  }
}

// --------- residual + LN: h (hi/lo) + r(fp32) -> bf16 hi/lo + fp16 [+fp32] -
__global__ __launch_bounds__(256) void ln2_kernel(
    const u16* __restrict__ ah, const u16* __restrict__ al,
    const float* __restrict__ r, const float* __restrict__ gg,
    const float* __restrict__ be, u16* __restrict__ oh, u16* __restrict__ ol,
    u16* __restrict__ o16, float* __restrict__ ofp) {
  __shared__ float smw[4];
  long row = blockIdx.x;
  int t = threadIdx.x;
  long base = row * D_;
  float x0 = bf2f(ah[base + t]) + bf2f(al[base + t]);
  float x1 = bf2f(ah[base + t + 256]) + bf2f(al[base + t + 256]);
  if (r) {
    x0 += r[base + t];
    x1 += r[base + t + 256];
  }
  float v = x0 + x1;
#pragma unroll
  for (int off = 32; off > 0; off >>= 1) v += __shfl_xor(v, off, 64);
  if ((t & 63) == 0) smw[t >> 6] = v;
  __syncthreads();
  float mean = (smw[0] + smw[1] + smw[2] + smw[3]) * (1.f / D_);
  __syncthreads();
  float d0 = x0 - mean, d1 = x1 - mean;
  float vv = d0 * d0 + d1 * d1;
#pragma unroll
  for (int off = 32; off > 0; off >>= 1) vv += __shfl_xor(vv, off, 64);
  if ((t & 63) == 0) smw[t >> 6] = vv;
  __syncthreads();
  float var = (smw[0] + smw[1] + smw[2] + smw[3]) * (1.f / D_);
  float rstd = rsqrtf(var + 1e-5f);
  float v0 = d0 * rstd * gg[t] + be[t];
  float v1 = d1 * rstd * gg[t + 256] + be[t + 256];
  if (oh) {
    u16 h0 = f2bf(v0), h1 = f2bf(v1);
    oh[base + t] = h0;
    oh[base + t + 256] = h1;
    ol[base + t] = f2bf(v0 - bf2f(h0));
    ol[base + t + 256] = f2bf(v1 - bf2f(h1));
  }
  if (o16) {
    o16[base + t] = f2h(v0);
    o16[base + t + 256] = f2h(v1);
  }
  if (ofp) {
    ofp[base + t] = v0;
    ofp[base + t + 256] = v1;
  }
}

// ---------------- embedding: circular conv1d + PE -> bf16 hi/lo + fp16 -----
__global__ __launch_bounds__(256) void embed_kernel(
    const float* __restrict__ x, const float* __restrict__ tw,
    u16* __restrict__ oh, u16* __restrict__ ol, u16* __restrict__ o16) {
  __shared__ float xs[18][56];
  int bi = blockIdx.x;
  int lt = (bi & 15) * 16;
  int b = bi >> 4;
  int t = threadIdx.x;
  for (int idx = t; idx < 18 * 55; idx += 256) {
    int rr = idx / 55, cc = idx % 55;
    int gl = (lt + rr - 1 + L_) & (L_ - 1);
    xs[rr][cc] = x[(long)(b * L_ + gl) * C_ + cc];
  }
  __syncthreads();
  for (int dp = 0; dp < 2; ++dp) {
    int d = t + dp * 256;
    float acc[16] = {};
    const float* wr = tw + (long)d * (C_ * 3);
    for (int c = 0; c < C_; ++c) {
#pragma unroll
      for (int w = 0; w < 3; ++w) {
        float wv = wr[c * 3 + w];
#pragma unroll
        for (int l = 0; l < 16; ++l) acc[l] = fmaf(xs[l + w][c], wv, acc[l]);
      }
    }
    float ang_scale = expf(-(float)(d & ~1) * 0.017988946039015984f);
#pragma unroll
    for (int l = 0; l < 16; ++l) {
      float ang = (float)(lt + l) * ang_scale;
      float pe = (d & 1) ? cosf(ang) : sinf(ang);
      float v = acc[l] + pe;
      long idx = (long)(b * L_ + lt + l) * D_ + d;
      u16 h = f2bf(v);
      oh[idx] = h;
      ol[idx] = f2bf(v - bf2f(h));
      o16[idx] = f2h(v);
    }
  }
}

extern "C" void kernel_launch(void* const* d_in, const int* in_sizes, int n_in,
                              void* d_out, int out_size, void* d_ws,
                              size_t ws_size, hipStream_t stream) {
  (void)in_sizes; (void)n_in; (void)out_size; (void)ws_size;
  const float* x = (const float*)d_in[0];
  const float* tok_w = (const float*)d_in[1];
  const float* qkv_w = (const float*)d_in[2];
  const float* qkv_b = (const float*)d_in[3];
  const float* sig_w = (const float*)d_in[4];
  const float* sig_b = (const float*)d_in[5];
  const float* out_w = (const float*)d_in[6];
  const float* out_b = (const float*)d_in[7];
  const float* c1w = (const float*)d_in[8];
  const float* c1b = (const float*)d_in[9];
  const float* c2w = (const float*)d_in[10];
  const float* c2b = (const float*)d_in[11];
  const float* ln1g = (const float*)d_in[12];
  const float* ln1b = (const float*)d_in[13];
  const float* ln2g = (const float*)d_in[14];
  const float* ln2b = (const float*)d_in[15];
  const float* lnfg = (const float*)d_in[16];
  const float* lnfb = (const float*)d_in[17];
  const float* latw = (const float*)d_in[18];
  const float* latb = (const float*)d_in[19];
  const float* d1w = (const float*)d_in[20];
  const float* d1b = (const float*)d_in[21];
  const float* d2w = (const float*)d_in[22];
  const float* d2b = (const float*)d_in[23];
  float* out = (float*)d_out;

  const long BLD = (long)B_ * L_ * D_;         // 4194304
  const long CHUNK = (long)B_ * H_ * L_ * L_;  // 16777216
  const long SER_OFF = (long)B_ * L_ * C_;
  const long PRI_OFF = SER_OFF + NL_ * CHUNK;
  const long Z_OFF = PRI_OFF + NL_ * CHUNK;
  const int M = B_ * L_;  // 8192
  const int DD = D_ * D_;

  char* wp = (char*)d_ws;
  auto alloc = [&](size_t bytes) {
    char* p = wp;
    wp += (bytes + 255) & ~(size_t)255;
    return p;
  };
  u16* hh = (u16*)alloc(BLD * 2);
  u16* hl = (u16*)alloc(BLD * 2);
  u16* h16 = (u16*)alloc(BLD * 2);
  float* tb = (float*)alloc(BLD * 4);
  u16* qkh = (u16*)alloc(BLD * 4);  // (M,1024); reused as y16 / dec fp32
  u16* qkl = (u16*)alloc(BLD * 4);  // (M,1024)
  u16* vt16 = (u16*)alloc(BLD * 2);
  u16* pv16 = (u16*)alloc(BLD * 2);
  u16* wqkvh = (u16*)alloc((size_t)NL_ * 3 * DD * 2);
  u16* wqkvl = (u16*)alloc((size_t)NL_ * 3 * DD * 2);
  u16* wv16 = (u16*)alloc((size_t)NL_ * DD * 2);
  u16* wo16 = (u16*)alloc((size_t)NL_ * DD * 2);
  u16* c116 = (u16*)alloc((size_t)NL_ * DD * 2);
  u16* c216 = (u16*)alloc((size_t)NL_ * DD * 2);

  int nqkv = NL_ * 3 * DD;
  convsplit<<<(nqkv + 255) / 256, 256, 0, stream>>>(qkv_w, wqkvh, wqkvl, nqkv);
  for (int i = 0; i < NL_; ++i)
    conv16<<<DD / 256, 256, 0, stream>>>(qkv_w + (long)(i * 3 + 2) * DD,
                                         wv16 + (long)i * DD, DD);
  conv16<<<NL_ * DD / 256, 256, 0, stream>>>(out_w, wo16, NL_ * DD);
  conv16<<<NL_ * DD / 256, 256, 0, stream>>>(c1w, c116, NL_ * DD);
  conv16<<<NL_ * DD / 256, 256, 0, stream>>>(c2w, c216, NL_ * DD);

  embed_kernel<<<B_ * 16, 256, 0, stream>>>(x, tok_w, hh, hl, h16);

  for (int i = 0; i < NL_; ++i) {
    const long ofQK = (long)(i * 3) * DD;
    // merged q,k projection: (M,1024), bf16 split in + split out
    mgemm<2, 2, 1, 0, 2><<<dim3(8, 64), 256, 0, stream>>>(
        hh, hl, wqkvh + ofQK, wqkvl + ofQK, qkv_b + (long)i * 3 * D_, nullptr,
        qkh, qkl, D_, D_, D_, 2 * D_, 1.f);
    // v transposed fp16: vt(d, m) = Wv @ h^T (bias folded into PV epilogue)
    mgemm<2, 2, 2, 0, 3><<<dim3(64, 4), 256, 0, stream>>>(
        wv16 + (long)i * DD, nullptr, h16, nullptr, nullptr, nullptr, vt16,
        nullptr, D_, D_, D_, M, 1.f);
    prior2_kernel<<<M, 256, 0, stream>>>(hh, hl, sig_w + (long)i * H_ * D_,
                                         sig_b + i * H_,
                                         out + PRI_OFF + i * CHUNK);
    fused_attn<<<dim3(4, 256), 256, 0, stream>>>(
        qkh, qkl, vt16, qkv_b + (long)(i * 3 + 2) * D_,
        out + SER_OFF + i * CHUNK, pv16);
    // out projection fp16 single (fp32 out)
    mgemm<2, 2, 2, 0, 0><<<dim3(4, 64), 256, 0, stream>>>(
        pv16, nullptr, wo16 + (long)i * DD, nullptr, out_b + i * D_, tb,
        nullptr, nullptr, D_, D_, D_, D_, 1.f);
    ln2_kernel<<<M, 256, 0, stream>>>(hh, hl, tb, ln1g + i * D_, ln1b + i * D_,
                                      hh, hl, h16, nullptr);
    // FFN fp16 single (intermediate y16 reuses qkh)
    u16* y16 = qkh;
    mgemm<2, 2, 2, 1, 3><<<dim3(4, 64), 256, 0, stream>>>(
        h16, nullptr, c116 + (long)i * DD, nullptr, c1b + i * DF_, nullptr,
        y16, nullptr, D_, D_, D_, DF_, 1.f);
    mgemm<2, 2, 2, 0, 0><<<dim3(4, 64), 256, 0, stream>>>(
        y16, nullptr, c216 + (long)i * DD, nullptr, c2b + i * D_, tb, nullptr,
        nullptr, DF_, DF_, DF_, D_, 1.f);
    ln2_kernel<<<M, 256, 0, stream>>>(hh, hl, tb, ln2g + i * D_, ln2b + i * D_,
                                      hh, hl, h16, nullptr);
  }
  ln2_kernel<<<M, 256, 0, stream>>>(hh, hl, nullptr, lnfg, lnfb, nullptr,
                                    nullptr, nullptr, tb);
  float* dec = (float*)qkh;  // 16MB fp32 scratch (qk dead)
  gemm_kernel<0><<<dim3(1, M / 64), 256, 0, stream>>>(
      tb, latw, latb, out + Z_OFF, M, Z_, D_, D_, D_, Z_, 1.f);
  gemm_kernel<2><<<dim3(8, M / 64), 256, 0, stream>>>(
      out + Z_OFF, d1w, d1b, dec, M, D_, Z_, Z_, Z_, D_, 1.f);
  gemm_kernel<0><<<dim3(1, M / 64), 256, 0, stream>>>(
      dec, d2w, d2b, out, M, C_, D_, D_, D_, C_, 1.f);
}

// Round 6
// 1001.160 us; speedup vs baseline: 1.3037x; 1.1016x over previous
//
#include <hip/hip_runtime.h>
#include <math.h>

#define B_ 32
#define L_ 256
#define C_ 55
#define D_ 512
#define H_ 8
#define NL_ 3
#define DF_ 512
#define Z_ 16
#define DK_ 64

typedef unsigned short u16;
typedef __attribute__((ext_vector_type(8))) short s16x8;
typedef __attribute__((ext_vector_type(8))) _Float16 f16x8;
typedef __attribute__((ext_vector_type(4))) float f32x4;

__device__ __forceinline__ u16 f2h(float f) {
  _Float16 h = (_Float16)f;
  return __builtin_bit_cast(u16, h);
}
__device__ __forceinline__ void gload16(const void* g, void* l) {
  __builtin_amdgcn_global_load_lds(
      (const __attribute__((address_space(1))) unsigned*)g,
      (__attribute__((address_space(3))) unsigned*)l, 16, 0, 0);
}

// ================= fp16 MFMA GEMM: C = act(A @ B^T + bias) =================
// A: (M,K) fp16 row-major; B: (N,K) fp16 row-major.
// OUT: 0 fp32, 1 fp16. ACT: 0 none, 1 exact gelu.
template <int WM, int WN, int ACT, int OUT>
__global__ __launch_bounds__(WM * WN * 64) void mgemm(
    const u16* __restrict__ A16, const u16* __restrict__ B16,
    const float* __restrict__ bias, float* __restrict__ Cf,
    u16* __restrict__ C16, int K, int lda, int ldb, int ldc) {
  constexpr int BM = WM * 64, BN = WN * 64, T = WM * WN * 64;
  __shared__ __align__(16) short As[BM * 32];
  __shared__ __align__(16) short Bs[BN * 32];
  const int t = threadIdx.x, lane = t & 63, w = t >> 6;
  const int wm = w / WN, wn = w % WN;
  const long m0 = (long)blockIdx.y * BM, n0 = (long)blockIdx.x * BN;
  const char* Ab = (const char*)(A16 + m0 * lda);
  const char* Bb = (const char*)(B16 + n0 * ldb);
  const int fr = lane & 15, gq = lane >> 4;
  const int aoff = ((wm * 64 + fr) * 64 + gq * 16) >> 1;
  const int boff = ((wn * 64 + fr) * 64 + gq * 16) >> 1;
  const long lda2 = (long)lda * 2, ldb2 = (long)ldb * 2;
  f32x4 acc[4][4] = {};
  for (int k0 = 0; k0 < K; k0 += 32) {
    const long kb = (long)k0 * 2;
#pragma unroll
    for (int e = 0; e < BM * 4; e += T) {
      int d = (e + t) * 16;
      gload16(Ab + (long)(d >> 6) * lda2 + kb + (d & 63), (char*)As + d);
    }
#pragma unroll
    for (int e = 0; e < BN * 4; e += T) {
      int d = (e + t) * 16;
      gload16(Bb + (long)(d >> 6) * ldb2 + kb + (d & 63), (char*)Bs + d);
    }
    __syncthreads();
    f16x8 a[4], b[4];
#pragma unroll
    for (int m = 0; m < 4; ++m) a[m] = *(const f16x8*)(As + aoff + m * 512);
#pragma unroll
    for (int n = 0; n < 4; ++n) b[n] = *(const f16x8*)(Bs + boff + n * 512);
#pragma unroll
    for (int m = 0; m < 4; ++m)
#pragma unroll
      for (int n = 0; n < 4; ++n)
        acc[m][n] =
            __builtin_amdgcn_mfma_f32_16x16x32_f16(a[m], b[n], acc[m][n], 0, 0, 0);
    __syncthreads();
  }
#pragma unroll
  for (int m = 0; m < 4; ++m) {
    long mg = m0 + wm * 64 + m * 16 + gq * 4;
#pragma unroll
    for (int n = 0; n < 4; ++n) {
      long ng = n0 + wn * 64 + n * 16 + fr;
      float bv = bias ? bias[ng] : 0.f;
#pragma unroll
      for (int r = 0; r < 4; ++r) {
        float v = acc[m][n][r] + bv;
        if (ACT == 1) v = 0.5f * v * (1.f + erff(v * 0.70710678118654752f));
        long idx = (mg + r) * ldc + ng;
        if (OUT == 0) Cf[idx] = v;
        if (OUT == 1) C16[idx] = f2h(v);
      }
    }
  }
}

// =============== fused attention: scores+softmax+series+PV =================
// grid (L/64, B*H), 256 threads. Q,K from merged qk16 (ld=1024 shorts):
// q cols [0,512), k cols [512,1024). vt16 is (512, M) fp16. pv16 (M,512) fp16.
__global__ __launch_bounds__(256, 2) void fused_attn(
    const u16* __restrict__ qk16, const u16* __restrict__ vt16,
    const float* __restrict__ vbias, float* __restrict__ ser,
    u16* __restrict__ pv16) {
  __shared__ __align__(16) char smem[51200];
  char* Kreg = smem;                       // 32KB: K staging / P matrix (fp16)
  char* Vreg = smem + 32768;               // 16KB: Q stage (9.2KB) / V half
  float* rowred = (float*)(smem + 49152);  // [4][64][2]
  const int t = threadIdx.x, lane = t & 63, w = t >> 6;
  const int fr = lane & 15, gq = lane >> 4;
  const int r0 = blockIdx.x * 64;
  const int bh = blockIdx.y, b = bh >> 3, h = bh & 7;
  const long qrow0 = (long)b * 256 + r0;
  const long krow0 = (long)b * 256;
  // ---- stage Q (rows r0..+63, 64 cols fp16), layout row stride 144B
  {
    const char* qs = (const char*)qk16 + qrow0 * 2048 + h * 128;
#pragma unroll
    for (int j = 0; j < 2; ++j) {
      int id = t + j * 256;
      int row = id >> 3, c = id & 7;
      *(s16x8*)(Vreg + row * 144 + c * 16) =
          *(const s16x8*)(qs + (long)row * 2048 + c * 16);
    }
  }
  // ---- stage K full (256x64 fp16) with chunk-xor swizzle
  const char* kb = (const char*)qk16 + krow0 * 2048 + 1024 + h * 128;
#pragma unroll
  for (int j = 0; j < 8; ++j) {
    int id = t + j * 256;
    int row = id >> 3, c = (id & 7) ^ (row & 7);
    gload16(kb + (long)row * 2048 + c * 16, Kreg + id * 16);
  }
  __syncthreads();
  f32x4 acc[4][4] = {};
  // ---- QK^T single pass fp16
#pragma unroll
  for (int ks = 0; ks < 2; ++ks) {
    f16x8 aq[4], bk[4];
#pragma unroll
    for (int m = 0; m < 4; ++m)
      aq[m] = *(const f16x8*)(Vreg + (m * 16 + fr) * 144 + gq * 16 + ks * 64);
#pragma unroll
    for (int n = 0; n < 4; ++n) {
      int row = w * 64 + n * 16 + fr;
      bk[n] = *(const f16x8*)(Kreg + row * 128 +
                              ((gq * 16 + ks * 64) ^ ((row & 7) << 4)));
    }
#pragma unroll
    for (int m = 0; m < 4; ++m)
#pragma unroll
      for (int n = 0; n < 4; ++n)
        acc[m][n] =
            __builtin_amdgcn_mfma_f32_16x16x32_f16(aq[m], bk[n], acc[m][n], 0, 0, 0);
  }
  // ---- softmax: scale, wave-local max/sum, one cross-wave LDS round
#pragma unroll
  for (int m = 0; m < 4; ++m)
#pragma unroll
    for (int n = 0; n < 4; ++n) acc[m][n] *= 0.125f;
  float lmax[4][4], lsum[4][4];
#pragma unroll
  for (int m = 0; m < 4; ++m)
#pragma unroll
    for (int r = 0; r < 4; ++r) {
      float v = fmaxf(fmaxf(acc[m][0][r], acc[m][1][r]),
                      fmaxf(acc[m][2][r], acc[m][3][r]));
#pragma unroll
      for (int off = 8; off > 0; off >>= 1) v = fmaxf(v, __shfl_xor(v, off, 64));
      lmax[m][r] = v;
    }
#pragma unroll
  for (int m = 0; m < 4; ++m)
#pragma unroll
    for (int n = 0; n < 4; ++n)
#pragma unroll
      for (int r = 0; r < 4; ++r)
        acc[m][n][r] = __expf(acc[m][n][r] - lmax[m][r]);
#pragma unroll
  for (int m = 0; m < 4; ++m)
#pragma unroll
    for (int r = 0; r < 4; ++r) {
      float s = acc[m][0][r] + acc[m][1][r] + acc[m][2][r] + acc[m][3][r];
#pragma unroll
      for (int off = 8; off > 0; off >>= 1) s += __shfl_xor(s, off, 64);
      lsum[m][r] = s;
    }
  if (fr == 0) {
#pragma unroll
    for (int m = 0; m < 4; ++m)
#pragma unroll
      for (int r = 0; r < 4; ++r) {
        int row = m * 16 + gq * 4 + r;
        rowred[(w * 64 + row) * 2] = lmax[m][r];
        rowred[(w * 64 + row) * 2 + 1] = lsum[m][r];
      }
  }
  __syncthreads();
  float scale[4][4];
#pragma unroll
  for (int m = 0; m < 4; ++m)
#pragma unroll
    for (int r = 0; r < 4; ++r) {
      int row = m * 16 + gq * 4 + r;
      float g = -1e30f, tot = 0.f;
      float2 pr[4];
#pragma unroll
      for (int ww = 0; ww < 4; ++ww) {
        pr[ww] = *(const float2*)&rowred[(ww * 64 + row) * 2];
        g = fmaxf(g, pr[ww].x);
      }
#pragma unroll
      for (int ww = 0; ww < 4; ++ww) tot += pr[ww].y * __expf(pr[ww].x - g);
      scale[m][r] = __expf(lmax[m][r] - g) / tot;
    }
  // ---- issue V half0 loads (d rows 0..31, fp16) into Vreg (Q is dead)
  const char* vtb = (const char*)vt16 + ((long)h * 64 * 8192 + krow0) * 2;
#pragma unroll
  for (int j = 0; j < 4; ++j) {
    int id = t + j * 256;
    int row = id >> 5, c = (id & 31) ^ (row & 7);
    gload16(vtb + (long)row * 16384 + c * 16, Vreg + id * 16);
  }
  // ---- write series (fp32, global) + P (fp16, swizzled LDS @ Kreg)
  float* serb = ser + ((long)bh * 256 + r0) * 256 + w * 64;
#pragma unroll
  for (int m = 0; m < 4; ++m)
#pragma unroll
    for (int n = 0; n < 4; ++n)
#pragma unroll
      for (int r = 0; r < 4; ++r) {
        int row = m * 16 + gq * 4 + r, col = n * 16 + fr;
        float p = acc[m][n][r] * scale[m][r];
        serb[(long)row * 256 + col] = p;
        int pb = row * 512 + (((w * 64 + col) * 2) ^ ((row & 7) << 4));
        *(u16*)(Kreg + pb) = f2h(p);
      }
  __syncthreads();  // drains V half0 + P visible
  // ---- PV in two d-halves, fp16 single pass
#pragma unroll
  for (int half = 0; half < 2; ++half) {
    if (half) {
      __syncthreads();  // all half0 reads done
#pragma unroll
      for (int j = 0; j < 4; ++j) {
        int id = t + j * 256;
        int row = id >> 5, c = (id & 31) ^ (row & 7);
        gload16(vtb + (long)(32 + row) * 16384 + c * 16, Vreg + id * 16);
      }
      __syncthreads();  // drain
    }
    f32x4 acc2[2] = {};
#pragma unroll
    for (int ks = 0; ks < 8; ++ks) {
      int arow = w * 16 + fr;
      f16x8 pa = *(const f16x8*)(
          Kreg + arow * 512 + ((gq * 16 + ks * 64) ^ ((arow & 7) << 4)));
#pragma unroll
      for (int n = 0; n < 2; ++n) {
        int vrow = n * 16 + fr;
        int vo = vrow * 512 + ((gq * 16 + ks * 64) ^ ((vrow & 7) << 4));
        f16x8 vb = *(const f16x8*)(Vreg + vo);
        acc2[n] = __builtin_amdgcn_mfma_f32_16x16x32_f16(pa, vb, acc2[n], 0, 0, 0);
      }
    }
#pragma unroll
    for (int n = 0; n < 2; ++n) {
#pragma unroll
      for (int r = 0; r < 4; ++r) {
        int gcol = h * 64 + half * 32 + n * 16 + fr;
        long gm = qrow0 + w * 16 + gq * 4 + r;
        pv16[gm * 512 + gcol] = f2h(acc2[n][r] + vbias[gcol]);
      }
    }
  }
}

// ---------------- fp32 tiled GEMM (small decoder GEMMs only) ---------------
template <int ACT>
__global__ __launch_bounds__(256) void gemm_kernel(
    const float* __restrict__ A, const float* __restrict__ Bm,
    const float* __restrict__ bias, float* __restrict__ C, int M, int N, int K,
    int lda, int ldb, int ldc) {
  __shared__ float Asm[16][65];
  __shared__ float Bsm[16][65];
  int t = threadIdx.x;
  int tx = t & 15, ty = t >> 4;
  int n0 = blockIdx.x * 64, m0 = blockIdx.y * 64;
  float acc[4][4] = {};
  for (int k0 = 0; k0 < K; k0 += 16) {
#pragma unroll
    for (int e = 0; e < 4; ++e) {
      int idx = t + e * 256;
      int mi = idx >> 4, ki = idx & 15;
      int m = m0 + mi, kk = k0 + ki;
      Asm[ki][mi] = (m < M && kk < K) ? A[(long)m * lda + kk] : 0.f;
      int n = n0 + mi;
      Bsm[ki][mi] = (n < N && kk < K) ? Bm[(long)n * ldb + kk] : 0.f;
    }
    __syncthreads();
#pragma unroll
    for (int kk = 0; kk < 16; ++kk) {
      float a[4], b[4];
#pragma unroll
      for (int i = 0; i < 4; ++i) a[i] = Asm[kk][ty + 16 * i];
#pragma unroll
      for (int j = 0; j < 4; ++j) b[j] = Bsm[kk][tx + 16 * j];
#pragma unroll
      for (int i = 0; i < 4; ++i)
#pragma unroll
        for (int j = 0; j < 4; ++j) acc[i][j] = fmaf(a[i], b[j], acc[i][j]);
    }
    __syncthreads();
  }
#pragma unroll
  for (int i = 0; i < 4; ++i) {
    int m = m0 + ty + 16 * i;
    if (m >= M) continue;
#pragma unroll
    for (int j = 0; j < 4; ++j) {
      int n = n0 + tx + 16 * j;
      if (n >= N) continue;
      float v = acc[i][j];
      if (bias) v += bias[n];
      if (ACT == 2) v = fmaxf(v, 0.f);
      C[(long)m * ldc + n] = v;
    }
  }
}

// ---------------- weight conversion fp32 -> fp16 ---------------------------
__global__ __launch_bounds__(256) void conv16(const float* __restrict__ in,
                                              u16* __restrict__ o, int n) {
  int i = blockIdx.x * 256 + threadIdx.x;
  if (i >= n) return;
  o[i] = f2h(in[i]);
}

// ---------------- prior: per-(b,l) block, all 8 heads batched --------------
__global__ __launch_bounds__(256) void prior2_kernel(
    const float* __restrict__ hbuf, const float* __restrict__ sw,
    const float* __restrict__ sb, float* __restrict__ out) {
  __shared__ float sm[4][8];
  int bl = blockIdx.x;
  int l = bl & 255, b = bl >> 8;
  int t = threadIdx.x;
  const float* hrow = hbuf + (long)bl * 512;
  float h0 = hrow[t], h1 = hrow[t + 256];
  float part[8];
#pragma unroll
  for (int hd = 0; hd < 8; ++hd) {
    const float* wrow = sw + hd * 512;
    part[hd] = h0 * wrow[t] + h1 * wrow[t + 256];
  }
#pragma unroll
  for (int off = 32; off > 0; off >>= 1)
#pragma unroll
    for (int hd = 0; hd < 8; ++hd) part[hd] += __shfl_xor(part[hd], off, 64);
  int wid = t >> 6;
  if ((t & 63) == 0) {
#pragma unroll
    for (int hd = 0; hd < 8; ++hd) sm[wid][hd] = part[hd];
  }
  __syncthreads();
  float d = (float)(l - t);
  float d2 = d * d;
  long obase = ((long)b * 8 * 256 + l) * 256 + t;
#pragma unroll
  for (int hd = 0; hd < 8; ++hd) {
    float sig = sm[0][hd] + sm[1][hd] + sm[2][hd] + sm[3][hd] + sb[hd];
    sig = 1.f / (1.f + expf(-5.f * sig));
    sig += 1e-5f;
    sig = expf(sig * 1.0986122886681098f) - 1.f;
    float coef = 0.3989422804014327f / sig;
    float c2 = -0.5f / (sig * sig);
    out[obase + (long)hd * 65536] = coef * expf(c2 * d2);
  }
}

// --------- residual + LN: a(fp32) + r(fp32) -> fp32 [+ fp16] ---------------
__global__ __launch_bounds__(256) void ln2_kernel(
    const float* __restrict__ a, const float* __restrict__ r,
    const float* __restrict__ gg, const float* __restrict__ be,
    float* __restrict__ ofp, u16* __restrict__ o16) {
  __shared__ float smw[4];
  long base = (long)blockIdx.x * D_;
  int t = threadIdx.x;
  float x0 = a[base + t], x1 = a[base + t + 256];
  if (r) {
    x0 += r[base + t];
    x1 += r[base + t + 256];
  }
  float v = x0 + x1;
#pragma unroll
  for (int off = 32; off > 0; off >>= 1) v += __shfl_xor(v, off, 64);
  if ((t & 63) == 0) smw[t >> 6] = v;
  __syncthreads();
  float mean = (smw[0] + smw[1] + smw[2] + smw[3]) * (1.f / D_);
  __syncthreads();
  float d0 = x0 - mean, d1 = x1 - mean;
  float vv = d0 * d0 + d1 * d1;
#pragma unroll
  for (int off = 32; off > 0; off >>= 1) vv += __shfl_xor(vv, off, 64);
  if ((t & 63) == 0) smw[t >> 6] = vv;
  __syncthreads();
  float var = (smw[0] + smw[1] + smw[2] + smw[3]) * (1.f / D_);
  float rstd = rsqrtf(var + 1e-5f);
  float v0 = d0 * rstd * gg[t] + be[t];
  float v1 = d1 * rstd * gg[t + 256] + be[t + 256];
  ofp[base + t] = v0;
  ofp[base + t + 256] = v1;
  if (o16) {
    o16[base + t] = f2h(v0);
    o16[base + t + 256] = f2h(v1);
  }
}

// ---------------- embedding: circular conv1d + PE -> fp32 + fp16 -----------
__global__ __launch_bounds__(256) void embed_kernel(
    const float* __restrict__ x, const float* __restrict__ tw,
    float* __restrict__ ofp, u16* __restrict__ o16) {
  __shared__ float xs[18][56];
  int bi = blockIdx.x;
  int lt = (bi & 15) * 16;
  int b = bi >> 4;
  int t = threadIdx.x;
  for (int idx = t; idx < 18 * 55; idx += 256) {
    int rr = idx / 55, cc = idx % 55;
    int gl = (lt + rr - 1 + L_) & (L_ - 1);
    xs[rr][cc] = x[(long)(b * L_ + gl) * C_ + cc];
  }
  __syncthreads();
  for (int dp = 0; dp < 2; ++dp) {
    int d = t + dp * 256;
    float acc[16] = {};
    const float* wr = tw + (long)d * (C_ * 3);
    for (int c = 0; c < C_; ++c) {
#pragma unroll
      for (int w = 0; w < 3; ++w) {
        float wv = wr[c * 3 + w];
#pragma unroll
        for (int l = 0; l < 16; ++l) acc[l] = fmaf(xs[l + w][c], wv, acc[l]);
      }
    }
    float ang_scale = expf(-(float)(d & ~1) * 0.017988946039015984f);
#pragma unroll
    for (int l = 0; l < 16; ++l) {
      float ang = (float)(lt + l) * ang_scale;
      float pe = (d & 1) ? cosf(ang) : sinf(ang);
      float v = acc[l] + pe;
      long idx = (long)(b * L_ + lt + l) * D_ + d;
      ofp[idx] = v;
      o16[idx] = f2h(v);
    }
  }
}

extern "C" void kernel_launch(void* const* d_in, const int* in_sizes, int n_in,
                              void* d_out, int out_size, void* d_ws,
                              size_t ws_size, hipStream_t stream) {
  (void)in_sizes; (void)n_in; (void)out_size; (void)ws_size;
  const float* x = (const float*)d_in[0];
  const float* tok_w = (const float*)d_in[1];
  const float* qkv_w = (const float*)d_in[2];
  const float* qkv_b = (const float*)d_in[3];
  const float* sig_w = (const float*)d_in[4];
  const float* sig_b = (const float*)d_in[5];
  const float* out_w = (const float*)d_in[6];
  const float* out_b = (const float*)d_in[7];
  const float* c1w = (const float*)d_in[8];
  const float* c1b = (const float*)d_in[9];
  const float* c2w = (const float*)d_in[10];
  const float* c2b = (const float*)d_in[11];
  const float* ln1g = (const float*)d_in[12];
  const float* ln1b = (const float*)d_in[13];
  const float* ln2g = (const float*)d_in[14];
  const float* ln2b = (const float*)d_in[15];
  const float* lnfg = (const float*)d_in[16];
  const float* lnfb = (const float*)d_in[17];
  const float* latw = (const float*)d_in[18];
  const float* latb = (const float*)d_in[19];
  const float* d1w = (const float*)d_in[20];
  const float* d1b = (const float*)d_in[21];
  const float* d2w = (const float*)d_in[22];
  const float* d2b = (const float*)d_in[23];
  float* out = (float*)d_out;

  const long BLD = (long)B_ * L_ * D_;         // 4194304
  const long CHUNK = (long)B_ * H_ * L_ * L_;  // 16777216
  const long SER_OFF = (long)B_ * L_ * C_;
  const long PRI_OFF = SER_OFF + NL_ * CHUNK;
  const long Z_OFF = PRI_OFF + NL_ * CHUNK;
  const int M = B_ * L_;  // 8192
  const int DD = D_ * D_;

  char* wp = (char*)d_ws;
  auto alloc = [&](size_t bytes) {
    char* p = wp;
    wp += (bytes + 255) & ~(size_t)255;
    return p;
  };
  float* h32 = (float*)alloc(BLD * 4);
  u16* h16 = (u16*)alloc(BLD * 2);
  float* tb = (float*)alloc(BLD * 4);
  u16* qk16 = (u16*)alloc(BLD * 4);  // (M,1024); reused as y16 / dec fp32
  u16* vt16 = (u16*)alloc(BLD * 2);
  u16* pv16 = (u16*)alloc(BLD * 2);
  u16* wqkv16 = (u16*)alloc((size_t)NL_ * 3 * DD * 2);
  u16* wo16 = (u16*)alloc((size_t)NL_ * DD * 2);
  u16* c116 = (u16*)alloc((size_t)NL_ * DD * 2);
  u16* c216 = (u16*)alloc((size_t)NL_ * DD * 2);

  conv16<<<NL_ * 3 * DD / 256, 256, 0, stream>>>(qkv_w, wqkv16, NL_ * 3 * DD);
  conv16<<<NL_ * DD / 256, 256, 0, stream>>>(out_w, wo16, NL_ * DD);
  conv16<<<NL_ * DD / 256, 256, 0, stream>>>(c1w, c116, NL_ * DD);
  conv16<<<NL_ * DD / 256, 256, 0, stream>>>(c2w, c216, NL_ * DD);

  embed_kernel<<<B_ * 16, 256, 0, stream>>>(x, tok_w, h32, h16);

  for (int i = 0; i < NL_; ++i) {
    const long ofQK = (long)(i * 3) * DD, ofV = (long)(i * 3 + 2) * DD;
    // merged q,k projection: (M,1024) fp16
    mgemm<2, 2, 0, 1><<<dim3(8, 64), 256, 0, stream>>>(
        h16, wqkv16 + ofQK, qkv_b + (long)i * 3 * D_, nullptr, qk16, D_, D_,
        D_, 2 * D_);
    // v transposed fp16: vt(d, m) = Wv @ h^T (bias folded into PV epilogue)
    mgemm<2, 1, 0, 1><<<dim3(128, 4), 128, 0, stream>>>(
        wqkv16 + ofV, h16, nullptr, nullptr, vt16, D_, D_, D_, M);
    prior2_kernel<<<M, 256, 0, stream>>>(h32, sig_w + (long)i * H_ * D_,
                                         sig_b + i * H_,
                                         out + PRI_OFF + i * CHUNK);
    fused_attn<<<dim3(4, 256), 256, 0, stream>>>(
        qk16, vt16, qkv_b + (long)(i * 3 + 2) * D_, out + SER_OFF + i * CHUNK,
        pv16);
    // out projection (fp32 out)
    mgemm<2, 1, 0, 0><<<dim3(8, 64), 128, 0, stream>>>(
        pv16, wo16 + (long)i * DD, out_b + i * D_, tb, nullptr, D_, D_, D_,
        D_);
    ln2_kernel<<<M, 256, 0, stream>>>(h32, tb, ln1g + i * D_, ln1b + i * D_,
                                      h32, h16);
    // FFN (intermediate y16 reuses qk16)
    u16* y16 = qk16;
    mgemm<2, 1, 1, 1><<<dim3(8, 64), 128, 0, stream>>>(
        h16, c116 + (long)i * DD, c1b + i * DF_, nullptr, y16, D_, D_, D_,
        DF_);
    mgemm<2, 1, 0, 0><<<dim3(8, 64), 128, 0, stream>>>(
        y16, c216 + (long)i * DD, c2b + i * D_, tb, nullptr, DF_, DF_, DF_,
        D_);
    ln2_kernel<<<M, 256, 0, stream>>>(h32, tb, ln2g + i * D_, ln2b + i * D_,
                                      h32, h16);
  }
  ln2_kernel<<<M, 256, 0, stream>>>(h32, nullptr, lnfg, lnfb, tb, nullptr);
  float* dec = (float*)qk16;  // 16MB fp32 scratch (qk dead)
  gemm_kernel<0><<<dim3(1, M / 64), 256, 0, stream>>>(
      tb, latw, latb, out + Z_OFF, M, Z_, D_, D_, D_, Z_);
  gemm_kernel<2><<<dim3(8, M / 64), 256, 0, stream>>>(
      out + Z_OFF, d1w, d1b, dec, M, D_, Z_, Z_, Z_, D_);
  gemm_kernel<0><<<dim3(1, M / 64), 256, 0, stream>>>(
      dec, d2w, d2b, out, M, C_, D_, D_, D_, C_);
}

// Round 7
// 979.242 us; speedup vs baseline: 1.3329x; 1.0224x over previous
//
#include <hip/hip_runtime.h>
#include <math.h>

#define B_ 32
#define L_ 256
#define C_ 55
#define D_ 512
#define H_ 8
#define NL_ 3
#define DF_ 512
#define Z_ 16
#define DK_ 64

typedef unsigned short u16;
typedef __attribute__((ext_vector_type(8))) short s16x8;
typedef __attribute__((ext_vector_type(8))) _Float16 f16x8;
typedef __attribute__((ext_vector_type(4))) float f32x4;

__device__ __forceinline__ u16 f2h(float f) {
  _Float16 h = (_Float16)f;
  return __builtin_bit_cast(u16, h);
}
__device__ __forceinline__ void gload16(const void* g, void* l) {
  __builtin_amdgcn_global_load_lds(
      (const __attribute__((address_space(1))) unsigned*)g,
      (__attribute__((address_space(3))) unsigned*)l, 16, 0, 0);
}

// ================= fp16 MFMA GEMM: C = act(A @ B^T + bias) =================
// BK=64, chunk-XOR swizzled LDS (conflict-free ds_read_b128).
// A: (M,K) fp16 row-major; B: (N,K) fp16 row-major. K % 64 == 0.
// OUT: 0 fp32, 1 fp16. ACT: 0 none, 1 exact gelu.
template <int WM, int WN, int ACT, int OUT>
__global__ __launch_bounds__(WM * WN * 64) void mgemm(
    const u16* __restrict__ A16, const u16* __restrict__ B16,
    const float* __restrict__ bias, float* __restrict__ Cf,
    u16* __restrict__ C16, int K, int lda, int ldb, int ldc) {
  constexpr int BM = WM * 64, BN = WN * 64, T = WM * WN * 64;
  constexpr int ACH = BM * 8, BCH = BN * 8;  // 16B chunks per K-tile
  __shared__ __align__(16) char As[BM * 128];
  __shared__ __align__(16) char Bs[BN * 128];
  const int t = threadIdx.x, lane = t & 63, w = t >> 6;
  const int wm = w / WN, wn = w % WN;
  const long m0 = (long)blockIdx.y * BM, n0 = (long)blockIdx.x * BN;
  const char* Ab = (const char*)(A16 + m0 * lda);
  const char* Bb = (const char*)(B16 + n0 * ldb);
  const int fr = lane & 15, gq = lane >> 4;
  const long lda2 = (long)lda * 2, ldb2 = (long)ldb * 2;
  f32x4 acc[4][4] = {};
  for (int k0 = 0; k0 < K; k0 += 64) {
    const long kb = (long)k0 * 2;
#pragma unroll
    for (int e = 0; e < ACH; e += T) {
      int id = e + t;
      int row = id >> 3, c = (id & 7) ^ (row & 7);
      gload16(Ab + (long)row * lda2 + kb + c * 16, As + id * 16);
    }
#pragma unroll
    for (int e = 0; e < BCH; e += T) {
      int id = e + t;
      int row = id >> 3, c = (id & 7) ^ (row & 7);
      gload16(Bb + (long)row * ldb2 + kb + c * 16, Bs + id * 16);
    }
    __syncthreads();
#pragma unroll
    for (int ks = 0; ks < 2; ++ks) {
      f16x8 a[4], b[4];
#pragma unroll
      for (int m = 0; m < 4; ++m) {
        int row = wm * 64 + m * 16 + fr;
        a[m] = *(const f16x8*)(As + row * 128 +
                               ((gq * 16 + ks * 64) ^ ((row & 7) << 4)));
      }
#pragma unroll
      for (int n = 0; n < 4; ++n) {
        int row = wn * 64 + n * 16 + fr;
        b[n] = *(const f16x8*)(Bs + row * 128 +
                               ((gq * 16 + ks * 64) ^ ((row & 7) << 4)));
      }
#pragma unroll
      for (int m = 0; m < 4; ++m)
#pragma unroll
        for (int n = 0; n < 4; ++n)
          acc[m][n] =
              __builtin_amdgcn_mfma_f32_16x16x32_f16(a[m], b[n], acc[m][n], 0, 0, 0);
    }
    __syncthreads();
  }
#pragma unroll
  for (int m = 0; m < 4; ++m) {
    long mg = m0 + wm * 64 + m * 16 + gq * 4;
#pragma unroll
    for (int n = 0; n < 4; ++n) {
      long ng = n0 + wn * 64 + n * 16 + fr;
      float bv = bias ? bias[ng] : 0.f;
#pragma unroll
      for (int r = 0; r < 4; ++r) {
        float v = acc[m][n][r] + bv;
        if (ACT == 1) v = 0.5f * v * (1.f + erff(v * 0.70710678118654752f));
        long idx = (mg + r) * ldc + ng;
        if (OUT == 0) Cf[idx] = v;
        if (OUT == 1) C16[idx] = f2h(v);
      }
    }
  }
}

// =============== fused attention: scores+softmax+series+prior+PV ===========
// grid (L/64, B*H), 256 threads. Q,K from merged qk16 (ld=1024 shorts):
// q cols [0,512), k cols [512,1024). vt16 is (512, M) fp16. pv16 (M,512) fp16.
// coef/c2f: per (bh, l) Gaussian params; prior written alongside series.
__global__ __launch_bounds__(256, 2) void fused_attn(
    const u16* __restrict__ qk16, const u16* __restrict__ vt16,
    const float* __restrict__ vbias, const float* __restrict__ coef,
    const float* __restrict__ c2f, float* __restrict__ ser,
    float* __restrict__ pri, u16* __restrict__ pv16) {
  __shared__ __align__(16) char smem[51200];
  char* Kreg = smem;                       // 32KB: K staging / P matrix (fp16)
  char* Vreg = smem + 32768;               // 16KB: Q stage (9.2KB) / V half
  float* rowred = (float*)(smem + 49152);  // [4][64][2]
  const int t = threadIdx.x, lane = t & 63, w = t >> 6;
  const int fr = lane & 15, gq = lane >> 4;
  const int r0 = blockIdx.x * 64;
  const int bh = blockIdx.y, b = bh >> 3, h = bh & 7;
  const long qrow0 = (long)b * 256 + r0;
  const long krow0 = (long)b * 256;
  // ---- stage Q (rows r0..+63, 64 cols fp16), layout row stride 144B
  {
    const char* qs = (const char*)qk16 + qrow0 * 2048 + h * 128;
#pragma unroll
    for (int j = 0; j < 2; ++j) {
      int id = t + j * 256;
      int row = id >> 3, c = id & 7;
      *(s16x8*)(Vreg + row * 144 + c * 16) =
          *(const s16x8*)(qs + (long)row * 2048 + c * 16);
    }
  }
  // ---- stage K full (256x64 fp16) with chunk-xor swizzle
  const char* kb = (const char*)qk16 + krow0 * 2048 + 1024 + h * 128;
#pragma unroll
  for (int j = 0; j < 8; ++j) {
    int id = t + j * 256;
    int row = id >> 3, c = (id & 7) ^ (row & 7);
    gload16(kb + (long)row * 2048 + c * 16, Kreg + id * 16);
  }
  __syncthreads();
  f32x4 acc[4][4] = {};
  // ---- QK^T single pass fp16
#pragma unroll
  for (int ks = 0; ks < 2; ++ks) {
    f16x8 aq[4], bk[4];
#pragma unroll
    for (int m = 0; m < 4; ++m)
      aq[m] = *(const f16x8*)(Vreg + (m * 16 + fr) * 144 + gq * 16 + ks * 64);
#pragma unroll
    for (int n = 0; n < 4; ++n) {
      int row = w * 64 + n * 16 + fr;
      bk[n] = *(const f16x8*)(Kreg + row * 128 +
                              ((gq * 16 + ks * 64) ^ ((row & 7) << 4)));
    }
#pragma unroll
    for (int m = 0; m < 4; ++m)
#pragma unroll
      for (int n = 0; n < 4; ++n)
        acc[m][n] =
            __builtin_amdgcn_mfma_f32_16x16x32_f16(aq[m], bk[n], acc[m][n], 0, 0, 0);
  }
  // ---- softmax: scale, wave-local max/sum, one cross-wave LDS round
#pragma unroll
  for (int m = 0; m < 4; ++m)
#pragma unroll
    for (int n = 0; n < 4; ++n) acc[m][n] *= 0.125f;
  float lmax[4][4], lsum[4][4];
#pragma unroll
  for (int m = 0; m < 4; ++m)
#pragma unroll
    for (int r = 0; r < 4; ++r) {
      float v = fmaxf(fmaxf(acc[m][0][r], acc[m][1][r]),
                      fmaxf(acc[m][2][r], acc[m][3][r]));
#pragma unroll
      for (int off = 8; off > 0; off >>= 1) v = fmaxf(v, __shfl_xor(v, off, 64));
      lmax[m][r] = v;
    }
#pragma unroll
  for (int m = 0; m < 4; ++m)
#pragma unroll
    for (int n = 0; n < 4; ++n)
#pragma unroll
      for (int r = 0; r < 4; ++r)
        acc[m][n][r] = __expf(acc[m][n][r] - lmax[m][r]);
#pragma unroll
  for (int m = 0; m < 4; ++m)
#pragma unroll
    for (int r = 0; r < 4; ++r) {
      float s = acc[m][0][r] + acc[m][1][r] + acc[m][2][r] + acc[m][3][r];
#pragma unroll
      for (int off = 8; off > 0; off >>= 1) s += __shfl_xor(s, off, 64);
      lsum[m][r] = s;
    }
  if (fr == 0) {
#pragma unroll
    for (int m = 0; m < 4; ++m)
#pragma unroll
      for (int r = 0; r < 4; ++r) {
        int row = m * 16 + gq * 4 + r;
        rowred[(w * 64 + row) * 2] = lmax[m][r];
        rowred[(w * 64 + row) * 2 + 1] = lsum[m][r];
      }
  }
  __syncthreads();
  float scale[4][4];
#pragma unroll
  for (int m = 0; m < 4; ++m)
#pragma unroll
    for (int r = 0; r < 4; ++r) {
      int row = m * 16 + gq * 4 + r;
      float g = -1e30f, tot = 0.f;
      float2 pr[4];
#pragma unroll
      for (int ww = 0; ww < 4; ++ww) {
        pr[ww] = *(const float2*)&rowred[(ww * 64 + row) * 2];
        g = fmaxf(g, pr[ww].x);
      }
#pragma unroll
      for (int ww = 0; ww < 4; ++ww) tot += pr[ww].y * __expf(pr[ww].x - g);
      scale[m][r] = __expf(lmax[m][r] - g) / tot;
    }
  // ---- issue V half0 loads (d rows 0..31, fp16) into Vreg (Q is dead)
  const char* vtb = (const char*)vt16 + ((long)h * 64 * 8192 + krow0) * 2;
#pragma unroll
  for (int j = 0; j < 4; ++j) {
    int id = t + j * 256;
    int row = id >> 5, c = (id & 31) ^ (row & 7);
    gload16(vtb + (long)row * 16384 + c * 16, Vreg + id * 16);
  }
  // ---- write series + prior (fp32, global) + P (fp16, swizzled LDS @ Kreg)
  float* serb = ser + ((long)bh * 256 + r0) * 256 + w * 64;
  float* prib = pri + ((long)bh * 256 + r0) * 256 + w * 64;
  const float* cfb = coef + bh * 256 + r0;
  const float* ccb = c2f + bh * 256 + r0;
#pragma unroll
  for (int m = 0; m < 4; ++m)
#pragma unroll
    for (int r = 0; r < 4; ++r) {
      int row = m * 16 + gq * 4 + r;
      float cf = cfb[row], cc = ccb[row];
      float fl = (float)(r0 + row);
#pragma unroll
      for (int n = 0; n < 4; ++n) {
        int col = n * 16 + fr;
        float p = acc[m][n][r] * scale[m][r];
        serb[(long)row * 256 + col] = p;
        int pb = row * 512 + (((w * 64 + col) * 2) ^ ((row & 7) << 4));
        *(u16*)(Kreg + pb) = f2h(p);
        float dd = fl - (float)(w * 64 + col);
        prib[(long)row * 256 + col] = cf * expf(cc * dd * dd);
      }
    }
  __syncthreads();  // drains V half0 + P visible
  // ---- PV in two d-halves, fp16 single pass
#pragma unroll
  for (int half = 0; half < 2; ++half) {
    if (half) {
      __syncthreads();  // all half0 reads done
#pragma unroll
      for (int j = 0; j < 4; ++j) {
        int id = t + j * 256;
        int row = id >> 5, c = (id & 31) ^ (row & 7);
        gload16(vtb + (long)(32 + row) * 16384 + c * 16, Vreg + id * 16);
      }
      __syncthreads();  // drain
    }
    f32x4 acc2[2] = {};
#pragma unroll
    for (int ks = 0; ks < 8; ++ks) {
      int arow = w * 16 + fr;
      f16x8 pa = *(const f16x8*)(
          Kreg + arow * 512 + ((gq * 16 + ks * 64) ^ ((arow & 7) << 4)));
#pragma unroll
      for (int n = 0; n < 2; ++n) {
        int vrow = n * 16 + fr;
        int vo = vrow * 512 + ((gq * 16 + ks * 64) ^ ((vrow & 7) << 4));
        f16x8 vb = *(const f16x8*)(Vreg + vo);
        acc2[n] = __builtin_amdgcn_mfma_f32_16x16x32_f16(pa, vb, acc2[n], 0, 0, 0);
      }
    }
#pragma unroll
    for (int n = 0; n < 2; ++n) {
#pragma unroll
      for (int r = 0; r < 4; ++r) {
        int gcol = h * 64 + half * 32 + n * 16 + fr;
        long gm = qrow0 + w * 16 + gq * 4 + r;
        pv16[gm * 512 + gcol] = f2h(acc2[n][r] + vbias[gcol]);
      }
    }
  }
}

// ---------------- fp32 tiled GEMM (small decoder GEMMs only) ---------------
template <int ACT>
__global__ __launch_bounds__(256) void gemm_kernel(
    const float* __restrict__ A, const float* __restrict__ Bm,
    const float* __restrict__ bias, float* __restrict__ C, int M, int N, int K,
    int lda, int ldb, int ldc) {
  __shared__ float Asm[16][65];
  __shared__ float Bsm[16][65];
  int t = threadIdx.x;
  int tx = t & 15, ty = t >> 4;
  int n0 = blockIdx.x * 64, m0 = blockIdx.y * 64;
  float acc[4][4] = {};
  for (int k0 = 0; k0 < K; k0 += 16) {
#pragma unroll
    for (int e = 0; e < 4; ++e) {
      int idx = t + e * 256;
      int mi = idx >> 4, ki = idx & 15;
      int m = m0 + mi, kk = k0 + ki;
      Asm[ki][mi] = (m < M && kk < K) ? A[(long)m * lda + kk] : 0.f;
      int n = n0 + mi;
      Bsm[ki][mi] = (n < N && kk < K) ? Bm[(long)n * ldb + kk] : 0.f;
    }
    __syncthreads();
#pragma unroll
    for (int kk = 0; kk < 16; ++kk) {
      float a[4], b[4];
#pragma unroll
      for (int i = 0; i < 4; ++i) a[i] = Asm[kk][ty + 16 * i];
#pragma unroll
      for (int j = 0; j < 4; ++j) b[j] = Bsm[kk][tx + 16 * j];
#pragma unroll
      for (int i = 0; i < 4; ++i)
#pragma unroll
        for (int j = 0; j < 4; ++j) acc[i][j] = fmaf(a[i], b[j], acc[i][j]);
    }
    __syncthreads();
  }
#pragma unroll
  for (int i = 0; i < 4; ++i) {
    int m = m0 + ty + 16 * i;
    if (m >= M) continue;
#pragma unroll
    for (int j = 0; j < 4; ++j) {
      int n = n0 + tx + 16 * j;
      if (n >= N) continue;
      float v = acc[i][j];
      if (bias) v += bias[n];
      if (ACT == 2) v = fmaxf(v, 0.f);
      C[(long)m * ldc + n] = v;
    }
  }
}

// ---------------- weight conversion fp32 -> fp16 ---------------------------
__global__ __launch_bounds__(256) void conv16(const float* __restrict__ in,
                                              u16* __restrict__ o, int n) {
  int i = blockIdx.x * 256 + threadIdx.x;
  if (i >= n) return;
  o[i] = f2h(in[i]);
}

// ---------------- sigma: per-(b,l) block -> Gaussian coef/c2 per head ------
__global__ __launch_bounds__(256) void sigma_kernel(
    const float* __restrict__ hbuf, const float* __restrict__ sw,
    const float* __restrict__ sb, float* __restrict__ coef,
    float* __restrict__ c2f) {
  __shared__ float sm[4][8];
  int bl = blockIdx.x;
  int l = bl & 255, b = bl >> 8;
  int t = threadIdx.x;
  const float* hrow = hbuf + (long)bl * 512;
  float h0 = hrow[t], h1 = hrow[t + 256];
  float part[8];
#pragma unroll
  for (int hd = 0; hd < 8; ++hd) {
    const float* wrow = sw + hd * 512;
    part[hd] = h0 * wrow[t] + h1 * wrow[t + 256];
  }
#pragma unroll
  for (int off = 32; off > 0; off >>= 1)
#pragma unroll
    for (int hd = 0; hd < 8; ++hd) part[hd] += __shfl_xor(part[hd], off, 64);
  int wid = t >> 6;
  if ((t & 63) == 0) {
#pragma unroll
    for (int hd = 0; hd < 8; ++hd) sm[wid][hd] = part[hd];
  }
  __syncthreads();
  if (t < 8) {
    float sig = sm[0][t] + sm[1][t] + sm[2][t] + sm[3][t] + sb[t];
    sig = 1.f / (1.f + expf(-5.f * sig));
    sig += 1e-5f;
    sig = expf(sig * 1.0986122886681098f) - 1.f;
    long idx = ((long)(b * 8 + t) << 8) | l;
    coef[idx] = 0.3989422804014327f / sig;
    c2f[idx] = -0.5f / (sig * sig);
  }
}

// --------- residual + LN: a(fp32) + r(fp32) -> fp32 [+ fp16] ---------------
__global__ __launch_bounds__(256) void ln2_kernel(
    const float* __restrict__ a, const float* __restrict__ r,
    const float* __restrict__ gg, const float* __restrict__ be,
    float* __restrict__ ofp, u16* __restrict__ o16) {
  __shared__ float smw[4];
  long base = (long)blockIdx.x * D_;
  int t = threadIdx.x;
  float x0 = a[base + t], x1 = a[base + t + 256];
  if (r) {
    x0 += r[base + t];
    x1 += r[base + t + 256];
  }
  float v = x0 + x1;
#pragma unroll
  for (int off = 32; off > 0; off >>= 1) v += __shfl_xor(v, off, 64);
  if ((t & 63) == 0) smw[t >> 6] = v;
  __syncthreads();
  float mean = (smw[0] + smw[1] + smw[2] + smw[3]) * (1.f / D_);
  __syncthreads();
  float d0 = x0 - mean, d1 = x1 - mean;
  float vv = d0 * d0 + d1 * d1;
#pragma unroll
  for (int off = 32; off > 0; off >>= 1) vv += __shfl_xor(vv, off, 64);
  if ((t & 63) == 0) smw[t >> 6] = vv;
  __syncthreads();
  float var = (smw[0] + smw[1] + smw[2] + smw[3]) * (1.f / D_);
  float rstd = rsqrtf(var + 1e-5f);
  float v0 = d0 * rstd * gg[t] + be[t];
  float v1 = d1 * rstd * gg[t + 256] + be[t + 256];
  ofp[base + t] = v0;
  ofp[base + t + 256] = v1;
  if (o16) {
    o16[base + t] = f2h(v0);
    o16[base + t + 256] = f2h(v1);
  }
}

// ---------------- embedding: circular conv1d + PE -> fp32 + fp16 -----------
__global__ __launch_bounds__(256) void embed_kernel(
    const float* __restrict__ x, const float* __restrict__ tw,
    float* __restrict__ ofp, u16* __restrict__ o16) {
  __shared__ float xs[18][56];
  int bi = blockIdx.x;
  int lt = (bi & 15) * 16;
  int b = bi >> 4;
  int t = threadIdx.x;
  for (int idx = t; idx < 18 * 55; idx += 256) {
    int rr = idx / 55, cc = idx % 55;
    int gl = (lt + rr - 1 + L_) & (L_ - 1);
    xs[rr][cc] = x[(long)(b * L_ + gl) * C_ + cc];
  }
  __syncthreads();
  for (int dp = 0; dp < 2; ++dp) {
    int d = t + dp * 256;
    float acc[16] = {};
    const float* wr = tw + (long)d * (C_ * 3);
    for (int c = 0; c < C_; ++c) {
#pragma unroll
      for (int w = 0; w < 3; ++w) {
        float wv = wr[c * 3 + w];
#pragma unroll
        for (int l = 0; l < 16; ++l) acc[l] = fmaf(xs[l + w][c], wv, acc[l]);
      }
    }
    float ang_scale = expf(-(float)(d & ~1) * 0.017988946039015984f);
#pragma unroll
    for (int l = 0; l < 16; ++l) {
      float ang = (float)(lt + l) * ang_scale;
      float pe = (d & 1) ? cosf(ang) : sinf(ang);
      float v = acc[l] + pe;
      long idx = (long)(b * L_ + lt + l) * D_ + d;
      ofp[idx] = v;
      o16[idx] = f2h(v);
    }
  }
}

extern "C" void kernel_launch(void* const* d_in, const int* in_sizes, int n_in,
                              void* d_out, int out_size, void* d_ws,
                              size_t ws_size, hipStream_t stream) {
  (void)in_sizes; (void)n_in; (void)out_size; (void)ws_size;
  const float* x = (const float*)d_in[0];
  const float* tok_w = (const float*)d_in[1];
  const float* qkv_w = (const float*)d_in[2];
  const float* qkv_b = (const float*)d_in[3];
  const float* sig_w = (const float*)d_in[4];
  const float* sig_b = (const float*)d_in[5];
  const float* out_w = (const float*)d_in[6];
  const float* out_b = (const float*)d_in[7];
  const float* c1w = (const float*)d_in[8];
  const float* c1b = (const float*)d_in[9];
  const float* c2w = (const float*)d_in[10];
  const float* c2b = (const float*)d_in[11];
  const float* ln1g = (const float*)d_in[12];
  const float* ln1b = (const float*)d_in[13];
  const float* ln2g = (const float*)d_in[14];
  const float* ln2b = (const float*)d_in[15];
  const float* lnfg = (const float*)d_in[16];
  const float* lnfb = (const float*)d_in[17];
  const float* latw = (const float*)d_in[18];
  const float* latb = (const float*)d_in[19];
  const float* d1w = (const float*)d_in[20];
  const float* d1b = (const float*)d_in[21];
  const float* d2w = (const float*)d_in[22];
  const float* d2b = (const float*)d_in[23];
  float* out = (float*)d_out;

  const long BLD = (long)B_ * L_ * D_;         // 4194304
  const long CHUNK = (long)B_ * H_ * L_ * L_;  // 16777216
  const long SER_OFF = (long)B_ * L_ * C_;
  const long PRI_OFF = SER_OFF + NL_ * CHUNK;
  const long Z_OFF = PRI_OFF + NL_ * CHUNK;
  const int M = B_ * L_;  // 8192
  const int DD = D_ * D_;

  char* wp = (char*)d_ws;
  auto alloc = [&](size_t bytes) {
    char* p = wp;
    wp += (bytes + 255) & ~(size_t)255;
    return p;
  };
  float* h32 = (float*)alloc(BLD * 4);
  u16* h16 = (u16*)alloc(BLD * 2);
  float* tb = (float*)alloc(BLD * 4);
  u16* qk16 = (u16*)alloc(BLD * 4);  // (M,1024); reused as y16 / dec fp32
  u16* vt16 = (u16*)alloc(BLD * 2);
  u16* pv16 = (u16*)alloc(BLD * 2);
  float* coef = (float*)alloc((size_t)B_ * H_ * L_ * 4);
  float* c2f = (float*)alloc((size_t)B_ * H_ * L_ * 4);
  u16* wqkv16 = (u16*)alloc((size_t)NL_ * 3 * DD * 2);
  u16* wo16 = (u16*)alloc((size_t)NL_ * DD * 2);
  u16* c116 = (u16*)alloc((size_t)NL_ * DD * 2);
  u16* c216 = (u16*)alloc((size_t)NL_ * DD * 2);

  conv16<<<NL_ * 3 * DD / 256, 256, 0, stream>>>(qkv_w, wqkv16, NL_ * 3 * DD);
  conv16<<<NL_ * DD / 256, 256, 0, stream>>>(out_w, wo16, NL_ * DD);
  conv16<<<NL_ * DD / 256, 256, 0, stream>>>(c1w, c116, NL_ * DD);
  conv16<<<NL_ * DD / 256, 256, 0, stream>>>(c2w, c216, NL_ * DD);

  embed_kernel<<<B_ * 16, 256, 0, stream>>>(x, tok_w, h32, h16);

  for (int i = 0; i < NL_; ++i) {
    const long ofQK = (long)(i * 3) * DD, ofV = (long)(i * 3 + 2) * DD;
    // merged q,k projection: (M,1024) fp16
    mgemm<2, 2, 0, 1><<<dim3(8, 64), 256, 0, stream>>>(
        h16, wqkv16 + ofQK, qkv_b + (long)i * 3 * D_, nullptr, qk16, D_, D_,
        D_, 2 * D_);
    // v transposed fp16: vt(d, m) = Wv @ h^T (bias folded into PV epilogue)
    mgemm<2, 1, 0, 1><<<dim3(128, 4), 128, 0, stream>>>(
        wqkv16 + ofV, h16, nullptr, nullptr, vt16, D_, D_, D_, M);
    sigma_kernel<<<M, 256, 0, stream>>>(h32, sig_w + (long)i * H_ * D_,
                                        sig_b + i * H_, coef, c2f);
    fused_attn<<<dim3(4, 256), 256, 0, stream>>>(
        qk16, vt16, qkv_b + (long)(i * 3 + 2) * D_, coef, c2f,
        out + SER_OFF + i * CHUNK, out + PRI_OFF + i * CHUNK, pv16);
    // out projection (fp32 out)
    mgemm<2, 1, 0, 0><<<dim3(8, 64), 128, 0, stream>>>(
        pv16, wo16 + (long)i * DD, out_b + i * D_, tb, nullptr, D_, D_, D_,
        D_);
    ln2_kernel<<<M, 256, 0, stream>>>(h32, tb, ln1g + i * D_, ln1b + i * D_,
                                      h32, h16);
    // FFN (intermediate y16 reuses qk16)
    u16* y16 = qk16;
    mgemm<2, 1, 1, 1><<<dim3(8, 64), 128, 0, stream>>>(
        h16, c116 + (long)i * DD, c1b + i * DF_, nullptr, y16, D_, D_, D_,
        DF_);
    mgemm<2, 1, 0, 0><<<dim3(8, 64), 128, 0, stream>>>(
        y16, c216 + (long)i * DD, c2b + i * D_, tb, nullptr, DF_, DF_, DF_,
        D_);
    ln2_kernel<<<M, 256, 0, stream>>>(h32, tb, ln2g + i * D_, ln2b + i * D_,
                                      h32, h16);
  }
  ln2_kernel<<<M, 256, 0, stream>>>(h32, nullptr, lnfg, lnfb, tb, nullptr);
  float* dec = (float*)qk16;  // 16MB fp32 scratch (qk dead)
  gemm_kernel<0><<<dim3(1, M / 64), 256, 0, stream>>>(
      tb, latw, latb, out + Z_OFF, M, Z_, D_, D_, D_, Z_);
  gemm_kernel<2><<<dim3(8, M / 64), 256, 0, stream>>>(
      out + Z_OFF, d1w, d1b, dec, M, D_, Z_, Z_, Z_, D_);
  gemm_kernel<0><<<dim3(1, M / 64), 256, 0, stream>>>(
      dec, d2w, d2b, out, M, C_, D_, D_, D_, C_);
}

// Round 9
// 851.515 us; speedup vs baseline: 1.5328x; 1.1500x over previous
//
#include <hip/hip_runtime.h>
#include <math.h>

#define B_ 32
#define L_ 256
#define C_ 55
#define D_ 512
#define H_ 8
#define NL_ 3
#define DF_ 512
#define Z_ 16
#define DK_ 64

typedef unsigned short u16;
typedef __attribute__((ext_vector_type(8))) short s16x8;
typedef __attribute__((ext_vector_type(8))) _Float16 f16x8;
typedef __attribute__((ext_vector_type(4))) float f32x4;

__device__ __forceinline__ u16 f2h(float f) {
  _Float16 h = (_Float16)f;
  return __builtin_bit_cast(u16, h);
}
__device__ __forceinline__ void gload16(const void* g, void* l) {
  __builtin_amdgcn_global_load_lds(
      (const __attribute__((address_space(1))) unsigned*)g,
      (__attribute__((address_space(3))) unsigned*)l, 16, 0, 0);
}

// ================= fp16 MFMA GEMM body: C = act(A @ B^T + bias) ============
// BK=64, chunk-XOR swizzled LDS. A: (M,K) fp16; B: (N,K) fp16. K % 64 == 0.
// OUT: 0 fp32, 1 fp16. ACT: 0 none, 1 exact gelu. Cols >= nmax dropped.
template <int WM, int WN, int ACT, int OUT>
__device__ __forceinline__ void mgemm_body(
    char* As, char* Bs, const u16* __restrict__ A16,
    const u16* __restrict__ B16, const float* __restrict__ bias,
    float* __restrict__ Cf, u16* __restrict__ C16, int K, int lda, int ldb,
    int ldc, int nmax, int bxi, int byi) {
  constexpr int BM = WM * 64, BN = WN * 64, T = WM * WN * 64;
  constexpr int ACH = BM * 8, BCH = BN * 8;  // 16B chunks per K-tile
  const int t = threadIdx.x, lane = t & 63, w = t >> 6;
  const int wm = w / WN, wn = w % WN;
  const long m0 = (long)byi * BM, n0 = (long)bxi * BN;
  const char* Ab = (const char*)(A16 + m0 * lda);
  const char* Bb = (const char*)(B16 + n0 * ldb);
  const int fr = lane & 15, gq = lane >> 4;
  const long lda2 = (long)lda * 2, ldb2 = (long)ldb * 2;
  f32x4 acc[4][4] = {};
  for (int k0 = 0; k0 < K; k0 += 64) {
    const long kb = (long)k0 * 2;
#pragma unroll
    for (int e = 0; e < ACH; e += T) {
      int id = e + t;
      int row = id >> 3, c = (id & 7) ^ (row & 7);
      gload16(Ab + (long)row * lda2 + kb + c * 16, As + id * 16);
    }
#pragma unroll
    for (int e = 0; e < BCH; e += T) {
      int id = e + t;
      int row = id >> 3, c = (id & 7) ^ (row & 7);
      gload16(Bb + (long)row * ldb2 + kb + c * 16, Bs + id * 16);
    }
    __syncthreads();
#pragma unroll
    for (int ks = 0; ks < 2; ++ks) {
      f16x8 a[4], b[4];
#pragma unroll
      for (int m = 0; m < 4; ++m) {
        int row = wm * 64 + m * 16 + fr;
        a[m] = *(const f16x8*)(As + row * 128 +
                               ((gq * 16 + ks * 64) ^ ((row & 7) << 4)));
      }
#pragma unroll
      for (int n = 0; n < 4; ++n) {
        int row = wn * 64 + n * 16 + fr;
        b[n] = *(const f16x8*)(Bs + row * 128 +
                               ((gq * 16 + ks * 64) ^ ((row & 7) << 4)));
      }
#pragma unroll
      for (int m = 0; m < 4; ++m)
#pragma unroll
        for (int n = 0; n < 4; ++n)
          acc[m][n] =
              __builtin_amdgcn_mfma_f32_16x16x32_f16(a[m], b[n], acc[m][n], 0, 0, 0);
    }
    __syncthreads();
  }
#pragma unroll
  for (int m = 0; m < 4; ++m) {
    long mg = m0 + wm * 64 + m * 16 + gq * 4;
#pragma unroll
    for (int n = 0; n < 4; ++n) {
      int ng = (int)n0 + wn * 64 + n * 16 + fr;
      if (ng >= nmax) continue;
      float bv = bias ? bias[ng] : 0.f;
#pragma unroll
      for (int r = 0; r < 4; ++r) {
        float v = acc[m][n][r] + bv;
        if (ACT == 1) v = 0.5f * v * (1.f + erff(v * 0.70710678118654752f));
        long idx = (mg + r) * ldc + ng;
        if (OUT == 0) Cf[idx] = v;
        if (OUT == 1) C16[idx] = f2h(v);
      }
    }
  }
}

template <int WM, int WN, int ACT, int OUT>
__global__ __launch_bounds__(WM * WN * 64) void mgemm(
    const u16* __restrict__ A16, const u16* __restrict__ B16,
    const float* __restrict__ bias, float* __restrict__ Cf,
    u16* __restrict__ C16, int K, int lda, int ldb, int ldc, int nmax) {
  __shared__ __align__(16) char As[WM * 64 * 128];
  __shared__ __align__(16) char Bs[WN * 64 * 128];
  mgemm_body<WM, WN, ACT, OUT>(As, Bs, A16, B16, bias, Cf, C16, K, lda, ldb,
                               ldc, nmax, blockIdx.x, blockIdx.y);
}

// ---- merged q,k projection (512 blocks) + v^T (256 blocks), one launch ----
__global__ __launch_bounds__(256) void qkv_kernel(
    const u16* __restrict__ h16, const u16* __restrict__ w16,
    const float* __restrict__ bias, u16* __restrict__ qk16,
    u16* __restrict__ vt16) {
  __shared__ __align__(16) char As[128 * 128];
  __shared__ __align__(16) char Bs[128 * 128];
  int bx = blockIdx.x;
  if (bx < 512) {
    mgemm_body<2, 2, 0, 1>(As, Bs, h16, w16, bias, nullptr, qk16, 512, 512,
                           512, 1024, 1024, bx & 7, bx >> 3);
  } else {
    int b2 = bx - 512;
    mgemm_body<2, 2, 0, 1>(As, Bs, w16 + 1024 * 512, h16, nullptr, nullptr,
                           vt16, 512, 512, 512, 8192, 8192, b2 >> 2, b2 & 3);
  }
}

// =============== fused attention: scores+softmax+series+prior+PV ===========
// grid (L/64, B*H), 256 threads. Q,K from merged qk16 (ld=1024 shorts):
// q cols [0,512), k cols [512,1024). vt16 is (512, M) fp16. pv16 (M,512) fp16.
__global__ __launch_bounds__(256, 2) void fused_attn(
    const u16* __restrict__ qk16, const u16* __restrict__ vt16,
    const float* __restrict__ vbias, const float* __restrict__ coef,
    const float* __restrict__ c2f, float* __restrict__ ser,
    float* __restrict__ pri, u16* __restrict__ pv16) {
  __shared__ __align__(16) char smem[67584];
  char* Kreg = smem;                       // 32KB: K staging / P matrix (fp16)
  char* V0 = smem + 32768;                 // 16KB: Q stage then V half0
  char* V1 = smem + 49152;                 // 16KB: V half1
  float* rowred = (float*)(smem + 65536);  // 2048B = [4][64][2] floats
  const int t = threadIdx.x, lane = t & 63, w = t >> 6;
  const int fr = lane & 15, gq = lane >> 4;
  const int r0 = blockIdx.x * 64;
  const int bh = blockIdx.y, b = bh >> 3, h = bh & 7;
  const long qrow0 = (long)b * 256 + r0;
  const long krow0 = (long)b * 256;
  // ---- stage Q (rows r0..+63, 64 cols fp16), row stride 144B, into V0
  {
    const char* qs = (const char*)qk16 + qrow0 * 2048 + h * 128;
#pragma unroll
    for (int j = 0; j < 2; ++j) {
      int id = t + j * 256;
      int row = id >> 3, c = id & 7;
      *(s16x8*)(V0 + row * 144 + c * 16) =
          *(const s16x8*)(qs + (long)row * 2048 + c * 16);
    }
  }
  // ---- stage K full (256x64 fp16) with chunk-xor swizzle
  const char* kb = (const char*)qk16 + krow0 * 2048 + 1024 + h * 128;
#pragma unroll
  for (int j = 0; j < 8; ++j) {
    int id = t + j * 256;
    int row = id >> 3, c = (id & 7) ^ (row & 7);
    gload16(kb + (long)row * 2048 + c * 16, Kreg + id * 16);
  }
  __syncthreads();
  f32x4 acc[4][4] = {};
  // ---- QK^T single pass fp16
#pragma unroll
  for (int ks = 0; ks < 2; ++ks) {
    f16x8 aq[4], bk[4];
#pragma unroll
    for (int m = 0; m < 4; ++m)
      aq[m] = *(const f16x8*)(V0 + (m * 16 + fr) * 144 + gq * 16 + ks * 64);
#pragma unroll
    for (int n = 0; n < 4; ++n) {
      int row = w * 64 + n * 16 + fr;
      bk[n] = *(const f16x8*)(Kreg + row * 128 +
                              ((gq * 16 + ks * 64) ^ ((row & 7) << 4)));
    }
#pragma unroll
    for (int m = 0; m < 4; ++m)
#pragma unroll
      for (int n = 0; n < 4; ++n)
        acc[m][n] =
            __builtin_amdgcn_mfma_f32_16x16x32_f16(aq[m], bk[n], acc[m][n], 0, 0, 0);
  }
  // ---- softmax: scale, wave-local max/sum, one cross-wave LDS round
#pragma unroll
  for (int m = 0; m < 4; ++m)
#pragma unroll
    for (int n = 0; n < 4; ++n) acc[m][n] *= 0.125f;
  float lmax[4][4], lsum[4][4];
#pragma unroll
  for (int m = 0; m < 4; ++m)
#pragma unroll
    for (int r = 0; r < 4; ++r) {
      float v = fmaxf(fmaxf(acc[m][0][r], acc[m][1][r]),
                      fmaxf(acc[m][2][r], acc[m][3][r]));
#pragma unroll
      for (int off = 8; off > 0; off >>= 1) v = fmaxf(v, __shfl_xor(v, off, 64));
      lmax[m][r] = v;
    }
#pragma unroll
  for (int m = 0; m < 4; ++m)
#pragma unroll
    for (int n = 0; n < 4; ++n)
#pragma unroll
      for (int r = 0; r < 4; ++r)
        acc[m][n][r] = __expf(acc[m][n][r] - lmax[m][r]);
#pragma unroll
  for (int m = 0; m < 4; ++m)
#pragma unroll
    for (int r = 0; r < 4; ++r) {
      float s = acc[m][0][r] + acc[m][1][r] + acc[m][2][r] + acc[m][3][r];
#pragma unroll
      for (int off = 8; off > 0; off >>= 1) s += __shfl_xor(s, off, 64);
      lsum[m][r] = s;
    }
  if (fr == 0) {
#pragma unroll
    for (int m = 0; m < 4; ++m)
#pragma unroll
      for (int r = 0; r < 4; ++r) {
        int row = m * 16 + gq * 4 + r;
        rowred[(w * 64 + row) * 2] = lmax[m][r];
        rowred[(w * 64 + row) * 2 + 1] = lsum[m][r];
      }
  }
  __syncthreads();  // also guarantees all waves done reading Q (V0) and K
  float scale[4][4];
#pragma unroll
  for (int m = 0; m < 4; ++m)
#pragma unroll
    for (int r = 0; r < 4; ++r) {
      int row = m * 16 + gq * 4 + r;
      float g = -1e30f, tot = 0.f;
      float2 pr[4];
#pragma unroll
      for (int ww = 0; ww < 4; ++ww) {
        pr[ww] = *(const float2*)&rowred[(ww * 64 + row) * 2];
        g = fmaxf(g, pr[ww].x);
      }
#pragma unroll
      for (int ww = 0; ww < 4; ++ww) tot += pr[ww].y * __expf(pr[ww].x - g);
      scale[m][r] = __expf(lmax[m][r] - g) / tot;
    }
  // ---- issue BOTH V halves (fp16) into V0 / V1 (Q dead, hidden under writes)
  const char* vtb = (const char*)vt16 + ((long)h * 64 * 8192 + krow0) * 2;
#pragma unroll
  for (int j = 0; j < 4; ++j) {
    int id = t + j * 256;
    int row = id >> 5, c = (id & 31) ^ (row & 7);
    gload16(vtb + (long)row * 16384 + c * 16, V0 + id * 16);
    gload16(vtb + (long)(32 + row) * 16384 + c * 16, V1 + id * 16);
  }
  // ---- write series + prior (fp32) + P (fp16, swizzled LDS @ Kreg)
  float* serb = ser + ((long)bh * 256 + r0) * 256 + w * 64;
  float* prib = pri + ((long)bh * 256 + r0) * 256 + w * 64;
  const float* cfb = coef + bh * 256 + r0;
  const float* ccb = c2f + bh * 256 + r0;
#pragma unroll
  for (int m = 0; m < 4; ++m)
#pragma unroll
    for (int r = 0; r < 4; ++r) {
      int row = m * 16 + gq * 4 + r;
      float cf = cfb[row], cc = ccb[row];
      float fl = (float)(r0 + row);
#pragma unroll
      for (int n = 0; n < 4; ++n) {
        int col = n * 16 + fr;
        float p = acc[m][n][r] * scale[m][r];
        serb[(long)row * 256 + col] = p;
        int pb = row * 512 + (((w * 64 + col) * 2) ^ ((row & 7) << 4));
        *(u16*)(Kreg + pb) = f2h(p);
        float dd = fl - (float)(w * 64 + col);
        prib[(long)row * 256 + col] = cf * expf(cc * dd * dd);
      }
    }
  __syncthreads();  // drains both V halves + P visible
  // ---- PV, both d-halves in one pass (pa reused)
  f32x4 acc2[2][2] = {};
#pragma unroll
  for (int ks = 0; ks < 8; ++ks) {
    int arow = w * 16 + fr;
    f16x8 pa = *(const f16x8*)(
        Kreg + arow * 512 + ((gq * 16 + ks * 64) ^ ((arow & 7) << 4)));
#pragma unroll
    for (int n = 0; n < 2; ++n) {
      int vrow = n * 16 + fr;
      int vo = vrow * 512 + ((gq * 16 + ks * 64) ^ ((vrow & 7) << 4));
      f16x8 vb0 = *(const f16x8*)(V0 + vo);
      f16x8 vb1 = *(const f16x8*)(V1 + vo);
      acc2[0][n] = __builtin_amdgcn_mfma_f32_16x16x32_f16(pa, vb0, acc2[0][n], 0, 0, 0);
      acc2[1][n] = __builtin_amdgcn_mfma_f32_16x16x32_f16(pa, vb1, acc2[1][n], 0, 0, 0);
    }
  }
#pragma unroll
  for (int half = 0; half < 2; ++half)
#pragma unroll
    for (int n = 0; n < 2; ++n)
#pragma unroll
      for (int r = 0; r < 4; ++r) {
        int gcol = h * 64 + half * 32 + n * 16 + fr;
        long gm = qrow0 + w * 16 + gq * 4 + r;
        pv16[gm * 512 + gcol] = f2h(acc2[half][n][r] + vbias[gcol]);
      }
}

// ---------------- fp32 tiled GEMM (d1 only: K=16) --------------------------
template <int ACT, bool O16>
__global__ __launch_bounds__(256) void gemm_kernel(
    const float* __restrict__ A, const float* __restrict__ Bm,
    const float* __restrict__ bias, float* __restrict__ C,
    u16* __restrict__ C16, int M, int N, int K, int lda, int ldb, int ldc) {
  __shared__ float Asm[16][65];
  __shared__ float Bsm[16][65];
  int t = threadIdx.x;
  int tx = t & 15, ty = t >> 4;
  int n0 = blockIdx.x * 64, m0 = blockIdx.y * 64;
  float acc[4][4] = {};
  for (int k0 = 0; k0 < K; k0 += 16) {
#pragma unroll
    for (int e = 0; e < 4; ++e) {
      int idx = t + e * 256;
      int mi = idx >> 4, ki = idx & 15;
      int m = m0 + mi, kk = k0 + ki;
      Asm[ki][mi] = (m < M && kk < K) ? A[(long)m * lda + kk] : 0.f;
      int n = n0 + mi;
      Bsm[ki][mi] = (n < N && kk < K) ? Bm[(long)n * ldb + kk] : 0.f;
    }
    __syncthreads();
#pragma unroll
    for (int kk = 0; kk < 16; ++kk) {
      float a[4], b[4];
#pragma unroll
      for (int i = 0; i < 4; ++i) a[i] = Asm[kk][ty + 16 * i];
#pragma unroll
      for (int j = 0; j < 4; ++j) b[j] = Bsm[kk][tx + 16 * j];
#pragma unroll
      for (int i = 0; i < 4; ++i)
#pragma unroll
        for (int j = 0; j < 4; ++j) acc[i][j] = fmaf(a[i], b[j], acc[i][j]);
    }
    __syncthreads();
  }
#pragma unroll
  for (int i = 0; i < 4; ++i) {
    int m = m0 + ty + 16 * i;
    if (m >= M) continue;
#pragma unroll
    for (int j = 0; j < 4; ++j) {
      int n = n0 + tx + 16 * j;
      if (n >= N) continue;
      float v = acc[i][j];
      if (bias) v += bias[n];
      if (ACT == 2) v = fmaxf(v, 0.f);
      if (O16)
        C16[(long)m * ldc + n] = f2h(v);
      else
        C[(long)m * ldc + n] = v;
    }
  }
}

// ---------------- weight conversions ---------------------------------------
__global__ __launch_bounds__(256) void conv16(const float* __restrict__ in,
                                              u16* __restrict__ o, int n) {
  int i = blockIdx.x * 256 + threadIdx.x;
  if (i >= n) return;
  o[i] = f2h(in[i]);
}
// pad (rows x 512) fp32 -> (64 x 512) fp16, zero rows >= rows
__global__ __launch_bounds__(256) void conv16pad(const float* __restrict__ in,
                                                 u16* __restrict__ o,
                                                 int rows) {
  int i = blockIdx.x * 256 + threadIdx.x;  // grid 128 -> 32768
  int r = i >> 9, c = i & 511;
  o[i] = (r < rows) ? f2h(in[r * 512 + c]) : (u16)0;
}

// ---------------- sigma: per-(b,l) block -> Gaussian coef/c2 per head ------
__global__ __launch_bounds__(256) void sigma_kernel(
    const float* __restrict__ hbuf, const float* __restrict__ sw,
    const float* __restrict__ sb, float* __restrict__ coef,
    float* __restrict__ c2f) {
  __shared__ float sm[4][8];
  int bl = blockIdx.x;
  int l = bl & 255, b = bl >> 8;
  int t = threadIdx.x;
  const float* hrow = hbuf + (long)bl * 512;
  float h0 = hrow[t], h1 = hrow[t + 256];
  float part[8];
#pragma unroll
  for (int hd = 0; hd < 8; ++hd) {
    const float* wrow = sw + hd * 512;
    part[hd] = h0 * wrow[t] + h1 * wrow[t + 256];
  }
#pragma unroll
  for (int off = 32; off > 0; off >>= 1)
#pragma unroll
    for (int hd = 0; hd < 8; ++hd) part[hd] += __shfl_xor(part[hd], off, 64);
  int wid = t >> 6;
  if ((t & 63) == 0) {
#pragma unroll
    for (int hd = 0; hd < 8; ++hd) sm[wid][hd] = part[hd];
  }
  __syncthreads();
  if (t < 8) {
    float sig = sm[0][t] + sm[1][t] + sm[2][t] + sm[3][t] + sb[t];
    sig = 1.f / (1.f + expf(-5.f * sig));
    sig += 1e-5f;
    sig = expf(sig * 1.0986122886681098f) - 1.f;
    long idx = ((long)(b * 8 + t) << 8) | l;
    coef[idx] = 0.3989422804014327f / sig;
    c2f[idx] = -0.5f / (sig * sig);
  }
}

// --------- residual + LN: a(fp32) + r(fp32) -> fp32 [+ fp16] ---------------
__global__ __launch_bounds__(256) void ln2_kernel(
    const float* __restrict__ a, const float* __restrict__ r,
    const float* __restrict__ gg, const float* __restrict__ be,
    float* __restrict__ ofp, u16* __restrict__ o16) {
  __shared__ float smw[4];
  long base = (long)blockIdx.x * D_;
  int t = threadIdx.x;
  float x0 = a[base + t], x1 = a[base + t + 256];
  if (r) {
    x0 += r[base + t];
    x1 += r[base + t + 256];
  }
  float v = x0 + x1;
#pragma unroll
  for (int off = 32; off > 0; off >>= 1) v += __shfl_xor(v, off, 64);
  if ((t & 63) == 0) smw[t >> 6] = v;
  __syncthreads();
  float mean = (smw[0] + smw[1] + smw[2] + smw[3]) * (1.f / D_);
  __syncthreads();
  float d0 = x0 - mean, d1 = x1 - mean;
  float vv = d0 * d0 + d1 * d1;
#pragma unroll
  for (int off = 32; off > 0; off >>= 1) vv += __shfl_xor(vv, off, 64);
  if ((t & 63) == 0) smw[t >> 6] = vv;
  __syncthreads();
  float var = (smw[0] + smw[1] + smw[2] + smw[3]) * (1.f / D_);
  float rstd = rsqrtf(var + 1e-5f);
  float v0 = d0 * rstd * gg[t] + be[t];
  float v1 = d1 * rstd * gg[t + 256] + be[t + 256];
  ofp[base + t] = v0;
  ofp[base + t + 256] = v1;
  if (o16) {
    o16[base + t] = f2h(v0);
    o16[base + t + 256] = f2h(v1);
  }
}

// ---------------- embedding: circular conv1d + PE -> fp32 + fp16 -----------
__global__ __launch_bounds__(256) void embed_kernel(
    const float* __restrict__ x, const float* __restrict__ tw,
    float* __restrict__ ofp, u16* __restrict__ o16) {
  __shared__ float xs[18][56];
  int bi = blockIdx.x;
  int lt = (bi & 15) * 16;
  int b = bi >> 4;
  int t = threadIdx.x;
  for (int idx = t; idx < 18 * 55; idx += 256) {
    int rr = idx / 55, cc = idx % 55;
    int gl = (lt + rr - 1 + L_) & (L_ - 1);
    xs[rr][cc] = x[(long)(b * L_ + gl) * C_ + cc];
  }
  __syncthreads();
  for (int dp = 0; dp < 2; ++dp) {
    int d = t + dp * 256;
    float acc[16] = {};
    const float* wr = tw + (long)d * (C_ * 3);
    for (int c = 0; c < C_; ++c) {
#pragma unroll
      for (int w = 0; w < 3; ++w) {
        float wv = wr[c * 3 + w];
#pragma unroll
        for (int l = 0; l < 16; ++l) acc[l] = fmaf(xs[l + w][c], wv, acc[l]);
      }
    }
    float ang_scale = expf(-(float)(d & ~1) * 0.017988946039015984f);
#pragma unroll
    for (int l = 0; l < 16; ++l) {
      float ang = (float)(lt + l) * ang_scale;
      float pe = (d & 1) ? cosf(ang) : sinf(ang);
      float v = acc[l] + pe;
      long idx = (long)(b * L_ + lt + l) * D_ + d;
      ofp[idx] = v;
      o16[idx] = f2h(v);
    }
  }
}

extern "C" void kernel_launch(void* const* d_in, const int* in_sizes, int n_in,
                              void* d_out, int out_size, void* d_ws,
                              size_t ws_size, hipStream_t stream) {
  (void)in_sizes; (void)n_in; (void)out_size; (void)ws_size;
  const float* x = (const float*)d_in[0];
  const float* tok_w = (const float*)d_in[1];
  const float* qkv_w = (const float*)d_in[2];
  const float* qkv_b = (const float*)d_in[3];
  const float* sig_w = (const float*)d_in[4];
  const float* sig_b = (const float*)d_in[5];
  const float* out_w = (const float*)d_in[6];
  const float* out_b = (const float*)d_in[7];
  const float* c1w = (const float*)d_in[8];
  const float* c1b = (const float*)d_in[9];
  const float* c2w = (const float*)d_in[10];
  const float* c2b = (const float*)d_in[11];
  const float* ln1g = (const float*)d_in[12];
  const float* ln1b = (const float*)d_in[13];
  const float* ln2g = (const float*)d_in[14];
  const float* ln2b = (const float*)d_in[15];
  const float* lnfg = (const float*)d_in[16];
  const float* lnfb = (const float*)d_in[17];
  const float* latw = (const float*)d_in[18];
  const float* latb = (const float*)d_in[19];
  const float* d1w = (const float*)d_in[20];
  const float* d1b = (const float*)d_in[21];
  const float* d2w = (const float*)d_in[22];
  const float* d2b = (const float*)d_in[23];
  float* out = (float*)d_out;

  const long BLD = (long)B_ * L_ * D_;         // 4194304
  const long CHUNK = (long)B_ * H_ * L_ * L_;  // 16777216
  const long SER_OFF = (long)B_ * L_ * C_;
  const long PRI_OFF = SER_OFF + NL_ * CHUNK;
  const long Z_OFF = PRI_OFF + NL_ * CHUNK;
  const int M = B_ * L_;  // 8192
  const int DD = D_ * D_;

  char* wp = (char*)d_ws;
  auto alloc = [&](size_t bytes) {
    char* p = wp;
    wp += (bytes + 255) & ~(size_t)255;
    return p;
  };
  float* h32 = (float*)alloc(BLD * 4);
  u16* h16 = (u16*)alloc(BLD * 2);
  float* tb = (float*)alloc(BLD * 4);
  u16* qk16 = (u16*)alloc(BLD * 4);  // (M,1024); reused as y16
  u16* vt16 = (u16*)alloc(BLD * 2);  // also dec16 at tail
  u16* pv16 = (u16*)alloc(BLD * 2);
  float* coef = (float*)alloc((size_t)B_ * H_ * L_ * 4);
  float* c2f = (float*)alloc((size_t)B_ * H_ * L_ * 4);
  u16* wqkv16 = (u16*)alloc((size_t)NL_ * 3 * DD * 2);
  u16* wo16 = (u16*)alloc((size_t)NL_ * DD * 2);
  u16* c116 = (u16*)alloc((size_t)NL_ * DD * 2);
  u16* c216 = (u16*)alloc((size_t)NL_ * DD * 2);
  u16* latpad = (u16*)alloc((size_t)64 * 512 * 2);
  u16* d2pad = (u16*)alloc((size_t)64 * 512 * 2);

  conv16<<<NL_ * 3 * DD / 256, 256, 0, stream>>>(qkv_w, wqkv16, NL_ * 3 * DD);
  conv16<<<NL_ * DD / 256, 256, 0, stream>>>(out_w, wo16, NL_ * DD);
  conv16<<<NL_ * DD / 256, 256, 0, stream>>>(c1w, c116, NL_ * DD);
  conv16<<<NL_ * DD / 256, 256, 0, stream>>>(c2w, c216, NL_ * DD);
  conv16pad<<<128, 256, 0, stream>>>(latw, latpad, Z_);
  conv16pad<<<128, 256, 0, stream>>>(d2w, d2pad, C_);

  embed_kernel<<<B_ * 16, 256, 0, stream>>>(x, tok_w, h32, h16);

  for (int i = 0; i < NL_; ++i) {
    const long ofQK = (long)(i * 3) * DD;
    // merged q,k projection + v^T, one 768-block launch
    qkv_kernel<<<768, 256, 0, stream>>>(h16, wqkv16 + ofQK,
                                        qkv_b + (long)i * 3 * D_, qk16, vt16);
    sigma_kernel<<<M, 256, 0, stream>>>(h32, sig_w + (long)i * H_ * D_,
                                        sig_b + i * H_, coef, c2f);
    fused_attn<<<dim3(4, 256), 256, 0, stream>>>(
        qk16, vt16, qkv_b + (long)(i * 3 + 2) * D_, coef, c2f,
        out + SER_OFF + i * CHUNK, out + PRI_OFF + i * CHUNK, pv16);
    // out projection (fp32 out)
    mgemm<2, 1, 0, 0><<<dim3(8, 64), 128, 0, stream>>>(
        pv16, wo16 + (long)i * DD, out_b + i * D_, tb, nullptr, D_, D_, D_, D_,
        D_);
    ln2_kernel<<<M, 256, 0, stream>>>(h32, tb, ln1g + i * D_, ln1b + i * D_,
                                      h32, h16);
    // FFN (intermediate y16 reuses qk16)
    u16* y16 = qk16;
    mgemm<2, 1, 1, 1><<<dim3(8, 64), 128, 0, stream>>>(
        h16, c116 + (long)i * DD, c1b + i * DF_, nullptr, y16, D_, D_, D_, DF_,
        DF_);
    mgemm<2, 1, 0, 0><<<dim3(8, 64), 128, 0, stream>>>(
        y16, c216 + (long)i * DD, c2b + i * D_, tb, nullptr, DF_, DF_, DF_, D_,
        D_);
    ln2_kernel<<<M, 256, 0, stream>>>(h32, tb, ln2g + i * D_, ln2b + i * D_,
                                      h32, h16);
  }
  // final LN -> tb (fp32) + h16 (fp16)
  ln2_kernel<<<M, 256, 0, stream>>>(h32, nullptr, lnfg, lnfb, tb, h16);
  // latent: z = LNf(h) @ latw^T + latb  (fp16 MFMA, N=16 guarded)
  mgemm<2, 1, 0, 0><<<dim3(1, 64), 128, 0, stream>>>(
      h16, latpad, latb, out + Z_OFF, nullptr, D_, D_, D_, Z_, Z_);
  // d1: relu(z @ d1w^T + d1b) -> fp16 (K=16, fp32 path)
  u16* dec16 = vt16;
  gemm_kernel<2, true><<<dim3(8, 128), 256, 0, stream>>>(
      out + Z_OFF, d1w, d1b, nullptr, dec16, M, D_, Z_, Z_, Z_, D_);
  // d2: recon = dec @ d2w^T + d2b (fp16 MFMA, N=55 guarded)
  mgemm<2, 1, 0, 0><<<dim3(1, 64), 128, 0, stream>>>(
      dec16, d2pad, d2b, out, nullptr, D_, D_, D_, C_, C_);
}

// Round 10
// 771.722 us; speedup vs baseline: 1.6913x; 1.1034x over previous
//
#include <hip/hip_runtime.h>
#include <math.h>

#define B_ 32
#define L_ 256
#define C_ 55
#define D_ 512
#define H_ 8
#define NL_ 3
#define DF_ 512
#define Z_ 16
#define DK_ 64

typedef unsigned short u16;
typedef __attribute__((ext_vector_type(8))) short s16x8;
typedef __attribute__((ext_vector_type(8))) _Float16 f16x8;
typedef __attribute__((ext_vector_type(4))) float f32x4;

__device__ __forceinline__ u16 f2h(float f) {
  _Float16 h = (_Float16)f;
  return __builtin_bit_cast(u16, h);
}
__device__ __forceinline__ void gload16(const void* g, void* l) {
  __builtin_amdgcn_global_load_lds(
      (const __attribute__((address_space(1))) unsigned*)g,
      (__attribute__((address_space(3))) unsigned*)l, 16, 0, 0);
}

// ================= fp16 MFMA GEMM body: C = act(A @ B^T + bias) ============
// BK=64, chunk-XOR swizzled LDS. A: (M,K) fp16; B: (N,K) fp16. K % 64 == 0.
// OUT: 0 fp32, 1 fp16. ACT: 0 none, 1 exact gelu. Cols >= nmax dropped.
template <int WM, int WN, int ACT, int OUT>
__device__ __forceinline__ void mgemm_body(
    char* As, char* Bs, const u16* __restrict__ A16,
    const u16* __restrict__ B16, const float* __restrict__ bias,
    float* __restrict__ Cf, u16* __restrict__ C16, int K, int lda, int ldb,
    int ldc, int nmax, int bxi, int byi) {
  constexpr int BM = WM * 64, BN = WN * 64, T = WM * WN * 64;
  constexpr int ACH = BM * 8, BCH = BN * 8;  // 16B chunks per K-tile
  const int t = threadIdx.x, lane = t & 63, w = t >> 6;
  const int wm = w / WN, wn = w % WN;
  const long m0 = (long)byi * BM, n0 = (long)bxi * BN;
  const char* Ab = (const char*)(A16 + m0 * lda);
  const char* Bb = (const char*)(B16 + n0 * ldb);
  const int fr = lane & 15, gq = lane >> 4;
  const long lda2 = (long)lda * 2, ldb2 = (long)ldb * 2;
  f32x4 acc[4][4] = {};
  for (int k0 = 0; k0 < K; k0 += 64) {
    const long kb = (long)k0 * 2;
#pragma unroll
    for (int e = 0; e < ACH; e += T) {
      int id = e + t;
      int row = id >> 3, c = (id & 7) ^ (row & 7);
      gload16(Ab + (long)row * lda2 + kb + c * 16, As + id * 16);
    }
#pragma unroll
    for (int e = 0; e < BCH; e += T) {
      int id = e + t;
      int row = id >> 3, c = (id & 7) ^ (row & 7);
      gload16(Bb + (long)row * ldb2 + kb + c * 16, Bs + id * 16);
    }
    __syncthreads();
#pragma unroll
    for (int ks = 0; ks < 2; ++ks) {
      f16x8 a[4], b[4];
#pragma unroll
      for (int m = 0; m < 4; ++m) {
        int row = wm * 64 + m * 16 + fr;
        a[m] = *(const f16x8*)(As + row * 128 +
                               ((gq * 16 + ks * 64) ^ ((row & 7) << 4)));
      }
#pragma unroll
      for (int n = 0; n < 4; ++n) {
        int row = wn * 64 + n * 16 + fr;
        b[n] = *(const f16x8*)(Bs + row * 128 +
                               ((gq * 16 + ks * 64) ^ ((row & 7) << 4)));
      }
#pragma unroll
      for (int m = 0; m < 4; ++m)
#pragma unroll
        for (int n = 0; n < 4; ++n)
          acc[m][n] =
              __builtin_amdgcn_mfma_f32_16x16x32_f16(a[m], b[n], acc[m][n], 0, 0, 0);
    }
    __syncthreads();
  }
#pragma unroll
  for (int m = 0; m < 4; ++m) {
    long mg = m0 + wm * 64 + m * 16 + gq * 4;
#pragma unroll
    for (int n = 0; n < 4; ++n) {
      int ng = (int)n0 + wn * 64 + n * 16 + fr;
      if (ng >= nmax) continue;
      float bv = bias ? bias[ng] : 0.f;
#pragma unroll
      for (int r = 0; r < 4; ++r) {
        float v = acc[m][n][r] + bv;
        if (ACT == 1) v = 0.5f * v * (1.f + erff(v * 0.70710678118654752f));
        long idx = (mg + r) * ldc + ng;
        if (OUT == 0) Cf[idx] = v;
        if (OUT == 1) C16[idx] = f2h(v);
      }
    }
  }
}

template <int WM, int WN, int ACT, int OUT>
__global__ __launch_bounds__(WM * WN * 64) void mgemm(
    const u16* __restrict__ A16, const u16* __restrict__ B16,
    const float* __restrict__ bias, float* __restrict__ Cf,
    u16* __restrict__ C16, int K, int lda, int ldb, int ldc, int nmax) {
  __shared__ __align__(16) char As[WM * 64 * 128];
  __shared__ __align__(16) char Bs[WN * 64 * 128];
  mgemm_body<WM, WN, ACT, OUT>(As, Bs, A16, B16, bias, Cf, C16, K, lda, ldb,
                               ldc, nmax, blockIdx.x, blockIdx.y);
}

// ---- merged: q,k proj (512 blocks) + v^T (256) + sigma (8192), one launch -
__global__ __launch_bounds__(256) void qkv_kernel(
    const u16* __restrict__ h16, const u16* __restrict__ w16,
    const float* __restrict__ bias, u16* __restrict__ qk16,
    u16* __restrict__ vt16, const float* __restrict__ h32,
    const float* __restrict__ sw, const float* __restrict__ sb,
    float* __restrict__ coef, float* __restrict__ c2f) {
  __shared__ __align__(16) char As[128 * 128];
  __shared__ __align__(16) char Bs[128 * 128];
  __shared__ float sm[4][8];
  int bx = blockIdx.x;
  if (bx < 512) {
    mgemm_body<2, 2, 0, 1>(As, Bs, h16, w16, bias, nullptr, qk16, 512, 512,
                           512, 1024, 1024, bx & 7, bx >> 3);
  } else if (bx < 768) {
    int b2 = bx - 512;
    mgemm_body<2, 2, 0, 1>(As, Bs, w16 + 1024 * 512, h16, nullptr, nullptr,
                           vt16, 512, 512, 512, 8192, 8192, b2 >> 2, b2 & 3);
  } else {
    // sigma body (identical to proven standalone sigma_kernel)
    int bl = bx - 768;
    int l = bl & 255, b = bl >> 8;
    int t = threadIdx.x;
    const float* hrow = h32 + (long)bl * 512;
    float h0 = hrow[t], h1 = hrow[t + 256];
    float part[8];
#pragma unroll
    for (int hd = 0; hd < 8; ++hd) {
      const float* wrow = sw + hd * 512;
      part[hd] = h0 * wrow[t] + h1 * wrow[t + 256];
    }
#pragma unroll
    for (int off = 32; off > 0; off >>= 1)
#pragma unroll
      for (int hd = 0; hd < 8; ++hd) part[hd] += __shfl_xor(part[hd], off, 64);
    int wid = t >> 6;
    if ((t & 63) == 0) {
#pragma unroll
      for (int hd = 0; hd < 8; ++hd) sm[wid][hd] = part[hd];
    }
    __syncthreads();
    if (t < 8) {
      float sig = sm[0][t] + sm[1][t] + sm[2][t] + sm[3][t] + sb[t];
      sig = 1.f / (1.f + expf(-5.f * sig));
      sig += 1e-5f;
      sig = expf(sig * 1.0986122886681098f) - 1.f;
      long idx = ((long)(b * 8 + t) << 8) | l;
      coef[idx] = 0.3989422804014327f / sig;
      c2f[idx] = -0.5f / (sig * sig);
    }
  }
}

// =============== fused attention: scores+softmax+series+prior+PV ===========
__global__ __launch_bounds__(256, 2) void fused_attn(
    const u16* __restrict__ qk16, const u16* __restrict__ vt16,
    const float* __restrict__ vbias, const float* __restrict__ coef,
    const float* __restrict__ c2f, float* __restrict__ ser,
    float* __restrict__ pri, u16* __restrict__ pv16) {
  __shared__ __align__(16) char smem[67584];
  char* Kreg = smem;                       // 32KB: K staging / P matrix (fp16)
  char* V0 = smem + 32768;                 // 16KB: Q stage then V half0
  char* V1 = smem + 49152;                 // 16KB: V half1
  float* rowred = (float*)(smem + 65536);  // 2048B = [4][64][2] floats
  const int t = threadIdx.x, lane = t & 63, w = t >> 6;
  const int fr = lane & 15, gq = lane >> 4;
  const int r0 = blockIdx.x * 64;
  const int bh = blockIdx.y, b = bh >> 3, h = bh & 7;
  const long qrow0 = (long)b * 256 + r0;
  const long krow0 = (long)b * 256;
  {
    const char* qs = (const char*)qk16 + qrow0 * 2048 + h * 128;
#pragma unroll
    for (int j = 0; j < 2; ++j) {
      int id = t + j * 256;
      int row = id >> 3, c = id & 7;
      *(s16x8*)(V0 + row * 144 + c * 16) =
          *(const s16x8*)(qs + (long)row * 2048 + c * 16);
    }
  }
  const char* kb = (const char*)qk16 + krow0 * 2048 + 1024 + h * 128;
#pragma unroll
  for (int j = 0; j < 8; ++j) {
    int id = t + j * 256;
    int row = id >> 3, c = (id & 7) ^ (row & 7);
    gload16(kb + (long)row * 2048 + c * 16, Kreg + id * 16);
  }
  __syncthreads();
  f32x4 acc[4][4] = {};
#pragma unroll
  for (int ks = 0; ks < 2; ++ks) {
    f16x8 aq[4], bk[4];
#pragma unroll
    for (int m = 0; m < 4; ++m)
      aq[m] = *(const f16x8*)(V0 + (m * 16 + fr) * 144 + gq * 16 + ks * 64);
#pragma unroll
    for (int n = 0; n < 4; ++n) {
      int row = w * 64 + n * 16 + fr;
      bk[n] = *(const f16x8*)(Kreg + row * 128 +
                              ((gq * 16 + ks * 64) ^ ((row & 7) << 4)));
    }
#pragma unroll
    for (int m = 0; m < 4; ++m)
#pragma unroll
      for (int n = 0; n < 4; ++n)
        acc[m][n] =
            __builtin_amdgcn_mfma_f32_16x16x32_f16(aq[m], bk[n], acc[m][n], 0, 0, 0);
  }
#pragma unroll
  for (int m = 0; m < 4; ++m)
#pragma unroll
    for (int n = 0; n < 4; ++n) acc[m][n] *= 0.125f;
  float lmax[4][4], lsum[4][4];
#pragma unroll
  for (int m = 0; m < 4; ++m)
#pragma unroll
    for (int r = 0; r < 4; ++r) {
      float v = fmaxf(fmaxf(acc[m][0][r], acc[m][1][r]),
                      fmaxf(acc[m][2][r], acc[m][3][r]));
#pragma unroll
      for (int off = 8; off > 0; off >>= 1) v = fmaxf(v, __shfl_xor(v, off, 64));
      lmax[m][r] = v;
    }
#pragma unroll
  for (int m = 0; m < 4; ++m)
#pragma unroll
    for (int n = 0; n < 4; ++n)
#pragma unroll
      for (int r = 0; r < 4; ++r)
        acc[m][n][r] = __expf(acc[m][n][r] - lmax[m][r]);
#pragma unroll
  for (int m = 0; m < 4; ++m)
#pragma unroll
    for (int r = 0; r < 4; ++r) {
      float s = acc[m][0][r] + acc[m][1][r] + acc[m][2][r] + acc[m][3][r];
#pragma unroll
      for (int off = 8; off > 0; off >>= 1) s += __shfl_xor(s, off, 64);
      lsum[m][r] = s;
    }
  if (fr == 0) {
#pragma unroll
    for (int m = 0; m < 4; ++m)
#pragma unroll
      for (int r = 0; r < 4; ++r) {
        int row = m * 16 + gq * 4 + r;
        rowred[(w * 64 + row) * 2] = lmax[m][r];
        rowred[(w * 64 + row) * 2 + 1] = lsum[m][r];
      }
  }
  __syncthreads();
  float scale[4][4];
#pragma unroll
  for (int m = 0; m < 4; ++m)
#pragma unroll
    for (int r = 0; r < 4; ++r) {
      int row = m * 16 + gq * 4 + r;
      float g = -1e30f, tot = 0.f;
      float2 pr[4];
#pragma unroll
      for (int ww = 0; ww < 4; ++ww) {
        pr[ww] = *(const float2*)&rowred[(ww * 64 + row) * 2];
        g = fmaxf(g, pr[ww].x);
      }
#pragma unroll
      for (int ww = 0; ww < 4; ++ww) tot += pr[ww].y * __expf(pr[ww].x - g);
      scale[m][r] = __expf(lmax[m][r] - g) / tot;
    }
  const char* vtb = (const char*)vt16 + ((long)h * 64 * 8192 + krow0) * 2;
#pragma unroll
  for (int j = 0; j < 4; ++j) {
    int id = t + j * 256;
    int row = id >> 5, c = (id & 31) ^ (row & 7);
    gload16(vtb + (long)row * 16384 + c * 16, V0 + id * 16);
    gload16(vtb + (long)(32 + row) * 16384 + c * 16, V1 + id * 16);
  }
  float* serb = ser + ((long)bh * 256 + r0) * 256 + w * 64;
  float* prib = pri + ((long)bh * 256 + r0) * 256 + w * 64;
  const float* cfb = coef + bh * 256 + r0;
  const float* ccb = c2f + bh * 256 + r0;
#pragma unroll
  for (int m = 0; m < 4; ++m)
#pragma unroll
    for (int r = 0; r < 4; ++r) {
      int row = m * 16 + gq * 4 + r;
      float cf = cfb[row], cc = ccb[row];
      float fl = (float)(r0 + row);
#pragma unroll
      for (int n = 0; n < 4; ++n) {
        int col = n * 16 + fr;
        float p = acc[m][n][r] * scale[m][r];
        serb[(long)row * 256 + col] = p;
        int pb = row * 512 + (((w * 64 + col) * 2) ^ ((row & 7) << 4));
        *(u16*)(Kreg + pb) = f2h(p);
        float dd = fl - (float)(w * 64 + col);
        prib[(long)row * 256 + col] = cf * __expf(cc * dd * dd);
      }
    }
  __syncthreads();  // drains both V halves + P visible
  f32x4 acc2[2][2] = {};
#pragma unroll
  for (int ks = 0; ks < 8; ++ks) {
    int arow = w * 16 + fr;
    f16x8 pa = *(const f16x8*)(
        Kreg + arow * 512 + ((gq * 16 + ks * 64) ^ ((arow & 7) << 4)));
#pragma unroll
    for (int n = 0; n < 2; ++n) {
      int vrow = n * 16 + fr;
      int vo = vrow * 512 + ((gq * 16 + ks * 64) ^ ((vrow & 7) << 4));
      f16x8 vb0 = *(const f16x8*)(V0 + vo);
      f16x8 vb1 = *(const f16x8*)(V1 + vo);
      acc2[0][n] = __builtin_amdgcn_mfma_f32_16x16x32_f16(pa, vb0, acc2[0][n], 0, 0, 0);
      acc2[1][n] = __builtin_amdgcn_mfma_f32_16x16x32_f16(pa, vb1, acc2[1][n], 0, 0, 0);
    }
  }
#pragma unroll
  for (int half = 0; half < 2; ++half)
#pragma unroll
    for (int n = 0; n < 2; ++n)
#pragma unroll
      for (int r = 0; r < 4; ++r) {
        int gcol = h * 64 + half * 32 + n * 16 + fr;
        long gm = qrow0 + w * 16 + gq * 4 + r;
        pv16[gm * 512 + gcol] = f2h(acc2[half][n][r] + vbias[gcol]);
      }
}

// ---------------- fp32 tiled GEMM (d1 only: K=16) --------------------------
template <int ACT, bool O16>
__global__ __launch_bounds__(256) void gemm_kernel(
    const float* __restrict__ A, const float* __restrict__ Bm,
    const float* __restrict__ bias, float* __restrict__ C,
    u16* __restrict__ C16, int M, int N, int K, int lda, int ldb, int ldc) {
  __shared__ float Asm[16][65];
  __shared__ float Bsm[16][65];
  int t = threadIdx.x;
  int tx = t & 15, ty = t >> 4;
  int n0 = blockIdx.x * 64, m0 = blockIdx.y * 64;
  float acc[4][4] = {};
  for (int k0 = 0; k0 < K; k0 += 16) {
#pragma unroll
    for (int e = 0; e < 4; ++e) {
      int idx = t + e * 256;
      int mi = idx >> 4, ki = idx & 15;
      int m = m0 + mi, kk = k0 + ki;
      Asm[ki][mi] = (m < M && kk < K) ? A[(long)m * lda + kk] : 0.f;
      int n = n0 + mi;
      Bsm[ki][mi] = (n < N && kk < K) ? Bm[(long)n * ldb + kk] : 0.f;
    }
    __syncthreads();
#pragma unroll
    for (int kk = 0; kk < 16; ++kk) {
      float a[4], b[4];
#pragma unroll
      for (int i = 0; i < 4; ++i) a[i] = Asm[kk][ty + 16 * i];
#pragma unroll
      for (int j = 0; j < 4; ++j) b[j] = Bsm[kk][tx + 16 * j];
#pragma unroll
      for (int i = 0; i < 4; ++i)
#pragma unroll
        for (int j = 0; j < 4; ++j) acc[i][j] = fmaf(a[i], b[j], acc[i][j]);
    }
    __syncthreads();
  }
#pragma unroll
  for (int i = 0; i < 4; ++i) {
    int m = m0 + ty + 16 * i;
    if (m >= M) continue;
#pragma unroll
    for (int j = 0; j < 4; ++j) {
      int n = n0 + tx + 16 * j;
      if (n >= N) continue;
      float v = acc[i][j];
      if (bias) v += bias[n];
      if (ACT == 2) v = fmaxf(v, 0.f);
      if (O16)
        C16[(long)m * ldc + n] = f2h(v);
      else
        C[(long)m * ldc + n] = v;
    }
  }
}

// -------- merged one-time prep: embed (512 blocks) + all weight convs ------
__global__ __launch_bounds__(256) void conv_embed_kernel(
    const float* __restrict__ x, const float* __restrict__ tw,
    const float* __restrict__ qkv_w, const float* __restrict__ out_w,
    const float* __restrict__ c1w, const float* __restrict__ c2w,
    const float* __restrict__ latw, const float* __restrict__ d2w,
    float* __restrict__ h32, u16* __restrict__ h16, u16* __restrict__ wqkv16,
    u16* __restrict__ wo16, u16* __restrict__ c116, u16* __restrict__ c216,
    u16* __restrict__ latpad, u16* __restrict__ d2pad) {
  __shared__ float xs[18][56];
  int bx = blockIdx.x;
  int t = threadIdx.x;
  if (bx < 512) {
    // ---- embed: circular conv1d + PE -> fp32 + fp16
    int lt = (bx & 15) * 16;
    int b = bx >> 4;
    for (int idx = t; idx < 18 * 55; idx += 256) {
      int rr = idx / 55, cc = idx % 55;
      int gl = (lt + rr - 1 + L_) & (L_ - 1);
      xs[rr][cc] = x[(long)(b * L_ + gl) * C_ + cc];
    }
    __syncthreads();
    for (int dp = 0; dp < 2; ++dp) {
      int d = t + dp * 256;
      float acc[16] = {};
      const float* wr = tw + (long)d * (C_ * 3);
      for (int c = 0; c < C_; ++c) {
#pragma unroll
        for (int w = 0; w < 3; ++w) {
          float wv = wr[c * 3 + w];
#pragma unroll
          for (int l = 0; l < 16; ++l) acc[l] = fmaf(xs[l + w][c], wv, acc[l]);
        }
      }
      float ang_scale = expf(-(float)(d & ~1) * 0.017988946039015984f);
#pragma unroll
      for (int l = 0; l < 16; ++l) {
        float ang = (float)(lt + l) * ang_scale;
        float pe = (d & 1) ? cosf(ang) : sinf(ang);
        float v = acc[l] + pe;
        long idx = (long)(b * L_ + lt + l) * D_ + d;
        h32[idx] = v;
        h16[idx] = f2h(v);
      }
    }
    return;
  }
  int cb = bx - 512;
  if (cb < 9216) {            // wqkv: NL*3*DD = 2359296
    int i = cb * 256 + t;
    wqkv16[i] = f2h(qkv_w[i]);
  } else if (cb < 12288) {    // wo
    int i = (cb - 9216) * 256 + t;
    wo16[i] = f2h(out_w[i]);
  } else if (cb < 15360) {    // c1
    int i = (cb - 12288) * 256 + t;
    c116[i] = f2h(c1w[i]);
  } else if (cb < 18432) {    // c2
    int i = (cb - 15360) * 256 + t;
    c216[i] = f2h(c2w[i]);
  } else if (cb < 18560) {    // latpad (64x512, zero rows >= 16)
    int i = (cb - 18432) * 256 + t;
    int r = i >> 9, c = i & 511;
    latpad[i] = (r < Z_) ? f2h(latw[r * 512 + c]) : (u16)0;
  } else {                    // d2pad (64x512, zero rows >= 55)
    int i = (cb - 18560) * 256 + t;
    int r = i >> 9, c = i & 511;
    d2pad[i] = (r < C_) ? f2h(d2w[r * 512 + c]) : (u16)0;
  }
}

// --------- residual + LN (+ optional fused second/final LN) ----------------
// out: v = LN(a (+r)) with gg/be. If g2: u = LN2(v) with g2/b2 -> o16 = u.
// Else o16 = v. ofp (if non-null) always gets v.
__global__ __launch_bounds__(256) void ln2_kernel(
    const float* __restrict__ a, const float* __restrict__ r,
    const float* __restrict__ gg, const float* __restrict__ be,
    float* __restrict__ ofp, u16* __restrict__ o16,
    const float* __restrict__ g2, const float* __restrict__ b2) {
  __shared__ float smw[4];
  long base = (long)blockIdx.x * D_;
  int t = threadIdx.x;
  float x0 = a[base + t], x1 = a[base + t + 256];
  if (r) {
    x0 += r[base + t];
    x1 += r[base + t + 256];
  }
  float v = x0 + x1;
#pragma unroll
  for (int off = 32; off > 0; off >>= 1) v += __shfl_xor(v, off, 64);
  if ((t & 63) == 0) smw[t >> 6] = v;
  __syncthreads();
  float mean = (smw[0] + smw[1] + smw[2] + smw[3]) * (1.f / D_);
  __syncthreads();
  float d0 = x0 - mean, d1 = x1 - mean;
  float vv = d0 * d0 + d1 * d1;
#pragma unroll
  for (int off = 32; off > 0; off >>= 1) vv += __shfl_xor(vv, off, 64);
  if ((t & 63) == 0) smw[t >> 6] = vv;
  __syncthreads();
  float var = (smw[0] + smw[1] + smw[2] + smw[3]) * (1.f / D_);
  float rstd = rsqrtf(var + 1e-5f);
  float v0 = d0 * rstd * gg[t] + be[t];
  float v1 = d1 * rstd * gg[t + 256] + be[t + 256];
  if (ofp) {
    ofp[base + t] = v0;
    ofp[base + t + 256] = v1;
  }
  if (g2) {
    // second LN pass (bit-identical to standalone kernel on v0/v1)
    __syncthreads();
    float s2 = v0 + v1;
#pragma unroll
    for (int off = 32; off > 0; off >>= 1) s2 += __shfl_xor(s2, off, 64);
    if ((t & 63) == 0) smw[t >> 6] = s2;
    __syncthreads();
    float mean2 = (smw[0] + smw[1] + smw[2] + smw[3]) * (1.f / D_);
    __syncthreads();
    float e0 = v0 - mean2, e1 = v1 - mean2;
    float vv2 = e0 * e0 + e1 * e1;
#pragma unroll
    for (int off = 32; off > 0; off >>= 1) vv2 += __shfl_xor(vv2, off, 64);
    if ((t & 63) == 0) smw[t >> 6] = vv2;
    __syncthreads();
    float var2 = (smw[0] + smw[1] + smw[2] + smw[3]) * (1.f / D_);
    float rstd2 = rsqrtf(var2 + 1e-5f);
    v0 = e0 * rstd2 * g2[t] + b2[t];
    v1 = e1 * rstd2 * g2[t + 256] + b2[t + 256];
  }
  if (o16) {
    o16[base + t] = f2h(v0);
    o16[base + t + 256] = f2h(v1);
  }
}

extern "C" void kernel_launch(void* const* d_in, const int* in_sizes, int n_in,
                              void* d_out, int out_size, void* d_ws,
                              size_t ws_size, hipStream_t stream) {
  (void)in_sizes; (void)n_in; (void)out_size; (void)ws_size;
  const float* x = (const float*)d_in[0];
  const float* tok_w = (const float*)d_in[1];
  const float* qkv_w = (const float*)d_in[2];
  const float* qkv_b = (const float*)d_in[3];
  const float* sig_w = (const float*)d_in[4];
  const float* sig_b = (const float*)d_in[5];
  const float* out_w = (const float*)d_in[6];
  const float* out_b = (const float*)d_in[7];
  const float* c1w = (const float*)d_in[8];
  const float* c1b = (const float*)d_in[9];
  const float* c2w = (const float*)d_in[10];
  const float* c2b = (const float*)d_in[11];
  const float* ln1g = (const float*)d_in[12];
  const float* ln1b = (const float*)d_in[13];
  const float* ln2g = (const float*)d_in[14];
  const float* ln2b = (const float*)d_in[15];
  const float* lnfg = (const float*)d_in[16];
  const float* lnfb = (const float*)d_in[17];
  const float* latw = (const float*)d_in[18];
  const float* latb = (const float*)d_in[19];
  const float* d1w = (const float*)d_in[20];
  const float* d1b = (const float*)d_in[21];
  const float* d2w = (const float*)d_in[22];
  const float* d2b = (const float*)d_in[23];
  float* out = (float*)d_out;

  const long BLD = (long)B_ * L_ * D_;         // 4194304
  const long CHUNK = (long)B_ * H_ * L_ * L_;  // 16777216
  const long SER_OFF = (long)B_ * L_ * C_;
  const long PRI_OFF = SER_OFF + NL_ * CHUNK;
  const long Z_OFF = PRI_OFF + NL_ * CHUNK;
  const int M = B_ * L_;  // 8192
  const int DD = D_ * D_;

  char* wp = (char*)d_ws;
  auto alloc = [&](size_t bytes) {
    char* p = wp;
    wp += (bytes + 255) & ~(size_t)255;
    return p;
  };
  float* h32 = (float*)alloc(BLD * 4);
  u16* h16 = (u16*)alloc(BLD * 2);
  float* tb = (float*)alloc(BLD * 4);
  u16* qk16 = (u16*)alloc(BLD * 4);  // (M,1024); reused as y16
  u16* vt16 = (u16*)alloc(BLD * 2);  // also dec16 at tail
  u16* pv16 = (u16*)alloc(BLD * 2);
  float* coef = (float*)alloc((size_t)B_ * H_ * L_ * 4);
  float* c2f = (float*)alloc((size_t)B_ * H_ * L_ * 4);
  u16* wqkv16 = (u16*)alloc((size_t)NL_ * 3 * DD * 2);
  u16* wo16 = (u16*)alloc((size_t)NL_ * DD * 2);
  u16* c116 = (u16*)alloc((size_t)NL_ * DD * 2);
  u16* c216 = (u16*)alloc((size_t)NL_ * DD * 2);
  u16* latpad = (u16*)alloc((size_t)64 * 512 * 2);
  u16* d2pad = (u16*)alloc((size_t)64 * 512 * 2);

  // one-time prep: embed + all weight conversions, one launch (18688 blocks)
  conv_embed_kernel<<<18688, 256, 0, stream>>>(
      x, tok_w, qkv_w, out_w, c1w, c2w, latw, d2w, h32, h16, wqkv16, wo16,
      c116, c216, latpad, d2pad);

  for (int i = 0; i < NL_; ++i) {
    const long ofQK = (long)(i * 3) * DD;
    // merged q,k projection + v^T + sigma, one 8960-block launch
    qkv_kernel<<<8960, 256, 0, stream>>>(
        h16, wqkv16 + ofQK, qkv_b + (long)i * 3 * D_, qk16, vt16, h32,
        sig_w + (long)i * H_ * D_, sig_b + i * H_, coef, c2f);
    fused_attn<<<dim3(4, 256), 256, 0, stream>>>(
        qk16, vt16, qkv_b + (long)(i * 3 + 2) * D_, coef, c2f,
        out + SER_OFF + i * CHUNK, out + PRI_OFF + i * CHUNK, pv16);
    // out projection (fp32 out)
    mgemm<2, 1, 0, 0><<<dim3(8, 64), 128, 0, stream>>>(
        pv16, wo16 + (long)i * DD, out_b + i * D_, tb, nullptr, D_, D_, D_, D_,
        D_);
    ln2_kernel<<<M, 256, 0, stream>>>(h32, tb, ln1g + i * D_, ln1b + i * D_,
                                      h32, h16, nullptr, nullptr);
    // FFN (intermediate y16 reuses qk16)
    u16* y16 = qk16;
    mgemm<2, 1, 1, 1><<<dim3(8, 64), 128, 0, stream>>>(
        h16, c116 + (long)i * DD, c1b + i * DF_, nullptr, y16, D_, D_, D_, DF_,
        DF_);
    mgemm<2, 1, 0, 0><<<dim3(8, 64), 128, 0, stream>>>(
        y16, c216 + (long)i * DD, c2b + i * D_, tb, nullptr, DF_, DF_, DF_, D_,
        D_);
    // trailing LN; layer 2 fuses the final LN (h32 no longer needed then)
    bool last = (i == NL_ - 1);
    ln2_kernel<<<M, 256, 0, stream>>>(
        h32, tb, ln2g + i * D_, ln2b + i * D_, last ? nullptr : h32, h16,
        last ? lnfg : nullptr, last ? lnfb : nullptr);
  }
  // latent: z = LNf(h) @ latw^T + latb  (fp16 MFMA, N=16 guarded)
  mgemm<2, 1, 0, 0><<<dim3(1, 64), 128, 0, stream>>>(
      h16, latpad, latb, out + Z_OFF, nullptr, D_, D_, D_, Z_, Z_);
  // d1: relu(z @ d1w^T + d1b) -> fp16 (K=16, fp32 path)
  u16* dec16 = vt16;
  gemm_kernel<2, true><<<dim3(8, 128), 256, 0, stream>>>(
      out + Z_OFF, d1w, d1b, nullptr, dec16, M, D_, Z_, Z_, Z_, D_);
  // d2: recon = dec @ d2w^T + d2b (fp16 MFMA, N=55 guarded)
  mgemm<2, 1, 0, 0><<<dim3(1, 64), 128, 0, stream>>>(
      dec16, d2pad, d2b, out, nullptr, D_, D_, D_, C_, C_);
}

// Round 11
// 640.317 us; speedup vs baseline: 2.0384x; 1.2052x over previous
//
#include <hip/hip_runtime.h>
#include <math.h>

#define B_ 32
#define L_ 256
#define C_ 55
#define D_ 512
#define H_ 8
#define NL_ 3
#define DF_ 512
#define Z_ 16
#define DK_ 64

typedef unsigned short u16;
typedef __attribute__((ext_vector_type(8))) short s16x8;
typedef __attribute__((ext_vector_type(8))) _Float16 f16x8;
typedef __attribute__((ext_vector_type(4))) float f32x4;

__device__ __forceinline__ u16 f2h(float f) {
  _Float16 h = (_Float16)f;
  return __builtin_bit_cast(u16, h);
}
__device__ __forceinline__ void gload16(const void* g, void* l) {
  __builtin_amdgcn_global_load_lds(
      (const __attribute__((address_space(1))) unsigned*)g,
      (__attribute__((address_space(3))) unsigned*)l, 16, 0, 0);
}

// ================= fp16 MFMA GEMM body: C = act(A @ B^T + bias) ============
// BK=64, chunk-XOR swizzled LDS. A: (M,K) fp16; B: (N,K) fp16. K % 64 == 0.
// MF: 16-row fragments per wave (wave tile = MF*16 x 64). BM = WM*MF*16.
// OUT: 0 fp32, 1 fp16. ACT: 0 none, 1 exact gelu. Cols >= nmax dropped.
template <int MF, int WM, int WN, int ACT, int OUT>
__device__ __forceinline__ void mgemm_body(
    char* As, char* Bs, const u16* __restrict__ A16,
    const u16* __restrict__ B16, const float* __restrict__ bias,
    float* __restrict__ Cf, u16* __restrict__ C16, int K, int lda, int ldb,
    int ldc, int nmax, int bxi, int byi) {
  constexpr int BM = WM * MF * 16, BN = WN * 64, T = WM * WN * 64;
  constexpr int ACH = BM * 8, BCH = BN * 8;  // 16B chunks per K-tile
  const int t = threadIdx.x, lane = t & 63, w = t >> 6;
  const int wm = w / WN, wn = w % WN;
  const long m0 = (long)byi * BM, n0 = (long)bxi * BN;
  const char* Ab = (const char*)(A16 + m0 * lda);
  const char* Bb = (const char*)(B16 + n0 * ldb);
  const int fr = lane & 15, gq = lane >> 4;
  const long lda2 = (long)lda * 2, ldb2 = (long)ldb * 2;
  f32x4 acc[MF][4] = {};
  for (int k0 = 0; k0 < K; k0 += 64) {
    const long kb = (long)k0 * 2;
#pragma unroll
    for (int e = 0; e < ACH; e += T) {
      int id = e + t;
      int row = id >> 3, c = (id & 7) ^ (row & 7);
      gload16(Ab + (long)row * lda2 + kb + c * 16, As + id * 16);
    }
#pragma unroll
    for (int e = 0; e < BCH; e += T) {
      int id = e + t;
      int row = id >> 3, c = (id & 7) ^ (row & 7);
      gload16(Bb + (long)row * ldb2 + kb + c * 16, Bs + id * 16);
    }
    __syncthreads();
#pragma unroll
    for (int ks = 0; ks < 2; ++ks) {
      f16x8 a[MF], b[4];
#pragma unroll
      for (int m = 0; m < MF; ++m) {
        int row = wm * (MF * 16) + m * 16 + fr;
        a[m] = *(const f16x8*)(As + row * 128 +
                               ((gq * 16 + ks * 64) ^ ((row & 7) << 4)));
      }
#pragma unroll
      for (int n = 0; n < 4; ++n) {
        int row = wn * 64 + n * 16 + fr;
        b[n] = *(const f16x8*)(Bs + row * 128 +
                               ((gq * 16 + ks * 64) ^ ((row & 7) << 4)));
      }
#pragma unroll
      for (int m = 0; m < MF; ++m)
#pragma unroll
        for (int n = 0; n < 4; ++n)
          acc[m][n] =
              __builtin_amdgcn_mfma_f32_16x16x32_f16(a[m], b[n], acc[m][n], 0, 0, 0);
    }
    __syncthreads();
  }
#pragma unroll
  for (int m = 0; m < MF; ++m) {
    long mg = m0 + wm * (MF * 16) + m * 16 + gq * 4;
#pragma unroll
    for (int n = 0; n < 4; ++n) {
      int ng = (int)n0 + wn * 64 + n * 16 + fr;
      if (ng >= nmax) continue;
      float bv = bias ? bias[ng] : 0.f;
#pragma unroll
      for (int r = 0; r < 4; ++r) {
        float v = acc[m][n][r] + bv;
        if (ACT == 1) v = 0.5f * v * (1.f + erff(v * 0.70710678118654752f));
        long idx = (mg + r) * ldc + ng;
        if (OUT == 0) Cf[idx] = v;
        if (OUT == 1) C16[idx] = f2h(v);
      }
    }
  }
}

template <int MF, int WM, int WN, int ACT, int OUT>
__global__ __launch_bounds__(WM * WN * 64) void mgemm(
    const u16* __restrict__ A16, const u16* __restrict__ B16,
    const float* __restrict__ bias, float* __restrict__ Cf,
    u16* __restrict__ C16, int K, int lda, int ldb, int ldc, int nmax) {
  __shared__ __align__(16) char As[WM * MF * 16 * 128];
  __shared__ __align__(16) char Bs[WN * 64 * 128];
  mgemm_body<MF, WM, WN, ACT, OUT>(As, Bs, A16, B16, bias, Cf, C16, K, lda,
                                   ldb, ldc, nmax, blockIdx.x, blockIdx.y);
}

// ---- merged: sigma (8192, first) + q,k proj (512) + v^T (512), one launch -
__global__ __launch_bounds__(256) void qkv_kernel(
    const u16* __restrict__ h16, const u16* __restrict__ w16,
    const float* __restrict__ bias, u16* __restrict__ qk16,
    u16* __restrict__ vt16, const float* __restrict__ h32,
    const float* __restrict__ sw, const float* __restrict__ sb,
    float* __restrict__ coef, float* __restrict__ c2f) {
  __shared__ __align__(16) char As[128 * 128];
  __shared__ __align__(16) char Bs[128 * 128];
  __shared__ float sm[4][8];
  int bx = blockIdx.x;
  if (bx < 8192) {
    // sigma body (identical to proven standalone sigma_kernel)
    int bl = bx;
    int l = bl & 255, b = bl >> 8;
    int t = threadIdx.x;
    const float* hrow = h32 + (long)bl * 512;
    float h0 = hrow[t], h1 = hrow[t + 256];
    float part[8];
#pragma unroll
    for (int hd = 0; hd < 8; ++hd) {
      const float* wrow = sw + hd * 512;
      part[hd] = h0 * wrow[t] + h1 * wrow[t + 256];
    }
#pragma unroll
    for (int off = 32; off > 0; off >>= 1)
#pragma unroll
      for (int hd = 0; hd < 8; ++hd) part[hd] += __shfl_xor(part[hd], off, 64);
    int wid = t >> 6;
    if ((t & 63) == 0) {
#pragma unroll
      for (int hd = 0; hd < 8; ++hd) sm[wid][hd] = part[hd];
    }
    __syncthreads();
    if (t < 8) {
      float sig = sm[0][t] + sm[1][t] + sm[2][t] + sm[3][t] + sb[t];
      sig = 1.f / (1.f + expf(-5.f * sig));
      sig += 1e-5f;
      sig = expf(sig * 1.0986122886681098f) - 1.f;
      long idx = ((long)(b * 8 + t) << 8) | l;
      coef[idx] = 0.3989422804014327f / sig;
      c2f[idx] = -0.5f / (sig * sig);
    }
  } else if (bx < 8704) {
    int b2 = bx - 8192;
    mgemm_body<4, 2, 2, 0, 1>(As, Bs, h16, w16, bias, nullptr, qk16, 512, 512,
                              512, 1024, 1024, b2 & 7, b2 >> 3);
  } else {
    int b3 = bx - 8704;  // 512 items: vt (512 x 8192), BM=64 BN=128
    mgemm_body<2, 2, 2, 0, 1>(As, Bs, w16 + 1024 * 512, h16, nullptr, nullptr,
                              vt16, 512, 512, 512, 8192, 8192, b3 & 63,
                              b3 >> 6);
  }
}

// =============== fused attention: scores+softmax+series+prior+PV ===========
__global__ __launch_bounds__(256, 2) void fused_attn(
    const u16* __restrict__ qk16, const u16* __restrict__ vt16,
    const float* __restrict__ vbias, const float* __restrict__ coef,
    const float* __restrict__ c2f, float* __restrict__ ser,
    float* __restrict__ pri, u16* __restrict__ pv16) {
  __shared__ __align__(16) char smem[67584];
  char* Kreg = smem;                       // 32KB: K staging / P matrix (fp16)
  char* V0 = smem + 32768;                 // 16KB: Q stage then V half0
  char* V1 = smem + 49152;                 // 16KB: V half1
  float* rowred = (float*)(smem + 65536);  // 2048B = [4][64][2] floats
  const int t = threadIdx.x, lane = t & 63, w = t >> 6;
  const int fr = lane & 15, gq = lane >> 4;
  const int r0 = blockIdx.x * 64;
  const int bh = blockIdx.y, b = bh >> 3, h = bh & 7;
  const long qrow0 = (long)b * 256 + r0;
  const long krow0 = (long)b * 256;
  {
    const char* qs = (const char*)qk16 + qrow0 * 2048 + h * 128;
#pragma unroll
    for (int j = 0; j < 2; ++j) {
      int id = t + j * 256;
      int row = id >> 3, c = id & 7;
      *(s16x8*)(V0 + row * 144 + c * 16) =
          *(const s16x8*)(qs + (long)row * 2048 + c * 16);
    }
  }
  const char* kb = (const char*)qk16 + krow0 * 2048 + 1024 + h * 128;
#pragma unroll
  for (int j = 0; j < 8; ++j) {
    int id = t + j * 256;
    int row = id >> 3, c = (id & 7) ^ (row & 7);
    gload16(kb + (long)row * 2048 + c * 16, Kreg + id * 16);
  }
  __syncthreads();
  f32x4 acc[4][4] = {};
#pragma unroll
  for (int ks = 0; ks < 2; ++ks) {
    f16x8 aq[4], bk[4];
#pragma unroll
    for (int m = 0; m < 4; ++m)
      aq[m] = *(const f16x8*)(V0 + (m * 16 + fr) * 144 + gq * 16 + ks * 64);
#pragma unroll
    for (int n = 0; n < 4; ++n) {
      int row = w * 64 + n * 16 + fr;
      bk[n] = *(const f16x8*)(Kreg + row * 128 +
                              ((gq * 16 + ks * 64) ^ ((row & 7) << 4)));
    }
#pragma unroll
    for (int m = 0; m < 4; ++m)
#pragma unroll
      for (int n = 0; n < 4; ++n)
        acc[m][n] =
            __builtin_amdgcn_mfma_f32_16x16x32_f16(aq[m], bk[n], acc[m][n], 0, 0, 0);
  }
#pragma unroll
  for (int m = 0; m < 4; ++m)
#pragma unroll
    for (int n = 0; n < 4; ++n) acc[m][n] *= 0.125f;
  float lmax[4][4], lsum[4][4];
#pragma unroll
  for (int m = 0; m < 4; ++m)
#pragma unroll
    for (int r = 0; r < 4; ++r) {
      float v = fmaxf(fmaxf(acc[m][0][r], acc[m][1][r]),
                      fmaxf(acc[m][2][r], acc[m][3][r]));
#pragma unroll
      for (int off = 8; off > 0; off >>= 1) v = fmaxf(v, __shfl_xor(v, off, 64));
      lmax[m][r] = v;
    }
#pragma unroll
  for (int m = 0; m < 4; ++m)
#pragma unroll
    for (int n = 0; n < 4; ++n)
#pragma unroll
      for (int r = 0; r < 4; ++r)
        acc[m][n][r] = __expf(acc[m][n][r] - lmax[m][r]);
#pragma unroll
  for (int m = 0; m < 4; ++m)
#pragma unroll
    for (int r = 0; r < 4; ++r) {
      float s = acc[m][0][r] + acc[m][1][r] + acc[m][2][r] + acc[m][3][r];
#pragma unroll
      for (int off = 8; off > 0; off >>= 1) s += __shfl_xor(s, off, 64);
      lsum[m][r] = s;
    }
  if (fr == 0) {
#pragma unroll
    for (int m = 0; m < 4; ++m)
#pragma unroll
      for (int r = 0; r < 4; ++r) {
        int row = m * 16 + gq * 4 + r;
        rowred[(w * 64 + row) * 2] = lmax[m][r];
        rowred[(w * 64 + row) * 2 + 1] = lsum[m][r];
      }
  }
  __syncthreads();
  float scale[4][4];
#pragma unroll
  for (int m = 0; m < 4; ++m)
#pragma unroll
    for (int r = 0; r < 4; ++r) {
      int row = m * 16 + gq * 4 + r;
      float g = -1e30f, tot = 0.f;
      float2 pr[4];
#pragma unroll
      for (int ww = 0; ww < 4; ++ww) {
        pr[ww] = *(const float2*)&rowred[(ww * 64 + row) * 2];
        g = fmaxf(g, pr[ww].x);
      }
#pragma unroll
      for (int ww = 0; ww < 4; ++ww) tot += pr[ww].y * __expf(pr[ww].x - g);
      scale[m][r] = __expf(lmax[m][r] - g) / tot;
    }
  const char* vtb = (const char*)vt16 + ((long)h * 64 * 8192 + krow0) * 2;
#pragma unroll
  for (int j = 0; j < 4; ++j) {
    int id = t + j * 256;
    int row = id >> 5, c = (id & 31) ^ (row & 7);
    gload16(vtb + (long)row * 16384 + c * 16, V0 + id * 16);
    gload16(vtb + (long)(32 + row) * 16384 + c * 16, V1 + id * 16);
  }
  float* serb = ser + ((long)bh * 256 + r0) * 256 + w * 64;
  float* prib = pri + ((long)bh * 256 + r0) * 256 + w * 64;
  const float* cfb = coef + bh * 256 + r0;
  const float* ccb = c2f + bh * 256 + r0;
#pragma unroll
  for (int m = 0; m < 4; ++m)
#pragma unroll
    for (int r = 0; r < 4; ++r) {
      int row = m * 16 + gq * 4 + r;
      float cf = cfb[row], cc = ccb[row];
      float fl = (float)(r0 + row);
#pragma unroll
      for (int n = 0; n < 4; ++n) {
        int col = n * 16 + fr;
        float p = acc[m][n][r] * scale[m][r];
        serb[(long)row * 256 + col] = p;
        int pb = row * 512 + (((w * 64 + col) * 2) ^ ((row & 7) << 4));
        *(u16*)(Kreg + pb) = f2h(p);
        float dd = fl - (float)(w * 64 + col);
        prib[(long)row * 256 + col] = cf * __expf(cc * dd * dd);
      }
    }
  __syncthreads();  // drains both V halves + P visible
  f32x4 acc2[2][2] = {};
#pragma unroll
  for (int ks = 0; ks < 8; ++ks) {
    int arow = w * 16 + fr;
    f16x8 pa = *(const f16x8*)(
        Kreg + arow * 512 + ((gq * 16 + ks * 64) ^ ((arow & 7) << 4)));
#pragma unroll
    for (int n = 0; n < 2; ++n) {
      int vrow = n * 16 + fr;
      int vo = vrow * 512 + ((gq * 16 + ks * 64) ^ ((vrow & 7) << 4));
      f16x8 vb0 = *(const f16x8*)(V0 + vo);
      f16x8 vb1 = *(const f16x8*)(V1 + vo);
      acc2[0][n] = __builtin_amdgcn_mfma_f32_16x16x32_f16(pa, vb0, acc2[0][n], 0, 0, 0);
      acc2[1][n] = __builtin_amdgcn_mfma_f32_16x16x32_f16(pa, vb1, acc2[1][n], 0, 0, 0);
    }
  }
#pragma unroll
  for (int half = 0; half < 2; ++half)
#pragma unroll
    for (int n = 0; n < 2; ++n)
#pragma unroll
      for (int r = 0; r < 4; ++r) {
        int gcol = h * 64 + half * 32 + n * 16 + fr;
        long gm = qrow0 + w * 16 + gq * 4 + r;
        pv16[gm * 512 + gcol] = f2h(acc2[half][n][r] + vbias[gcol]);
      }
}

// ---------------- fp32 tiled GEMM (d1 only: K=16) --------------------------
template <int ACT, bool O16>
__global__ __launch_bounds__(256) void gemm_kernel(
    const float* __restrict__ A, const float* __restrict__ Bm,
    const float* __restrict__ bias, float* __restrict__ C,
    u16* __restrict__ C16, int M, int N, int K, int lda, int ldb, int ldc) {
  __shared__ float Asm[16][65];
  __shared__ float Bsm[16][65];
  int t = threadIdx.x;
  int tx = t & 15, ty = t >> 4;
  int n0 = blockIdx.x * 64, m0 = blockIdx.y * 64;
  float acc[4][4] = {};
  for (int k0 = 0; k0 < K; k0 += 16) {
#pragma unroll
    for (int e = 0; e < 4; ++e) {
      int idx = t + e * 256;
      int mi = idx >> 4, ki = idx & 15;
      int m = m0 + mi, kk = k0 + ki;
      Asm[ki][mi] = (m < M && kk < K) ? A[(long)m * lda + kk] : 0.f;
      int n = n0 + mi;
      Bsm[ki][mi] = (n < N && kk < K) ? Bm[(long)n * ldb + kk] : 0.f;
    }
    __syncthreads();
#pragma unroll
    for (int kk = 0; kk < 16; ++kk) {
      float a[4], b[4];
#pragma unroll
      for (int i = 0; i < 4; ++i) a[i] = Asm[kk][ty + 16 * i];
#pragma unroll
      for (int j = 0; j < 4; ++j) b[j] = Bsm[kk][tx + 16 * j];
#pragma unroll
      for (int i = 0; i < 4; ++i)
#pragma unroll
        for (int j = 0; j < 4; ++j) acc[i][j] = fmaf(a[i], b[j], acc[i][j]);
    }
    __syncthreads();
  }
#pragma unroll
  for (int i = 0; i < 4; ++i) {
    int m = m0 + ty + 16 * i;
    if (m >= M) continue;
#pragma unroll
    for (int j = 0; j < 4; ++j) {
      int n = n0 + tx + 16 * j;
      if (n >= N) continue;
      float v = acc[i][j];
      if (bias) v += bias[n];
      if (ACT == 2) v = fmaxf(v, 0.f);
      if (O16)
        C16[(long)m * ldc + n] = f2h(v);
      else
        C[(long)m * ldc + n] = v;
    }
  }
}

// -------- merged one-time prep: embed (512 blocks) + all weight convs ------
__global__ __launch_bounds__(256) void conv_embed_kernel(
    const float* __restrict__ x, const float* __restrict__ tw,
    const float* __restrict__ qkv_w, const float* __restrict__ out_w,
    const float* __restrict__ c1w, const float* __restrict__ c2w,
    const float* __restrict__ latw, const float* __restrict__ d2w,
    float* __restrict__ h32, u16* __restrict__ h16, u16* __restrict__ wqkv16,
    u16* __restrict__ wo16, u16* __restrict__ c116, u16* __restrict__ c216,
    u16* __restrict__ latpad, u16* __restrict__ d2pad) {
  __shared__ float xs[18][56];
  int bx = blockIdx.x;
  int t = threadIdx.x;
  if (bx < 512) {
    int lt = (bx & 15) * 16;
    int b = bx >> 4;
    for (int idx = t; idx < 18 * 55; idx += 256) {
      int rr = idx / 55, cc = idx % 55;
      int gl = (lt + rr - 1 + L_) & (L_ - 1);
      xs[rr][cc] = x[(long)(b * L_ + gl) * C_ + cc];
    }
    __syncthreads();
    for (int dp = 0; dp < 2; ++dp) {
      int d = t + dp * 256;
      float acc[16] = {};
      const float* wr = tw + (long)d * (C_ * 3);
      for (int c = 0; c < C_; ++c) {
#pragma unroll
        for (int w = 0; w < 3; ++w) {
          float wv = wr[c * 3 + w];
#pragma unroll
          for (int l = 0; l < 16; ++l) acc[l] = fmaf(xs[l + w][c], wv, acc[l]);
        }
      }
      float ang_scale = expf(-(float)(d & ~1) * 0.017988946039015984f);
#pragma unroll
      for (int l = 0; l < 16; ++l) {
        float ang = (float)(lt + l) * ang_scale;
        float pe = (d & 1) ? cosf(ang) : sinf(ang);
        float v = acc[l] + pe;
        long idx = (long)(b * L_ + lt + l) * D_ + d;
        h32[idx] = v;
        h16[idx] = f2h(v);
      }
    }
    return;
  }
  int cb = bx - 512;
  if (cb < 9216) {
    int i = cb * 256 + t;
    wqkv16[i] = f2h(qkv_w[i]);
  } else if (cb < 12288) {
    int i = (cb - 9216) * 256 + t;
    wo16[i] = f2h(out_w[i]);
  } else if (cb < 15360) {
    int i = (cb - 12288) * 256 + t;
    c116[i] = f2h(c1w[i]);
  } else if (cb < 18432) {
    int i = (cb - 15360) * 256 + t;
    c216[i] = f2h(c2w[i]);
  } else if (cb < 18560) {
    int i = (cb - 18432) * 256 + t;
    int r = i >> 9, c = i & 511;
    latpad[i] = (r < Z_) ? f2h(latw[r * 512 + c]) : (u16)0;
  } else {
    int i = (cb - 18560) * 256 + t;
    int r = i >> 9, c = i & 511;
    d2pad[i] = (r < C_) ? f2h(d2w[r * 512 + c]) : (u16)0;
  }
}

// --------- wave-per-row residual + LN (+ optional fused second LN) ---------
// 4 rows/block (one per wave), no block barriers. Row held in 8 regs/lane.
__global__ __launch_bounds__(256) void lnw_kernel(
    const float* __restrict__ a, const float* __restrict__ r,
    const float* __restrict__ gg, const float* __restrict__ be,
    float* __restrict__ ofp, u16* __restrict__ o16,
    const float* __restrict__ g2, const float* __restrict__ b2) {
  int wave = threadIdx.x >> 6, lane = threadIdx.x & 63;
  long row = (long)blockIdx.x * 4 + wave;
  long base = row * D_ + lane * 8;
  int cb = lane * 8;
  f32x4 xa = *(const f32x4*)(a + base);
  f32x4 xb = *(const f32x4*)(a + base + 4);
  if (r) {
    xa += *(const f32x4*)(r + base);
    xb += *(const f32x4*)(r + base + 4);
  }
  float x[8] = {xa.x, xa.y, xa.z, xa.w, xb.x, xb.y, xb.z, xb.w};
  float s = 0.f;
#pragma unroll
  for (int e = 0; e < 8; ++e) s += x[e];
#pragma unroll
  for (int off = 32; off > 0; off >>= 1) s += __shfl_xor(s, off, 64);
  float mean = s * (1.f / D_);
  float vv = 0.f;
#pragma unroll
  for (int e = 0; e < 8; ++e) {
    x[e] -= mean;
    vv += x[e] * x[e];
  }
#pragma unroll
  for (int off = 32; off > 0; off >>= 1) vv += __shfl_xor(vv, off, 64);
  float rstd = rsqrtf(vv * (1.f / D_) + 1e-5f);
  f32x4 ga = *(const f32x4*)(gg + cb), gb = *(const f32x4*)(gg + cb + 4);
  f32x4 ba = *(const f32x4*)(be + cb), bb = *(const f32x4*)(be + cb + 4);
  float g[8] = {ga.x, ga.y, ga.z, ga.w, gb.x, gb.y, gb.z, gb.w};
  float bi[8] = {ba.x, ba.y, ba.z, ba.w, bb.x, bb.y, bb.z, bb.w};
  float v[8];
#pragma unroll
  for (int e = 0; e < 8; ++e) v[e] = x[e] * rstd * g[e] + bi[e];
  if (ofp) {
    f32x4 oa = {v[0], v[1], v[2], v[3]}, ob = {v[4], v[5], v[6], v[7]};
    *(f32x4*)(ofp + base) = oa;
    *(f32x4*)(ofp + base + 4) = ob;
  }
  if (g2) {
    float s2 = 0.f;
#pragma unroll
    for (int e = 0; e < 8; ++e) s2 += v[e];
#pragma unroll
    for (int off = 32; off > 0; off >>= 1) s2 += __shfl_xor(s2, off, 64);
    float mean2 = s2 * (1.f / D_);
    float vv2 = 0.f;
#pragma unroll
    for (int e = 0; e < 8; ++e) {
      v[e] -= mean2;
      vv2 += v[e] * v[e];
    }
#pragma unroll
    for (int off = 32; off > 0; off >>= 1) vv2 += __shfl_xor(vv2, off, 64);
    float rstd2 = rsqrtf(vv2 * (1.f / D_) + 1e-5f);
    f32x4 g2a = *(const f32x4*)(g2 + cb), g2b = *(const f32x4*)(g2 + cb + 4);
    f32x4 b2a = *(const f32x4*)(b2 + cb), b2b = *(const f32x4*)(b2 + cb + 4);
    float gg2[8] = {g2a.x, g2a.y, g2a.z, g2a.w, g2b.x, g2b.y, g2b.z, g2b.w};
    float bb2[8] = {b2a.x, b2a.y, b2a.z, b2a.w, b2b.x, b2b.y, b2b.z, b2b.w};
#pragma unroll
    for (int e = 0; e < 8; ++e) v[e] = v[e] * rstd2 * gg2[e] + bb2[e];
  }
  if (o16) {
    u16 h[8];
#pragma unroll
    for (int e = 0; e < 8; ++e) h[e] = f2h(v[e]);
    *(s16x8*)(o16 + base) = *(s16x8*)h;
  }
}

extern "C" void kernel_launch(void* const* d_in, const int* in_sizes, int n_in,
                              void* d_out, int out_size, void* d_ws,
                              size_t ws_size, hipStream_t stream) {
  (void)in_sizes; (void)n_in; (void)out_size; (void)ws_size;
  const float* x = (const float*)d_in[0];
  const float* tok_w = (const float*)d_in[1];
  const float* qkv_w = (const float*)d_in[2];
  const float* qkv_b = (const float*)d_in[3];
  const float* sig_w = (const float*)d_in[4];
  const float* sig_b = (const float*)d_in[5];
  const float* out_w = (const float*)d_in[6];
  const float* out_b = (const float*)d_in[7];
  const float* c1w = (const float*)d_in[8];
  const float* c1b = (const float*)d_in[9];
  const float* c2w = (const float*)d_in[10];
  const float* c2b = (const float*)d_in[11];
  const float* ln1g = (const float*)d_in[12];
  const float* ln1b = (const float*)d_in[13];
  const float* ln2g = (const float*)d_in[14];
  const float* ln2b = (const float*)d_in[15];
  const float* lnfg = (const float*)d_in[16];
  const float* lnfb = (const float*)d_in[17];
  const float* latw = (const float*)d_in[18];
  const float* latb = (const float*)d_in[19];
  const float* d1w = (const float*)d_in[20];
  const float* d1b = (const float*)d_in[21];
  const float* d2w = (const float*)d_in[22];
  const float* d2b = (const float*)d_in[23];
  float* out = (float*)d_out;

  const long BLD = (long)B_ * L_ * D_;         // 4194304
  const long CHUNK = (long)B_ * H_ * L_ * L_;  // 16777216
  const long SER_OFF = (long)B_ * L_ * C_;
  const long PRI_OFF = SER_OFF + NL_ * CHUNK;
  const long Z_OFF = PRI_OFF + NL_ * CHUNK;
  const int M = B_ * L_;  // 8192
  const int DD = D_ * D_;

  char* wp = (char*)d_ws;
  auto alloc = [&](size_t bytes) {
    char* p = wp;
    wp += (bytes + 255) & ~(size_t)255;
    return p;
  };
  float* h32 = (float*)alloc(BLD * 4);
  u16* h16 = (u16*)alloc(BLD * 2);
  float* tb = (float*)alloc(BLD * 4);
  u16* qk16 = (u16*)alloc(BLD * 4);  // (M,1024); reused as y16
  u16* vt16 = (u16*)alloc(BLD * 2);  // also dec16 at tail
  u16* pv16 = (u16*)alloc(BLD * 2);
  float* coef = (float*)alloc((size_t)B_ * H_ * L_ * 4);
  float* c2f = (float*)alloc((size_t)B_ * H_ * L_ * 4);
  u16* wqkv16 = (u16*)alloc((size_t)NL_ * 3 * DD * 2);
  u16* wo16 = (u16*)alloc((size_t)NL_ * DD * 2);
  u16* c116 = (u16*)alloc((size_t)NL_ * DD * 2);
  u16* c216 = (u16*)alloc((size_t)NL_ * DD * 2);
  u16* latpad = (u16*)alloc((size_t)64 * 512 * 2);
  u16* d2pad = (u16*)alloc((size_t)64 * 512 * 2);

  // one-time prep: embed + all weight conversions, one launch (18688 blocks)
  conv_embed_kernel<<<18688, 256, 0, stream>>>(
      x, tok_w, qkv_w, out_w, c1w, c2w, latw, d2w, h32, h16, wqkv16, wo16,
      c116, c216, latpad, d2pad);

  for (int i = 0; i < NL_; ++i) {
    const long ofQK = (long)(i * 3) * DD;
    // merged sigma (first) + q,k projection + v^T, one 9216-block launch
    qkv_kernel<<<9216, 256, 0, stream>>>(
        h16, wqkv16 + ofQK, qkv_b + (long)i * 3 * D_, qk16, vt16, h32,
        sig_w + (long)i * H_ * D_, sig_b + i * H_, coef, c2f);
    fused_attn<<<dim3(4, 256), 256, 0, stream>>>(
        qk16, vt16, qkv_b + (long)(i * 3 + 2) * D_, coef, c2f,
        out + SER_OFF + i * CHUNK, out + PRI_OFF + i * CHUNK, pv16);
    // out projection (fp32 out), MF=2: 2048 waves
    mgemm<2, 2, 1, 0, 0><<<dim3(8, 128), 128, 0, stream>>>(
        pv16, wo16 + (long)i * DD, out_b + i * D_, tb, nullptr, D_, D_, D_, D_,
        D_);
    lnw_kernel<<<M / 4, 256, 0, stream>>>(h32, tb, ln1g + i * D_,
                                          ln1b + i * D_, h32, h16, nullptr,
                                          nullptr);
    // FFN (intermediate y16 reuses qk16), MF=2
    u16* y16 = qk16;
    mgemm<2, 2, 1, 1, 1><<<dim3(8, 128), 128, 0, stream>>>(
        h16, c116 + (long)i * DD, c1b + i * DF_, nullptr, y16, D_, D_, D_, DF_,
        DF_);
    mgemm<2, 2, 1, 0, 0><<<dim3(8, 128), 128, 0, stream>>>(
        y16, c216 + (long)i * DD, c2b + i * D_, tb, nullptr, DF_, DF_, DF_, D_,
        D_);
    // trailing LN; layer 2 fuses the final LN (h32 no longer needed then)
    bool last = (i == NL_ - 1);
    lnw_kernel<<<M / 4, 256, 0, stream>>>(
        h32, tb, ln2g + i * D_, ln2b + i * D_, last ? nullptr : h32, h16,
        last ? lnfg : nullptr, last ? lnfb : nullptr);
  }
  // latent: z = LNf(h) @ latw^T + latb  (fp16 MFMA, N=16 guarded), MF=2
  mgemm<2, 2, 1, 0, 0><<<dim3(1, 128), 128, 0, stream>>>(
      h16, latpad, latb, out + Z_OFF, nullptr, D_, D_, D_, Z_, Z_);
  // d1: relu(z @ d1w^T + d1b) -> fp16 (K=16, fp32 path)
  u16* dec16 = vt16;
  gemm_kernel<2, true><<<dim3(8, 128), 256, 0, stream>>>(
      out + Z_OFF, d1w, d1b, nullptr, dec16, M, D_, Z_, Z_, Z_, D_);
  // d2: recon = dec @ d2w^T + d2b (fp16 MFMA, N=55 guarded), MF=2
  mgemm<2, 2, 1, 0, 0><<<dim3(1, 128), 128, 0, stream>>>(
      dec16, d2pad, d2b, out, nullptr, D_, D_, D_, C_, C_);
}